// Round 1
// baseline (24267.172 us; speedup 1.0000x reference)
//
#include <hip/hip_runtime.h>
#include <math.h>

// ---- problem constants ----
constexpr int B_ = 8;
constexpr int T_ = 128;
constexpr int D_ = 384;
constexpr int H_ = 6;
constexpr int DH_ = 64;
constexpr int L_ = 4;
constexpr int INTER_C = 1536;
constexpr int KC_ = 3;
constexpr int OUT_C = 80;
constexpr int TMEL_C = 1024;   // T * MAXDUR
constexpr int HD_ = H_ * DH_;  // 384

// ---------------------------------------------------------------------------
// Embedding + positional encoding:  x[b,t,d] = 2*emb[tok[b,t],d] + pe(b,d)
// (reference quirk: PE indexed by BATCH index, broadcast over time)
// ---------------------------------------------------------------------------
__global__ __launch_bounds__(256) void embed_kernel(
    const int* __restrict__ tokens, const float* __restrict__ emb,
    float* __restrict__ X) {
  int i = blockIdx.x * 256 + threadIdx.x;
  if (i >= B_ * T_ * D_) return;
  int d = i % D_;
  int bt = i / D_;
  int b = bt / T_;
  int tok = tokens[bt];
  // pe: even d -> sin(pos*den[d/2]), odd d -> cos(pos*den[(d-1)/2]),
  // den[i] = exp(-(2i)*ln(10000)/D)
  int i2 = d & ~1;
  const float c = 9.210340371976184f / (float)D_;  // ln(10000)/D
  float freq = expf(-(float)i2 * c);
  float ang = (float)b * freq;
  float pe = (d & 1) ? cosf(ang) : sinf(ang);
  X[i] = 2.0f * emb[(size_t)tok * D_ + d] + pe;
}

// ---------------------------------------------------------------------------
// Encoder key mask: maske[b,t] = (t > token_lengths[b]) ? -inf : 0
// ---------------------------------------------------------------------------
__global__ void enc_mask_kernel(const int* __restrict__ tl, float* __restrict__ maske) {
  int i = blockIdx.x * 256 + threadIdx.x;
  if (i >= B_ * T_) return;
  int b = i / T_, t = i % T_;
  maske[i] = (t > tl[b]) ? -INFINITY : 0.0f;
}

// ---------------------------------------------------------------------------
// Generic tiled GEMM / K=3 SAME conv (im2col on the fly).
// A: [B, TROWS, CIN]  (flattened rows = B*TROWS)
// W: [KCt*CIN, Cout]  (conv weight [K,Cin,Cout] flattens to this)
// C: [B*TROWS, Cout] = A(*)W + bias, optional relu
// ---------------------------------------------------------------------------
template <int CIN, int KCt, int TROWS>
__global__ __launch_bounds__(256) void gemm_conv_kernel(
    const float* __restrict__ A, const float* __restrict__ W,
    const float* __restrict__ bias, float* __restrict__ C,
    int Cout, int doRelu) {
  __shared__ float As[64][17];
  __shared__ float Ws[16][65];
  const int tid = threadIdx.x;
  const int tx = tid & 15, ty = tid >> 4;
  const int rowBase = blockIdx.y * 64;
  const int colBase = blockIdx.x * 64;
  constexpr int Ktot = CIN * KCt;
  constexpr int pad = KCt / 2;
  float acc[4][4] = {};
  for (int k0 = 0; k0 < Ktot; k0 += 16) {
#pragma unroll
    for (int e = 0; e < 4; ++e) {
      int li = e * 256 + tid;
      int r = li >> 4, cc = li & 15;
      int row = rowBase + r;
      int j = k0 + cc;
      float val;
      if constexpr (KCt == 1) {
        val = A[(size_t)row * CIN + j];
      } else {
        int b = row / TROWS, t = row % TROWS;  // TROWS is pow2 -> shifts
        int kk = j / CIN, ci = j % CIN;        // CIN const -> magic mul
        int tt2 = t + kk - pad;
        val = (tt2 >= 0 && tt2 < TROWS) ? A[((size_t)(b * TROWS + tt2)) * CIN + ci] : 0.0f;
      }
      As[r][cc] = val;
    }
#pragma unroll
    for (int e = 0; e < 4; ++e) {
      int li = e * 256 + tid;
      int r = li >> 6, cc = li & 63;
      int col = colBase + cc;
      Ws[r][cc] = (col < Cout) ? W[(size_t)(k0 + r) * Cout + col] : 0.0f;
    }
    __syncthreads();
#pragma unroll
    for (int kk2 = 0; kk2 < 16; ++kk2) {
      float av[4], wv[4];
#pragma unroll
      for (int i = 0; i < 4; ++i) av[i] = As[ty * 4 + i][kk2];
#pragma unroll
      for (int j2 = 0; j2 < 4; ++j2) wv[j2] = Ws[kk2][tx * 4 + j2];
#pragma unroll
      for (int i = 0; i < 4; ++i)
#pragma unroll
        for (int j2 = 0; j2 < 4; ++j2) acc[i][j2] += av[i] * wv[j2];
    }
    __syncthreads();
  }
#pragma unroll
  for (int i = 0; i < 4; ++i) {
    int row = rowBase + ty * 4 + i;
#pragma unroll
    for (int j2 = 0; j2 < 4; ++j2) {
      int col = colBase + tx * 4 + j2;
      if (col < Cout) {
        float v = acc[i][j2] + (bias ? bias[col] : 0.0f);
        if (doRelu) v = fmaxf(v, 0.0f);
        C[(size_t)row * Cout + col] = v;
      }
    }
  }
}

// ---------------------------------------------------------------------------
// Attention: one block per (q, h, b). scores in LDS, softmax, PV.
// Q/K/V layout: [B*T, H*DH] with head h at cols h*64..h*64+63
// ---------------------------------------------------------------------------
__global__ __launch_bounds__(256) void attn_kernel(
    const float* __restrict__ Qb, const float* __restrict__ Kb,
    const float* __restrict__ Vb, const float* __restrict__ maskadd,
    float* __restrict__ Ob, int T) {
  const int q = blockIdx.x, h = blockIdx.y, b = blockIdx.z;
  const int tid = threadIdx.x;
  __shared__ __align__(16) float sc[TMEL_C];
  __shared__ __align__(16) float qv[DH_];
  __shared__ float red[256];

  const float* qp = Qb + ((size_t)(b * T + q)) * HD_ + h * DH_;
  if (tid < DH_) qv[tid] = qp[tid];
  __syncthreads();

  float lmax = -INFINITY;
  for (int k = tid; k < T; k += 256) {
    const float4* kp4 = (const float4*)(Kb + ((size_t)(b * T + k)) * HD_ + h * DH_);
    const float4* qv4 = (const float4*)qv;
    float s = 0.0f;
#pragma unroll
    for (int d4 = 0; d4 < DH_ / 4; ++d4) {
      float4 kv = kp4[d4];
      float4 qq = qv4[d4];
      s += qq.x * kv.x + qq.y * kv.y + qq.z * kv.z + qq.w * kv.w;
    }
    s = s * 0.125f + maskadd[(size_t)b * T + k];
    sc[k] = s;
    lmax = fmaxf(lmax, s);
  }
  red[tid] = lmax;
  __syncthreads();
  for (int off = 128; off > 0; off >>= 1) {
    if (tid < off) red[tid] = fmaxf(red[tid], red[tid + off]);
    __syncthreads();
  }
  float gmax = red[0];
  __syncthreads();
  float lsum = 0.0f;
  for (int k = tid; k < T; k += 256) {
    float e = expf(sc[k] - gmax);
    sc[k] = e;
    lsum += e;
  }
  red[tid] = lsum;
  __syncthreads();
  for (int off = 128; off > 0; off >>= 1) {
    if (tid < off) red[tid] += red[tid + off];
    __syncthreads();
  }
  float inv = 1.0f / red[0];
  __syncthreads();

  const int d = tid & 63, c = tid >> 6;  // 4 key-chunks x 64 dims
  float acc = 0.0f;
  for (int k = c; k < T; k += 4)
    acc += sc[k] * Vb[((size_t)(b * T + k)) * HD_ + h * DH_ + d];
  red[tid] = acc;
  __syncthreads();
  if (tid < 64) {
    float o = (red[tid] + red[tid + 64] + red[tid + 128] + red[tid + 192]) * inv;
    Ob[((size_t)(b * T + q)) * HD_ + h * DH_ + tid] = o;
  }
}

// ---------------------------------------------------------------------------
// Y[row,:] = LN(X[row,:] + (Hh ? Hh[row,:] : 0)) * g + b    (D=384, 128 thr)
// Safe for Y aliasing X or Hh (row-local).
// ---------------------------------------------------------------------------
__global__ __launch_bounds__(128) void add_ln_kernel(
    const float* __restrict__ X, const float* __restrict__ Hh,
    const float* __restrict__ g, const float* __restrict__ bb,
    float* __restrict__ Y) {
  const int row = blockIdx.x;
  const int tid = threadIdx.x;
  __shared__ float red[128];
  float v[3];
  float s = 0.0f;
#pragma unroll
  for (int e = 0; e < 3; ++e) {
    int d = tid + e * 128;
    float x = X[(size_t)row * D_ + d];
    if (Hh) x += Hh[(size_t)row * D_ + d];
    v[e] = x;
    s += x;
  }
  red[tid] = s;
  __syncthreads();
  for (int off = 64; off > 0; off >>= 1) {
    if (tid < off) red[tid] += red[tid + off];
    __syncthreads();
  }
  float mean = red[0] / (float)D_;
  __syncthreads();
  float s2 = 0.0f;
#pragma unroll
  for (int e = 0; e < 3; ++e) {
    float dd = v[e] - mean;
    s2 += dd * dd;
  }
  red[tid] = s2;
  __syncthreads();
  for (int off = 64; off > 0; off >>= 1) {
    if (tid < off) red[tid] += red[tid + off];
    __syncthreads();
  }
  float invstd = rsqrtf(red[0] / (float)D_ + 1e-5f);
  __syncthreads();
#pragma unroll
  for (int e = 0; e < 3; ++e) {
    int d = tid + e * 128;
    Y[(size_t)row * D_ + d] = (v[e] - mean) * invstd * g[d] + bb[d];
  }
}

// ---------------------------------------------------------------------------
// Duration predictor head: lp[row] = dot(Hh[row,:], w) + b0
// ---------------------------------------------------------------------------
__global__ __launch_bounds__(64) void dp_linear_kernel(
    const float* __restrict__ Hh, const float* __restrict__ w,
    const float* __restrict__ b0, float* __restrict__ lp) {
  const int row = blockIdx.x;
  const int tid = threadIdx.x;
  float s = 0.0f;
  for (int d = tid; d < D_; d += 64) s += Hh[(size_t)row * D_ + d] * w[d];
#pragma unroll
  for (int off = 32; off > 0; off >>= 1) s += __shfl_down(s, off);
  if (tid == 0) lp[row] = s + b0[0];
}

// ---------------------------------------------------------------------------
// Length regulator
// ---------------------------------------------------------------------------
__global__ void lr_scan_kernel(const int* __restrict__ dur, int* __restrict__ cs,
                               int* __restrict__ mel) {
  int b = blockIdx.x;
  if (threadIdx.x == 0) {
    int s = 0;
    for (int t = 0; t < T_; ++t) {
      s += dur[b * T_ + t];
      cs[b * T_ + t] = s;
    }
    mel[b] = s;
  }
}

__global__ __launch_bounds__(256) void lr_build_kernel(
    const int* __restrict__ cs, const int* __restrict__ mel,
    int* __restrict__ idx, float* __restrict__ maskd) {
  int b = blockIdx.x;
  int mlen = mel[b];
  for (int m = threadIdx.x; m < TMEL_C; m += 256) {
    int t = -1;
    if (m < mlen) {
      int lo = 0, hi = T_ - 1;
      while (lo < hi) {
        int mid = (lo + hi) >> 1;
        if (cs[b * T_ + mid] > m) hi = mid; else lo = mid + 1;
      }
      t = lo;
    }
    idx[b * TMEL_C + m] = t;
    maskd[b * TMEL_C + m] = (m > mlen) ? -INFINITY : 0.0f;
  }
}

__global__ __launch_bounds__(128) void lr_gather_kernel(
    const float* __restrict__ XE, const int* __restrict__ idx,
    float* __restrict__ XD) {
  int row = blockIdx.x;  // b*TMEL + m
  int b = row / TMEL_C;
  int t = idx[row];
  for (int d = threadIdx.x; d < D_; d += 128)
    XD[(size_t)row * D_ + d] = (t >= 0) ? XE[((size_t)(b * T_ + t)) * D_ + d] : 0.0f;
}

// ---------------------------------------------------------------------------
// Final projection, transposed write: out[b, o, m] = dot(Xd[b,m,:], Wo[:,o]) + bo[o]
// ---------------------------------------------------------------------------
__global__ __launch_bounds__(128) void final_out_kernel(
    const float* __restrict__ Xd, const float* __restrict__ Wo,
    const float* __restrict__ bo, float* __restrict__ out) {
  const int m = blockIdx.x, b = blockIdx.y;
  const int tid = threadIdx.x;
  __shared__ float xr[D_];
  for (int d = tid; d < D_; d += 128) xr[d] = Xd[((size_t)(b * TMEL_C + m)) * D_ + d];
  __syncthreads();
  if (tid < OUT_C) {
    float s = bo[tid];
    for (int d = 0; d < D_; ++d) s += xr[d] * Wo[(size_t)d * OUT_C + tid];
    out[((size_t)(b * OUT_C + tid)) * TMEL_C + m] = s;
  }
}

// ---------------------------------------------------------------------------
// Host side
// ---------------------------------------------------------------------------
struct LayerW {
  const float *wq, *wk, *wv, *wo, *g1, *b1, *c1w, *c1b, *c2w, *c2b, *g2, *b2;
};

static void launch_layer(float* Xio, float* YT, float* Qb, float* Kb, float* Vb,
                         float* Ob, float* MID, const float* maskadd, int Trows,
                         const LayerW& w, hipStream_t stream) {
  const int BT = B_ * Trows;
  dim3 blk(256);
  dim3 gP(D_ / 64, BT / 64);
  // QKV + attention + out proj
  gemm_conv_kernel<D_, 1, T_><<<gP, blk, 0, stream>>>(Xio, w.wq, nullptr, Qb, D_, 0);
  gemm_conv_kernel<D_, 1, T_><<<gP, blk, 0, stream>>>(Xio, w.wk, nullptr, Kb, D_, 0);
  gemm_conv_kernel<D_, 1, T_><<<gP, blk, 0, stream>>>(Xio, w.wv, nullptr, Vb, D_, 0);
  attn_kernel<<<dim3(Trows, H_, B_), blk, 0, stream>>>(Qb, Kb, Vb, maskadd, Ob, Trows);
  gemm_conv_kernel<D_, 1, T_><<<gP, blk, 0, stream>>>(Ob, w.wo, nullptr, Qb, D_, 0);
  add_ln_kernel<<<BT, 128, 0, stream>>>(Xio, Qb, w.g1, w.b1, YT);
  // conv block (MID aliases Qb..Ob span; all dead by now)
  if (Trows == T_) {
    gemm_conv_kernel<D_, KC_, T_><<<dim3(INTER_C / 64, BT / 64), blk, 0, stream>>>(
        YT, w.c1w, w.c1b, MID, INTER_C, 1);
    gemm_conv_kernel<INTER_C, KC_, T_><<<gP, blk, 0, stream>>>(MID, w.c2w, w.c2b, Xio, D_, 0);
  } else {
    gemm_conv_kernel<D_, KC_, TMEL_C><<<dim3(INTER_C / 64, BT / 64), blk, 0, stream>>>(
        YT, w.c1w, w.c1b, MID, INTER_C, 1);
    gemm_conv_kernel<INTER_C, KC_, TMEL_C><<<gP, blk, 0, stream>>>(MID, w.c2w, w.c2b, Xio, D_, 0);
  }
  add_ln_kernel<<<BT, 128, 0, stream>>>(YT, Xio, w.g2, w.b2, Xio);
}

extern "C" void kernel_launch(void* const* d_in, const int* in_sizes, int n_in,
                              void* d_out, int out_size, void* d_ws, size_t ws_size,
                              hipStream_t stream) {
  const int* tokens = (const int*)d_in[0];
  const int* token_lengths = (const int*)d_in[1];
  const int* durations = (const int*)d_in[2];
  const float* emb = (const float*)d_in[3];
  const float* encw[12];
  const float* decw[12];
  for (int i = 0; i < 12; ++i) encw[i] = (const float*)d_in[4 + i];
  for (int i = 0; i < 12; ++i) decw[i] = (const float*)d_in[16 + i];
  const float* dp_c1w = (const float*)d_in[28];
  const float* dp_c1b = (const float*)d_in[29];
  const float* dp_ln1g = (const float*)d_in[30];
  const float* dp_ln1b = (const float*)d_in[31];
  const float* dp_c2w = (const float*)d_in[32];
  const float* dp_c2b = (const float*)d_in[33];
  const float* dp_ln2g = (const float*)d_in[34];
  const float* dp_ln2b = (const float*)d_in[35];
  const float* dp_w = (const float*)d_in[36];
  const float* dp_b = (const float*)d_in[37];
  const float* out_w = (const float*)d_in[38];
  const float* out_b = (const float*)d_in[39];

  float* out0 = (float*)d_out;                       // [B, OUT, TMEL]
  float* out_lp = out0 + (size_t)B_ * OUT_C * TMEL_C;  // [B, T]

  // workspace layout
  float* ws = (float*)d_ws;
  size_t off = 0;
  auto alloc = [&](size_t n) { float* p = ws + off; off += n; return p; };
  float* XE = alloc((size_t)B_ * T_ * D_);
  float* XD = alloc((size_t)B_ * TMEL_C * D_);
  float* YT = alloc((size_t)B_ * TMEL_C * D_);
  float* MID = alloc((size_t)B_ * TMEL_C * INTER_C);  // spans Qb..Ob exactly (4x B*TMEL*D)
  float* Qb = MID;
  float* Kb = MID + (size_t)B_ * TMEL_C * D_;
  float* Vb = Kb + (size_t)B_ * TMEL_C * D_;
  float* Ob = Vb + (size_t)B_ * TMEL_C * D_;
  float* MASKE = alloc(B_ * T_);
  float* MASKD = alloc(B_ * TMEL_C);
  int* CS = (int*)alloc(B_ * T_);
  int* MEL = (int*)alloc(B_);
  int* IDX = (int*)alloc(B_ * TMEL_C);

  // 1) embed + PE, encoder mask
  embed_kernel<<<(B_ * T_ * D_ + 255) / 256, 256, 0, stream>>>(tokens, emb, XE);
  enc_mask_kernel<<<(B_ * T_ + 255) / 256, 256, 0, stream>>>(token_lengths, MASKE);

  // 2) encoder stack
  for (int i = 0; i < L_; ++i) {
    LayerW w;
    w.wq = encw[0] + (size_t)i * D_ * HD_;
    w.wk = encw[1] + (size_t)i * D_ * HD_;
    w.wv = encw[2] + (size_t)i * D_ * HD_;
    w.wo = encw[3] + (size_t)i * HD_ * D_;
    w.g1 = encw[4] + (size_t)i * D_;
    w.b1 = encw[5] + (size_t)i * D_;
    w.c1w = encw[6] + (size_t)i * KC_ * D_ * INTER_C;
    w.c1b = encw[7] + (size_t)i * INTER_C;
    w.c2w = encw[8] + (size_t)i * KC_ * INTER_C * D_;
    w.c2b = encw[9] + (size_t)i * D_;
    w.g2 = encw[10] + (size_t)i * D_;
    w.b2 = encw[11] + (size_t)i * D_;
    launch_layer(XE, YT, Qb, Kb, Vb, Ob, MID, MASKE, T_, w, stream);
  }

  // 3) duration predictor -> length_predictions output
  {
    const int BT = B_ * T_;
    dim3 blk(256);
    dim3 gP(D_ / 64, BT / 64);
    gemm_conv_kernel<D_, KC_, T_><<<gP, blk, 0, stream>>>(XE, dp_c1w, dp_c1b, MID, D_, 1);
    add_ln_kernel<<<BT, 128, 0, stream>>>(MID, nullptr, dp_ln1g, dp_ln1b, YT);
    gemm_conv_kernel<D_, KC_, T_><<<gP, blk, 0, stream>>>(YT, dp_c2w, dp_c2b, MID, D_, 1);
    add_ln_kernel<<<BT, 128, 0, stream>>>(MID, nullptr, dp_ln2g, dp_ln2b, YT);
    dp_linear_kernel<<<BT, 64, 0, stream>>>(YT, dp_w, dp_b, out_lp);
  }

  // 4) length regulator -> XD, decoder mask
  lr_scan_kernel<<<B_, 32, 0, stream>>>(durations, CS, MEL);
  lr_build_kernel<<<B_, 256, 0, stream>>>(CS, MEL, IDX, MASKD);
  lr_gather_kernel<<<B_ * TMEL_C, 128, 0, stream>>>(XE, IDX, XD);

  // 5) decoder stack
  for (int i = 0; i < L_; ++i) {
    LayerW w;
    w.wq = decw[0] + (size_t)i * D_ * HD_;
    w.wk = decw[1] + (size_t)i * D_ * HD_;
    w.wv = decw[2] + (size_t)i * D_ * HD_;
    w.wo = decw[3] + (size_t)i * HD_ * D_;
    w.g1 = decw[4] + (size_t)i * D_;
    w.b1 = decw[5] + (size_t)i * D_;
    w.c1w = decw[6] + (size_t)i * KC_ * D_ * INTER_C;
    w.c1b = decw[7] + (size_t)i * INTER_C;
    w.c2w = decw[8] + (size_t)i * KC_ * INTER_C * D_;
    w.c2b = decw[9] + (size_t)i * D_;
    w.g2 = decw[10] + (size_t)i * D_;
    w.b2 = decw[11] + (size_t)i * D_;
    launch_layer(XD, YT, Qb, Kb, Vb, Ob, MID, MASKD, TMEL_C, w, stream);
  }

  // 6) final projection (transposed write)
  final_out_kernel<<<dim3(TMEL_C, B_), 128, 0, stream>>>(XD, out_w, out_b, out0);
}

// Round 2
// 12922.803 us; speedup vs baseline: 1.8779x; 1.8779x over previous
//
#include <hip/hip_runtime.h>
#include <math.h>

// ---- problem constants ----
constexpr int B_ = 8;
constexpr int T_ = 128;
constexpr int D_ = 384;
constexpr int H_ = 6;
constexpr int DH_ = 64;
constexpr int L_ = 4;
constexpr int INTER_C = 1536;
constexpr int KC_ = 3;
constexpr int OUT_C = 80;
constexpr int TMEL_C = 1024;   // T * MAXDUR
constexpr int HD_ = H_ * DH_;  // 384

// ---------------------------------------------------------------------------
// Embedding + positional encoding:  x[b,t,d] = 2*emb[tok[b,t],d] + pe(b,d)
// (reference quirk: PE indexed by BATCH index, broadcast over time)
// ---------------------------------------------------------------------------
__global__ __launch_bounds__(256) void embed_kernel(
    const int* __restrict__ tokens, const float* __restrict__ emb,
    float* __restrict__ X) {
  int i = blockIdx.x * 256 + threadIdx.x;
  if (i >= B_ * T_ * D_) return;
  int d = i % D_;
  int bt = i / D_;
  int b = bt / T_;
  int tok = tokens[bt];
  int i2 = d & ~1;
  const float c = 9.210340371976184f / (float)D_;  // ln(10000)/D
  float freq = expf(-(float)i2 * c);
  float ang = (float)b * freq;
  float pe = (d & 1) ? cosf(ang) : sinf(ang);
  X[i] = 2.0f * emb[(size_t)tok * D_ + d] + pe;
}

// ---------------------------------------------------------------------------
// Encoder key mask: maske[b,t] = (t > token_lengths[b]) ? -inf : 0
// ---------------------------------------------------------------------------
__global__ void enc_mask_kernel(const int* __restrict__ tl, float* __restrict__ maske) {
  int i = blockIdx.x * 256 + threadIdx.x;
  if (i >= B_ * T_) return;
  int b = i / T_, t = i % T_;
  maske[i] = (t > tl[b]) ? -INFINITY : 0.0f;
}

// ---------------------------------------------------------------------------
// Generic tiled GEMM / K=3 SAME conv (im2col on the fly).
// ---------------------------------------------------------------------------
template <int CIN, int KCt, int TROWS>
__global__ __launch_bounds__(256) void gemm_conv_kernel(
    const float* __restrict__ A, const float* __restrict__ W,
    const float* __restrict__ bias, float* __restrict__ C,
    int Cout, int doRelu) {
  __shared__ float As[64][17];
  __shared__ float Ws[16][65];
  const int tid = threadIdx.x;
  const int tx = tid & 15, ty = tid >> 4;
  const int rowBase = blockIdx.y * 64;
  const int colBase = blockIdx.x * 64;
  constexpr int Ktot = CIN * KCt;
  constexpr int pad = KCt / 2;
  float acc[4][4] = {};
  for (int k0 = 0; k0 < Ktot; k0 += 16) {
#pragma unroll
    for (int e = 0; e < 4; ++e) {
      int li = e * 256 + tid;
      int r = li >> 4, cc = li & 15;
      int row = rowBase + r;
      int j = k0 + cc;
      float val;
      if constexpr (KCt == 1) {
        val = A[(size_t)row * CIN + j];
      } else {
        int b = row / TROWS, t = row % TROWS;
        int kk = j / CIN, ci = j % CIN;
        int tt2 = t + kk - pad;
        val = (tt2 >= 0 && tt2 < TROWS) ? A[((size_t)(b * TROWS + tt2)) * CIN + ci] : 0.0f;
      }
      As[r][cc] = val;
    }
#pragma unroll
    for (int e = 0; e < 4; ++e) {
      int li = e * 256 + tid;
      int r = li >> 6, cc = li & 63;
      int col = colBase + cc;
      Ws[r][cc] = (col < Cout) ? W[(size_t)(k0 + r) * Cout + col] : 0.0f;
    }
    __syncthreads();
#pragma unroll
    for (int kk2 = 0; kk2 < 16; ++kk2) {
      float av[4], wv[4];
#pragma unroll
      for (int i = 0; i < 4; ++i) av[i] = As[ty * 4 + i][kk2];
#pragma unroll
      for (int j2 = 0; j2 < 4; ++j2) wv[j2] = Ws[kk2][tx * 4 + j2];
#pragma unroll
      for (int i = 0; i < 4; ++i)
#pragma unroll
        for (int j2 = 0; j2 < 4; ++j2) acc[i][j2] += av[i] * wv[j2];
    }
    __syncthreads();
  }
#pragma unroll
  for (int i = 0; i < 4; ++i) {
    int row = rowBase + ty * 4 + i;
#pragma unroll
    for (int j2 = 0; j2 < 4; ++j2) {
      int col = colBase + tx * 4 + j2;
      if (col < Cout) {
        float v = acc[i][j2] + (bias ? bias[col] : 0.0f);
        if (doRelu) v = fmaxf(v, 0.0f);
        C[(size_t)row * Cout + col] = v;
      }
    }
  }
}

// ---------------------------------------------------------------------------
// Flash-style tiled attention.
// Block = (32-query tile, head h, batch b), 256 threads.
// Per K-tile (64 keys): stage K^T and V in LDS (coalesced), compute S tile
// 32x64 register-blocked (2 rows x 4 cols per thread), online softmax,
// accumulate O in registers.
// ---------------------------------------------------------------------------
constexpr int QB_ = 32;
constexpr int KB_ = 64;

__global__ __launch_bounds__(256) void attn2_kernel(
    const float* __restrict__ Qb, const float* __restrict__ Kb,
    const float* __restrict__ Vb, const float* __restrict__ maskadd,
    float* __restrict__ Ob, int T) {
  const int qt = blockIdx.x, h = blockIdx.y, b = blockIdx.z;
  const int tid = threadIdx.x;
  const int tx = tid & 15, ty = tid >> 4;

  __shared__ float QsT[DH_][QB_ + 2];  // [d][q]  pitch 34 (float2-aligned reads)
  __shared__ float KsT[DH_][KB_ + 1];  // [d][k]  pitch 65 (odd -> 2-way max)
  __shared__ float Vs[KB_][DH_];       // [k][d]  pitch 64 (float4 reads ok)
  __shared__ float Ps[QB_][KB_ + 1];   // pitch 65
  __shared__ float redm[QB_][17];
  __shared__ float rowm[QB_], rowl[QB_], rowsc[QB_];

  const int q0 = qt * QB_;
  const size_t baseQ = ((size_t)(b * T + q0)) * HD_ + h * DH_;
  for (int e = tid; e < QB_ * DH_; e += 256) {
    int q = e >> 6, d = e & 63;  // consecutive lanes -> consecutive d (coalesced)
    QsT[d][q] = Qb[baseQ + (size_t)q * HD_ + d];
  }
  if (tid < QB_) { rowm[tid] = -INFINITY; rowl[tid] = 0.0f; }

  float oacc[2][4] = {};
  const int r0 = 2 * ty, c0 = 4 * tx;
  __syncthreads();

  for (int k0 = 0; k0 < T; k0 += KB_) {
    // ---- stage K (transposed) and V ----
    const size_t baseK = ((size_t)(b * T + k0)) * HD_ + h * DH_;
    for (int e = tid; e < KB_ * DH_; e += 256) {
      int kk = e >> 6, d = e & 63;
      KsT[d][kk] = Kb[baseK + (size_t)kk * HD_ + d];
      Vs[kk][d] = Vb[baseK + (size_t)kk * HD_ + d];
    }
    __syncthreads();

    // ---- S = Q K^T tile (2x4 per thread) ----
    float sacc[2][4] = {};
#pragma unroll 4
    for (int d = 0; d < DH_; ++d) {
      float2 qq = *(const float2*)&QsT[d][r0];
      float kv[4];
#pragma unroll
      for (int j = 0; j < 4; ++j) kv[j] = KsT[d][c0 + j];
#pragma unroll
      for (int j = 0; j < 4; ++j) {
        sacc[0][j] += qq.x * kv[j];
        sacc[1][j] += qq.y * kv[j];
      }
    }
    // scale + mask, per-thread row max
    float pmax[2] = {-INFINITY, -INFINITY};
#pragma unroll
    for (int i = 0; i < 2; ++i)
#pragma unroll
      for (int j = 0; j < 4; ++j) {
        float s = sacc[i][j] * 0.125f + maskadd[(size_t)b * T + k0 + c0 + j];
        sacc[i][j] = s;
        pmax[i] = fmaxf(pmax[i], s);
      }
    redm[r0][tx] = pmax[0];
    redm[r0 + 1][tx] = pmax[1];
    __syncthreads();
    if (tid < QB_) {
      float tm = -INFINITY;
#pragma unroll
      for (int u = 0; u < 16; ++u) tm = fmaxf(tm, redm[tid][u]);
      float mo = rowm[tid];
      float mn = fmaxf(mo, tm);
      float sc = expf(mo - mn);  // expf(-inf)=0 handles first tile
      rowm[tid] = mn;
      rowsc[tid] = sc;
      rowl[tid] *= sc;
    }
    __syncthreads();

    // rescale O, compute P = exp(s-m), partial row sums
    float psum[2] = {0.0f, 0.0f};
#pragma unroll
    for (int i = 0; i < 2; ++i) {
      float sc = rowsc[r0 + i];
      float m = rowm[r0 + i];
#pragma unroll
      for (int j = 0; j < 4; ++j) {
        oacc[i][j] *= sc;
        float p = expf(sacc[i][j] - m);
        Ps[r0 + i][c0 + j] = p;
        psum[i] += p;
      }
    }
    redm[r0][tx] = psum[0];
    redm[r0 + 1][tx] = psum[1];
    __syncthreads();
    if (tid < QB_) {
      float s = 0.0f;
#pragma unroll
      for (int u = 0; u < 16; ++u) s += redm[tid][u];
      rowl[tid] += s;
    }

    // ---- O += P V ----
#pragma unroll 4
    for (int kk = 0; kk < KB_; ++kk) {
      float p0 = Ps[r0][kk], p1 = Ps[r0 + 1][kk];
      float4 vv = *(const float4*)&Vs[kk][c0];
      oacc[0][0] += p0 * vv.x; oacc[0][1] += p0 * vv.y;
      oacc[0][2] += p0 * vv.z; oacc[0][3] += p0 * vv.w;
      oacc[1][0] += p1 * vv.x; oacc[1][1] += p1 * vv.y;
      oacc[1][2] += p1 * vv.z; oacc[1][3] += p1 * vv.w;
    }
    __syncthreads();  // protect KsT/Vs/redm for next tile; rowl for epilogue
  }

  float inv0 = 1.0f / rowl[r0];
  float inv1 = 1.0f / rowl[r0 + 1];
  size_t o0 = ((size_t)(b * T + q0 + r0)) * HD_ + h * DH_ + c0;
#pragma unroll
  for (int j = 0; j < 4; ++j) {
    Ob[o0 + j] = oacc[0][j] * inv0;
    Ob[o0 + HD_ + j] = oacc[1][j] * inv1;
  }
}

// ---------------------------------------------------------------------------
// Y[row,:] = LN(X[row,:] + (Hh ? Hh[row,:] : 0)) * g + b    (D=384, 128 thr)
// ---------------------------------------------------------------------------
__global__ __launch_bounds__(128) void add_ln_kernel(
    const float* __restrict__ X, const float* __restrict__ Hh,
    const float* __restrict__ g, const float* __restrict__ bb,
    float* __restrict__ Y) {
  const int row = blockIdx.x;
  const int tid = threadIdx.x;
  __shared__ float red[128];
  float v[3];
  float s = 0.0f;
#pragma unroll
  for (int e = 0; e < 3; ++e) {
    int d = tid + e * 128;
    float x = X[(size_t)row * D_ + d];
    if (Hh) x += Hh[(size_t)row * D_ + d];
    v[e] = x;
    s += x;
  }
  red[tid] = s;
  __syncthreads();
  for (int off = 64; off > 0; off >>= 1) {
    if (tid < off) red[tid] += red[tid + off];
    __syncthreads();
  }
  float mean = red[0] / (float)D_;
  __syncthreads();
  float s2 = 0.0f;
#pragma unroll
  for (int e = 0; e < 3; ++e) {
    float dd = v[e] - mean;
    s2 += dd * dd;
  }
  red[tid] = s2;
  __syncthreads();
  for (int off = 64; off > 0; off >>= 1) {
    if (tid < off) red[tid] += red[tid + off];
    __syncthreads();
  }
  float invstd = rsqrtf(red[0] / (float)D_ + 1e-5f);
  __syncthreads();
#pragma unroll
  for (int e = 0; e < 3; ++e) {
    int d = tid + e * 128;
    Y[(size_t)row * D_ + d] = (v[e] - mean) * invstd * g[d] + bb[d];
  }
}

// ---------------------------------------------------------------------------
// Duration predictor head
// ---------------------------------------------------------------------------
__global__ __launch_bounds__(64) void dp_linear_kernel(
    const float* __restrict__ Hh, const float* __restrict__ w,
    const float* __restrict__ b0, float* __restrict__ lp) {
  const int row = blockIdx.x;
  const int tid = threadIdx.x;
  float s = 0.0f;
  for (int d = tid; d < D_; d += 64) s += Hh[(size_t)row * D_ + d] * w[d];
#pragma unroll
  for (int off = 32; off > 0; off >>= 1) s += __shfl_down(s, off);
  if (tid == 0) lp[row] = s + b0[0];
}

// ---------------------------------------------------------------------------
// Length regulator
// ---------------------------------------------------------------------------
__global__ void lr_scan_kernel(const int* __restrict__ dur, int* __restrict__ cs,
                               int* __restrict__ mel) {
  int b = blockIdx.x;
  if (threadIdx.x == 0) {
    int s = 0;
    for (int t = 0; t < T_; ++t) {
      s += dur[b * T_ + t];
      cs[b * T_ + t] = s;
    }
    mel[b] = s;
  }
}

__global__ __launch_bounds__(256) void lr_build_kernel(
    const int* __restrict__ cs, const int* __restrict__ mel,
    int* __restrict__ idx, float* __restrict__ maskd) {
  int b = blockIdx.x;
  int mlen = mel[b];
  for (int m = threadIdx.x; m < TMEL_C; m += 256) {
    int t = -1;
    if (m < mlen) {
      int lo = 0, hi = T_ - 1;
      while (lo < hi) {
        int mid = (lo + hi) >> 1;
        if (cs[b * T_ + mid] > m) hi = mid; else lo = mid + 1;
      }
      t = lo;
    }
    idx[b * TMEL_C + m] = t;
    maskd[b * TMEL_C + m] = (m > mlen) ? -INFINITY : 0.0f;
  }
}

__global__ __launch_bounds__(128) void lr_gather_kernel(
    const float* __restrict__ XE, const int* __restrict__ idx,
    float* __restrict__ XD) {
  int row = blockIdx.x;  // b*TMEL + m
  int b = row / TMEL_C;
  int t = idx[row];
  for (int d = threadIdx.x; d < D_; d += 128)
    XD[(size_t)row * D_ + d] = (t >= 0) ? XE[((size_t)(b * T_ + t)) * D_ + d] : 0.0f;
}

// ---------------------------------------------------------------------------
// Final projection, transposed write
// ---------------------------------------------------------------------------
__global__ __launch_bounds__(128) void final_out_kernel(
    const float* __restrict__ Xd, const float* __restrict__ Wo,
    const float* __restrict__ bo, float* __restrict__ out) {
  const int m = blockIdx.x, b = blockIdx.y;
  const int tid = threadIdx.x;
  __shared__ float xr[D_];
  for (int d = tid; d < D_; d += 128) xr[d] = Xd[((size_t)(b * TMEL_C + m)) * D_ + d];
  __syncthreads();
  if (tid < OUT_C) {
    float s = bo[tid];
    for (int d = 0; d < D_; ++d) s += xr[d] * Wo[(size_t)d * OUT_C + tid];
    out[((size_t)(b * OUT_C + tid)) * TMEL_C + m] = s;
  }
}

// ---------------------------------------------------------------------------
// Host side
// ---------------------------------------------------------------------------
struct LayerW {
  const float *wq, *wk, *wv, *wo, *g1, *b1, *c1w, *c1b, *c2w, *c2b, *g2, *b2;
};

static void launch_layer(float* Xio, float* YT, float* Qb, float* Kb, float* Vb,
                         float* Ob, float* MID, const float* maskadd, int Trows,
                         const LayerW& w, hipStream_t stream) {
  const int BT = B_ * Trows;
  dim3 blk(256);
  dim3 gP(D_ / 64, BT / 64);
  gemm_conv_kernel<D_, 1, T_><<<gP, blk, 0, stream>>>(Xio, w.wq, nullptr, Qb, D_, 0);
  gemm_conv_kernel<D_, 1, T_><<<gP, blk, 0, stream>>>(Xio, w.wk, nullptr, Kb, D_, 0);
  gemm_conv_kernel<D_, 1, T_><<<gP, blk, 0, stream>>>(Xio, w.wv, nullptr, Vb, D_, 0);
  attn2_kernel<<<dim3(Trows / QB_, H_, B_), blk, 0, stream>>>(Qb, Kb, Vb, maskadd, Ob, Trows);
  gemm_conv_kernel<D_, 1, T_><<<gP, blk, 0, stream>>>(Ob, w.wo, nullptr, Qb, D_, 0);
  add_ln_kernel<<<BT, 128, 0, stream>>>(Xio, Qb, w.g1, w.b1, YT);
  if (Trows == T_) {
    gemm_conv_kernel<D_, KC_, T_><<<dim3(INTER_C / 64, BT / 64), blk, 0, stream>>>(
        YT, w.c1w, w.c1b, MID, INTER_C, 1);
    gemm_conv_kernel<INTER_C, KC_, T_><<<gP, blk, 0, stream>>>(MID, w.c2w, w.c2b, Xio, D_, 0);
  } else {
    gemm_conv_kernel<D_, KC_, TMEL_C><<<dim3(INTER_C / 64, BT / 64), blk, 0, stream>>>(
        YT, w.c1w, w.c1b, MID, INTER_C, 1);
    gemm_conv_kernel<INTER_C, KC_, TMEL_C><<<gP, blk, 0, stream>>>(MID, w.c2w, w.c2b, Xio, D_, 0);
  }
  add_ln_kernel<<<BT, 128, 0, stream>>>(YT, Xio, w.g2, w.b2, Xio);
}

extern "C" void kernel_launch(void* const* d_in, const int* in_sizes, int n_in,
                              void* d_out, int out_size, void* d_ws, size_t ws_size,
                              hipStream_t stream) {
  const int* tokens = (const int*)d_in[0];
  const int* token_lengths = (const int*)d_in[1];
  const int* durations = (const int*)d_in[2];
  const float* emb = (const float*)d_in[3];
  const float* encw[12];
  const float* decw[12];
  for (int i = 0; i < 12; ++i) encw[i] = (const float*)d_in[4 + i];
  for (int i = 0; i < 12; ++i) decw[i] = (const float*)d_in[16 + i];
  const float* dp_c1w = (const float*)d_in[28];
  const float* dp_c1b = (const float*)d_in[29];
  const float* dp_ln1g = (const float*)d_in[30];
  const float* dp_ln1b = (const float*)d_in[31];
  const float* dp_c2w = (const float*)d_in[32];
  const float* dp_c2b = (const float*)d_in[33];
  const float* dp_ln2g = (const float*)d_in[34];
  const float* dp_ln2b = (const float*)d_in[35];
  const float* dp_w = (const float*)d_in[36];
  const float* dp_b = (const float*)d_in[37];
  const float* out_w = (const float*)d_in[38];
  const float* out_b = (const float*)d_in[39];

  float* out0 = (float*)d_out;                         // [B, OUT, TMEL]
  float* out_lp = out0 + (size_t)B_ * OUT_C * TMEL_C;  // [B, T]

  float* ws = (float*)d_ws;
  size_t off = 0;
  auto alloc = [&](size_t n) { float* p = ws + off; off += n; return p; };
  float* XE = alloc((size_t)B_ * T_ * D_);
  float* XD = alloc((size_t)B_ * TMEL_C * D_);
  float* YT = alloc((size_t)B_ * TMEL_C * D_);
  float* MID = alloc((size_t)B_ * TMEL_C * INTER_C);
  float* Qb = MID;
  float* Kb = MID + (size_t)B_ * TMEL_C * D_;
  float* Vb = Kb + (size_t)B_ * TMEL_C * D_;
  float* Ob = Vb + (size_t)B_ * TMEL_C * D_;
  float* MASKE = alloc(B_ * T_);
  float* MASKD = alloc(B_ * TMEL_C);
  int* CS = (int*)alloc(B_ * T_);
  int* MEL = (int*)alloc(B_);
  int* IDX = (int*)alloc(B_ * TMEL_C);

  embed_kernel<<<(B_ * T_ * D_ + 255) / 256, 256, 0, stream>>>(tokens, emb, XE);
  enc_mask_kernel<<<(B_ * T_ + 255) / 256, 256, 0, stream>>>(token_lengths, MASKE);

  for (int i = 0; i < L_; ++i) {
    LayerW w;
    w.wq = encw[0] + (size_t)i * D_ * HD_;
    w.wk = encw[1] + (size_t)i * D_ * HD_;
    w.wv = encw[2] + (size_t)i * D_ * HD_;
    w.wo = encw[3] + (size_t)i * HD_ * D_;
    w.g1 = encw[4] + (size_t)i * D_;
    w.b1 = encw[5] + (size_t)i * D_;
    w.c1w = encw[6] + (size_t)i * KC_ * D_ * INTER_C;
    w.c1b = encw[7] + (size_t)i * INTER_C;
    w.c2w = encw[8] + (size_t)i * KC_ * INTER_C * D_;
    w.c2b = encw[9] + (size_t)i * D_;
    w.g2 = encw[10] + (size_t)i * D_;
    w.b2 = encw[11] + (size_t)i * D_;
    launch_layer(XE, YT, Qb, Kb, Vb, Ob, MID, MASKE, T_, w, stream);
  }

  {
    const int BT = B_ * T_;
    dim3 blk(256);
    dim3 gP(D_ / 64, BT / 64);
    gemm_conv_kernel<D_, KC_, T_><<<gP, blk, 0, stream>>>(XE, dp_c1w, dp_c1b, MID, D_, 1);
    add_ln_kernel<<<BT, 128, 0, stream>>>(MID, nullptr, dp_ln1g, dp_ln1b, YT);
    gemm_conv_kernel<D_, KC_, T_><<<gP, blk, 0, stream>>>(YT, dp_c2w, dp_c2b, MID, D_, 1);
    add_ln_kernel<<<BT, 128, 0, stream>>>(MID, nullptr, dp_ln2g, dp_ln2b, YT);
    dp_linear_kernel<<<BT, 64, 0, stream>>>(YT, dp_w, dp_b, out_lp);
  }

  lr_scan_kernel<<<B_, 32, 0, stream>>>(durations, CS, MEL);
  lr_build_kernel<<<B_, 256, 0, stream>>>(CS, MEL, IDX, MASKD);
  lr_gather_kernel<<<B_ * TMEL_C, 128, 0, stream>>>(XE, IDX, XD);

  for (int i = 0; i < L_; ++i) {
    LayerW w;
    w.wq = decw[0] + (size_t)i * D_ * HD_;
    w.wk = decw[1] + (size_t)i * D_ * HD_;
    w.wv = decw[2] + (size_t)i * D_ * HD_;
    w.wo = decw[3] + (size_t)i * HD_ * D_;
    w.g1 = decw[4] + (size_t)i * D_;
    w.b1 = decw[5] + (size_t)i * D_;
    w.c1w = decw[6] + (size_t)i * KC_ * D_ * INTER_C;
    w.c1b = decw[7] + (size_t)i * INTER_C;
    w.c2w = decw[8] + (size_t)i * KC_ * INTER_C * D_;
    w.c2b = decw[9] + (size_t)i * D_;
    w.g2 = decw[10] + (size_t)i * D_;
    w.b2 = decw[11] + (size_t)i * D_;
    launch_layer(XD, YT, Qb, Kb, Vb, Ob, MID, MASKD, TMEL_C, w, stream);
  }

  final_out_kernel<<<dim3(TMEL_C, B_), 128, 0, stream>>>(XD, out_w, out_b, out0);
}

// Round 3
// 2913.549 us; speedup vs baseline: 8.3291x; 4.4354x over previous
//
#include <hip/hip_runtime.h>
#include <math.h>

typedef __bf16 bf16;
typedef __attribute__((ext_vector_type(8))) __bf16 bf16x8;
typedef __attribute__((ext_vector_type(4))) float f32x4;

// ---- problem constants ----
constexpr int B_ = 8;
constexpr int T_ = 128;
constexpr int D_ = 384;
constexpr int H_ = 6;
constexpr int DH_ = 64;
constexpr int L_ = 4;
constexpr int INTER_ = 1536;
constexpr int OUT_C = 80;
constexpr int TMEL_ = 1024;
constexpr int HD_ = 384;     // H*DH
constexpr int QKV_N = 1152;  // 3*HD

// ===========================================================================
// Embedding + PE (PE indexed by BATCH per reference quirk): x = 2*emb + pe[b]
// Writes fp32 X and padded bf16 Xbf ([B][T+2][D], row t at b*(T+2)+1+t).
// ===========================================================================
__global__ __launch_bounds__(256) void embed_kernel(
    const int* __restrict__ tokens, const float* __restrict__ emb,
    float* __restrict__ X, bf16* __restrict__ Xbf) {
  int i = blockIdx.x * 256 + threadIdx.x;
  if (i >= B_ * T_ * D_) return;
  int d = i % D_;
  int bt = i / D_;
  int b = bt / T_, t = bt % T_;
  int tok = tokens[bt];
  int i2 = d & ~1;
  const float c = 9.210340371976184f / (float)D_;  // ln(10000)/D
  float freq = expf(-(float)i2 * c);
  float ang = (float)b * freq;
  float pe = (d & 1) ? cosf(ang) : sinf(ang);
  float v = 2.0f * emb[(size_t)tok * D_ + d] + pe;
  X[i] = v;
  Xbf[((size_t)b * (T_ + 2) + 1 + t) * D_ + d] = (bf16)v;
}

__global__ void enc_mask_kernel(const int* __restrict__ tl, float* __restrict__ maske) {
  int i = blockIdx.x * 256 + threadIdx.x;
  if (i >= B_ * T_) return;
  int b = i / T_, t = i % T_;
  maske[i] = (t > tl[b]) ? -INFINITY : 0.0f;
}

// ===========================================================================
// Weight transpose: src fp32 [K][N] (layer z via strides) -> dst bf16
// [N + rowOfs][K] row-major. K,N multiples of 32.
// ===========================================================================
__global__ __launch_bounds__(256) void transpose_w_kernel(
    const float* __restrict__ src, long srcLS, bf16* __restrict__ dst,
    long dstLS, int K, int N, int rowOfs) {
  src += (size_t)blockIdx.z * srcLS;
  dst += (size_t)blockIdx.z * dstLS;
  __shared__ float tile[32][33];
  const int tx = threadIdx.x & 31, ty = threadIdx.x >> 5;
  const int n0 = blockIdx.x * 32, k0 = blockIdx.y * 32;
#pragma unroll
  for (int j = 0; j < 4; ++j)
    tile[ty + j * 8][tx] = src[(size_t)(k0 + ty + j * 8) * N + n0 + tx];
  __syncthreads();
#pragma unroll
  for (int j = 0; j < 4; ++j)
    dst[(size_t)(n0 + rowOfs + ty + j * 8) * K + k0 + tx] = (bf16)tile[tx][ty + j * 8];
}

// Zero the 2 padding rows per batch of a padded bf16 activation buffer.
__global__ void zero_pads_kernel(bf16* buf, int Tp, int C) {
  int b = blockIdx.x >> 1, side = blockIdx.x & 1;
  size_t row = (size_t)b * (Tp + 2) + (side ? (Tp + 1) : 0);
  for (int c = threadIdx.x; c < C; c += 256) buf[row * C + c] = (bf16)0.0f;
}

// ===========================================================================
// MFMA bf16 GEMM, 128x128 tile, BK=64, 4 waves (2x2 of 64x64).
// A: padded bf16 activations [B][TP+2][lda]; output row r=b*TP+t.
// Conv K=3 SAME == plain GEMM over K'=3*lda with abase shifted by -lda (aofs).
// WT: bf16 [N][Ktot] (K-contiguous rows -> B-operand fragments).
// LDS: linear dest for global_load_lds; XOR swizzle (cb ^= row&7) applied to
// the global SOURCE during staging and to the ds_read address (rule 21).
// Outputs: optional fp32 [B*TP][ldc], optional padded bf16 [B][TP+2][ldc].
// ===========================================================================
template <int TP>
__global__ __launch_bounds__(256) void mfma_gemm_kernel(
    const bf16* __restrict__ A, int lda, int aofs,
    const bf16* __restrict__ WT, int Ktot,
    const float* __restrict__ bias, int relu,
    float* __restrict__ Cf, bf16* __restrict__ Cbf, int ldc) {
  __shared__ bf16 As[128 * 64];
  __shared__ bf16 Bs[128 * 64];
  const int tid = threadIdx.x;
  const int lane = tid & 63;
  const int wave = tid >> 6;
  const int wr = wave >> 1, wc = wave & 1;
  const int rowBase = blockIdx.y * 128;
  const int colBase = blockIdx.x * 128;
  const int bb = rowBase / TP;
  const long pr0 = (long)bb * (TP + 2) + 1 + (rowBase - bb * TP);
  const long abase = pr0 * (long)lda - aofs;

  f32x4 acc[4][4] = {};

  for (int k0 = 0; k0 < Ktot; k0 += 64) {
#pragma unroll
    for (int e = 0; e < 4; ++e) {
      int idx = e * 256 + tid;
      int lrow = idx >> 3, cb = idx & 7;
      const bf16* gp = A + abase + (long)lrow * lda + k0 + ((cb ^ (lrow & 7)) << 3);
      __builtin_amdgcn_global_load_lds(
          (const __attribute__((address_space(1))) unsigned int*)gp,
          (__attribute__((address_space(3))) unsigned int*)(As + idx * 8), 16, 0, 0);
    }
#pragma unroll
    for (int e = 0; e < 4; ++e) {
      int idx = e * 256 + tid;
      int lrow = idx >> 3, cb = idx & 7;
      const bf16* gp = WT + (long)(colBase + lrow) * Ktot + k0 + ((cb ^ (lrow & 7)) << 3);
      __builtin_amdgcn_global_load_lds(
          (const __attribute__((address_space(1))) unsigned int*)gp,
          (__attribute__((address_space(3))) unsigned int*)(Bs + idx * 8), 16, 0, 0);
    }
    __syncthreads();
#pragma unroll
    for (int ks = 0; ks < 2; ++ks) {
      bf16x8 af[4], bw[4];
#pragma unroll
      for (int m = 0; m < 4; ++m) {
        int row = wr * 64 + m * 16 + (lane & 15);
        int cb = ((ks << 2) + (lane >> 4)) ^ (row & 7);
        af[m] = *(const bf16x8*)(As + row * 64 + cb * 8);
      }
#pragma unroll
      for (int n = 0; n < 4; ++n) {
        int row = wc * 64 + n * 16 + (lane & 15);
        int cb = ((ks << 2) + (lane >> 4)) ^ (row & 7);
        bw[n] = *(const bf16x8*)(Bs + row * 64 + cb * 8);
      }
#pragma unroll
      for (int m = 0; m < 4; ++m)
#pragma unroll
        for (int n = 0; n < 4; ++n)
          acc[m][n] = __builtin_amdgcn_mfma_f32_16x16x32_bf16(af[m], bw[n], acc[m][n], 0, 0, 0);
    }
    __syncthreads();
  }

  // epilogue: C/D layout col=lane&15, row=(lane>>4)*4+q (m89-verified)
  const int qr = (lane >> 4) * 4;
  const int qc = lane & 15;
#pragma unroll
  for (int m = 0; m < 4; ++m) {
    int lrow = wr * 64 + m * 16 + qr;
#pragma unroll
    for (int n = 0; n < 4; ++n) {
      int gcol = colBase + wc * 64 + n * 16 + qc;
      float bv = bias ? bias[gcol] : 0.0f;
#pragma unroll
      for (int q = 0; q < 4; ++q) {
        float v = acc[m][n][q] + bv;
        if (relu) v = fmaxf(v, 0.0f);
        if (Cf) Cf[(long)(rowBase + lrow + q) * ldc + gcol] = v;
        if (Cbf) Cbf[(pr0 + lrow + q) * ldc + gcol] = (bf16)v;
      }
    }
  }
}

// ===========================================================================
// Flash attention on packed bf16 QKV [B][T+2][1152] (Q|K|V of 384 each).
// Block = (32-query tile, h, b), 256 threads; fp32 compute; bf16 O out
// (padded [B][T+2][384]).
// ===========================================================================
constexpr int QB_ = 32;
constexpr int KB_ = 64;

__global__ __launch_bounds__(256) void attn3_kernel(
    const bf16* __restrict__ QKV, const float* __restrict__ maskadd,
    bf16* __restrict__ Obf, int T) {
  const int qt = blockIdx.x, h = blockIdx.y, b = blockIdx.z;
  const int tid = threadIdx.x;
  const int tx = tid & 15, ty = tid >> 4;

  __shared__ float QsT[DH_][QB_ + 2];
  __shared__ float KsT[DH_][KB_ + 1];
  __shared__ float Vs[KB_][DH_];
  __shared__ float Ps[QB_][KB_ + 1];
  __shared__ float redm[QB_][17];
  __shared__ float rowm[QB_], rowl[QB_], rowsc[QB_];

  const int q0 = qt * QB_;
  const size_t base = ((size_t)b * (T + 2) + 1) * QKV_N + h * DH_;
  {  // stage Q (2048 elems, 8/thread), transpose into QsT
    int q = tid >> 3, dblk = tid & 7;
    bf16x8 v = *(const bf16x8*)(QKV + base + (size_t)(q0 + q) * QKV_N + dblk * 8);
#pragma unroll
    for (int j = 0; j < 8; ++j) QsT[dblk * 8 + j][q] = (float)v[j];
  }
  if (tid < QB_) { rowm[tid] = -INFINITY; rowl[tid] = 0.0f; }

  float oacc[2][4] = {};
  const int r0 = 2 * ty, c0 = 4 * tx;
  __syncthreads();

  for (int k0 = 0; k0 < T; k0 += KB_) {
#pragma unroll
    for (int e = 0; e < 2; ++e) {  // stage K^T and V (4096 elems each)
      int s = e * 256 + tid;
      int kk = s >> 3, dblk = s & 7;
      size_t rp = base + (size_t)(k0 + kk) * QKV_N + dblk * 8;
      bf16x8 kv = *(const bf16x8*)(QKV + rp + 384);
      bf16x8 vv = *(const bf16x8*)(QKV + rp + 768);
#pragma unroll
      for (int j = 0; j < 8; ++j) {
        KsT[dblk * 8 + j][kk] = (float)kv[j];
        Vs[kk][dblk * 8 + j] = (float)vv[j];
      }
    }
    __syncthreads();

    float sacc[2][4] = {};
#pragma unroll 4
    for (int d = 0; d < DH_; ++d) {
      float2 qq = *(const float2*)&QsT[d][r0];
      float kv[4];
#pragma unroll
      for (int j = 0; j < 4; ++j) kv[j] = KsT[d][c0 + j];
#pragma unroll
      for (int j = 0; j < 4; ++j) {
        sacc[0][j] += qq.x * kv[j];
        sacc[1][j] += qq.y * kv[j];
      }
    }
    float pmax[2] = {-INFINITY, -INFINITY};
#pragma unroll
    for (int i = 0; i < 2; ++i)
#pragma unroll
      for (int j = 0; j < 4; ++j) {
        float s = sacc[i][j] * 0.125f + maskadd[(size_t)b * T + k0 + c0 + j];
        sacc[i][j] = s;
        pmax[i] = fmaxf(pmax[i], s);
      }
    redm[r0][tx] = pmax[0];
    redm[r0 + 1][tx] = pmax[1];
    __syncthreads();
    if (tid < QB_) {
      float tm = -INFINITY;
#pragma unroll
      for (int u = 0; u < 16; ++u) tm = fmaxf(tm, redm[tid][u]);
      float mo = rowm[tid];
      float mn = fmaxf(mo, tm);
      float sc = expf(mo - mn);
      rowm[tid] = mn;
      rowsc[tid] = sc;
      rowl[tid] *= sc;
    }
    __syncthreads();

    float psum[2] = {0.0f, 0.0f};
#pragma unroll
    for (int i = 0; i < 2; ++i) {
      float sc = rowsc[r0 + i];
      float m = rowm[r0 + i];
#pragma unroll
      for (int j = 0; j < 4; ++j) {
        oacc[i][j] *= sc;
        float p = expf(sacc[i][j] - m);
        Ps[r0 + i][c0 + j] = p;
        psum[i] += p;
      }
    }
    redm[r0][tx] = psum[0];
    redm[r0 + 1][tx] = psum[1];
    __syncthreads();
    if (tid < QB_) {
      float s = 0.0f;
#pragma unroll
      for (int u = 0; u < 16; ++u) s += redm[tid][u];
      rowl[tid] += s;
    }

#pragma unroll 4
    for (int kk = 0; kk < KB_; ++kk) {
      float p0 = Ps[r0][kk], p1 = Ps[r0 + 1][kk];
      float4 vv = *(const float4*)&Vs[kk][c0];
      oacc[0][0] += p0 * vv.x; oacc[0][1] += p0 * vv.y;
      oacc[0][2] += p0 * vv.z; oacc[0][3] += p0 * vv.w;
      oacc[1][0] += p1 * vv.x; oacc[1][1] += p1 * vv.y;
      oacc[1][2] += p1 * vv.z; oacc[1][3] += p1 * vv.w;
    }
    __syncthreads();
  }

  float inv0 = 1.0f / rowl[r0];
  float inv1 = 1.0f / rowl[r0 + 1];
  size_t o0 = ((size_t)b * (T + 2) + 1 + q0 + r0) * D_ + h * DH_ + c0;
#pragma unroll
  for (int j = 0; j < 4; ++j) {
    Obf[o0 + j] = (bf16)(oacc[0][j] * inv0);
    Obf[o0 + D_ + j] = (bf16)(oacc[1][j] * inv1);
  }
}

// ===========================================================================
// Y = LN(X + Hh) * g + b. Writes fp32 Yf and optional padded bf16 Ybf.
// tshift: log2(Tp) for padded-row computation.
// ===========================================================================
__global__ __launch_bounds__(128) void add_ln_kernel(
    const float* __restrict__ X, const float* __restrict__ Hh,
    const float* __restrict__ g, const float* __restrict__ bb,
    float* __restrict__ Yf, bf16* __restrict__ Ybf, int tshift) {
  const int row = blockIdx.x;
  const int tid = threadIdx.x;
  __shared__ float red[128];
  float v[3];
  float s = 0.0f;
#pragma unroll
  for (int e = 0; e < 3; ++e) {
    int d = tid + e * 128;
    float x = X[(size_t)row * D_ + d];
    if (Hh) x += Hh[(size_t)row * D_ + d];
    v[e] = x;
    s += x;
  }
  red[tid] = s;
  __syncthreads();
  for (int off = 64; off > 0; off >>= 1) {
    if (tid < off) red[tid] += red[tid + off];
    __syncthreads();
  }
  float mean = red[0] / (float)D_;
  __syncthreads();
  float s2 = 0.0f;
#pragma unroll
  for (int e = 0; e < 3; ++e) {
    float dd = v[e] - mean;
    s2 += dd * dd;
  }
  red[tid] = s2;
  __syncthreads();
  for (int off = 64; off > 0; off >>= 1) {
    if (tid < off) red[tid] += red[tid + off];
    __syncthreads();
  }
  float invstd = rsqrtf(red[0] / (float)D_ + 1e-5f);
  __syncthreads();
  const int b = row >> tshift, t = row & ((1 << tshift) - 1);
  const size_t prow = (size_t)b * ((1 << tshift) + 2) + 1 + t;
#pragma unroll
  for (int e = 0; e < 3; ++e) {
    int d = tid + e * 128;
    float y = (v[e] - mean) * invstd * g[d] + bb[d];
    Yf[(size_t)row * D_ + d] = y;
    if (Ybf) Ybf[prow * D_ + d] = (bf16)y;
  }
}

__global__ __launch_bounds__(64) void dp_linear_kernel(
    const float* __restrict__ Hh, const float* __restrict__ w,
    const float* __restrict__ b0, float* __restrict__ lp) {
  const int row = blockIdx.x;
  const int tid = threadIdx.x;
  float s = 0.0f;
  for (int d = tid; d < D_; d += 64) s += Hh[(size_t)row * D_ + d] * w[d];
#pragma unroll
  for (int off = 32; off > 0; off >>= 1) s += __shfl_down(s, off);
  if (tid == 0) lp[row] = s + b0[0];
}

// ---------------------------------------------------------------------------
// Length regulator
// ---------------------------------------------------------------------------
__global__ void lr_scan_kernel(const int* __restrict__ dur, int* __restrict__ cs,
                               int* __restrict__ mel) {
  int b = blockIdx.x;
  if (threadIdx.x == 0) {
    int s = 0;
    for (int t = 0; t < T_; ++t) {
      s += dur[b * T_ + t];
      cs[b * T_ + t] = s;
    }
    mel[b] = s;
  }
}

__global__ __launch_bounds__(256) void lr_build_kernel(
    const int* __restrict__ cs, const int* __restrict__ mel,
    int* __restrict__ idx, float* __restrict__ maskd) {
  int b = blockIdx.x;
  int mlen = mel[b];
  for (int m = threadIdx.x; m < TMEL_; m += 256) {
    int t = -1;
    if (m < mlen) {
      int lo = 0, hi = T_ - 1;
      while (lo < hi) {
        int mid = (lo + hi) >> 1;
        if (cs[b * T_ + mid] > m) hi = mid; else lo = mid + 1;
      }
      t = lo;
    }
    idx[b * TMEL_ + m] = t;
    maskd[b * TMEL_ + m] = (m > mlen) ? -INFINITY : 0.0f;
  }
}

__global__ __launch_bounds__(128) void lr_gather_kernel(
    const float* __restrict__ XE, const int* __restrict__ idx,
    float* __restrict__ XD, bf16* __restrict__ XDbf) {
  int row = blockIdx.x;  // b*TMEL + m
  int b = row / TMEL_, m = row % TMEL_;
  int t = idx[row];
  size_t prow = ((size_t)b * (TMEL_ + 2) + 1 + m) * D_;
  for (int d = threadIdx.x; d < D_; d += 128) {
    float v = (t >= 0) ? XE[((size_t)(b * T_ + t)) * D_ + d] : 0.0f;
    XD[(size_t)row * D_ + d] = v;
    XDbf[prow + d] = (bf16)v;
  }
}

// ---------------------------------------------------------------------------
// Final projection, transposed write (fp32)
// ---------------------------------------------------------------------------
__global__ __launch_bounds__(128) void final_out_kernel(
    const float* __restrict__ Xd, const float* __restrict__ Wo,
    const float* __restrict__ bo, float* __restrict__ out) {
  const int m = blockIdx.x, b = blockIdx.y;
  const int tid = threadIdx.x;
  __shared__ float xr[D_];
  for (int d = tid; d < D_; d += 128) xr[d] = Xd[((size_t)(b * TMEL_ + m)) * D_ + d];
  __syncthreads();
  if (tid < OUT_C) {
    float s = bo[tid];
    for (int d = 0; d < D_; ++d) s += xr[d] * Wo[(size_t)d * OUT_C + tid];
    out[((size_t)(b * OUT_C + tid)) * TMEL_ + m] = s;
  }
}

// ===========================================================================
// Host
// ===========================================================================
extern "C" void kernel_launch(void* const* d_in, const int* in_sizes, int n_in,
                              void* d_out, int out_size, void* d_ws, size_t ws_size,
                              hipStream_t stream) {
  const int* tokens = (const int*)d_in[0];
  const int* token_lengths = (const int*)d_in[1];
  const int* durations = (const int*)d_in[2];
  const float* emb = (const float*)d_in[3];
  const float* encw[12];
  const float* decw[12];
  for (int i = 0; i < 12; ++i) encw[i] = (const float*)d_in[4 + i];
  for (int i = 0; i < 12; ++i) decw[i] = (const float*)d_in[16 + i];
  const float* dp_c1w = (const float*)d_in[28];
  const float* dp_c1b = (const float*)d_in[29];
  const float* dp_ln1g = (const float*)d_in[30];
  const float* dp_ln1b = (const float*)d_in[31];
  const float* dp_c2w = (const float*)d_in[32];
  const float* dp_c2b = (const float*)d_in[33];
  const float* dp_ln2g = (const float*)d_in[34];
  const float* dp_ln2b = (const float*)d_in[35];
  const float* dp_w = (const float*)d_in[36];
  const float* dp_b = (const float*)d_in[37];
  const float* out_w = (const float*)d_in[38];
  const float* out_b = (const float*)d_in[39];

  float* out0 = (float*)d_out;                       // [B, OUT, TMEL]
  float* out_lp = out0 + (size_t)B_ * OUT_C * TMEL_;  // [B, T]

  // ---- workspace (256B-aligned chunks) ----
  char* wsB = (char*)d_ws;
  size_t off = 0;
  auto alloc = [&](size_t bytes) {
    void* p = wsB + off;
    off = (off + bytes + 255) & ~(size_t)255;
    return p;
  };
  float* XE = (float*)alloc((size_t)B_ * T_ * D_ * 4);
  float* XD = (float*)alloc((size_t)B_ * TMEL_ * D_ * 4);
  float* YT = (float*)alloc((size_t)B_ * TMEL_ * D_ * 4);
  bf16* XEbf = (bf16*)alloc((size_t)B_ * (T_ + 2) * D_ * 2);
  bf16* XDbf = (bf16*)alloc((size_t)B_ * (TMEL_ + 2) * D_ * 2);
  bf16* YTbf = (bf16*)alloc((size_t)B_ * (TMEL_ + 2) * D_ * 2);
  bf16* MIDbf = (bf16*)alloc((size_t)B_ * (TMEL_ + 2) * INTER_ * 2);
  bf16* QKVbf = (bf16*)alloc((size_t)B_ * (TMEL_ + 2) * QKV_N * 2);
  bf16* OBbf = (bf16*)alloc((size_t)B_ * (TMEL_ + 2) * D_ * 2);
  float* OF = (float*)QKVbf;  // fp32 GEMM outputs alias QKVbf (disjoint lifetime)
  bf16* QKVT = (bf16*)alloc((size_t)L_ * QKV_N * D_ * 2);
  bf16* WOT = (bf16*)alloc((size_t)L_ * D_ * D_ * 2);
  bf16* C1T = (bf16*)alloc((size_t)INTER_ * (3 * D_) * 2);
  bf16* C2T = (bf16*)alloc((size_t)D_ * (3 * INTER_) * 2);
  bf16* DP1T = (bf16*)alloc((size_t)D_ * (3 * D_) * 2);
  bf16* DP2T = (bf16*)alloc((size_t)D_ * (3 * D_) * 2);
  float* MASKE = (float*)alloc(B_ * T_ * 4);
  float* MASKD = (float*)alloc(B_ * TMEL_ * 4);
  int* CS = (int*)alloc(B_ * T_ * 4);
  int* MEL = (int*)alloc(B_ * 4);
  int* IDX = (int*)alloc(B_ * TMEL_ * 4);

  auto tw = [&](const float* s, long sls, bf16* d, long dls, int K, int N,
                int ro, int Lz) {
    transpose_w_kernel<<<dim3(N / 32, K / 32, Lz), 256, 0, stream>>>(s, sls, d, dls, K, N, ro);
  };
  auto gemm = [&](int TP, int nT, int mT, const bf16* A, int lda, int aofs,
                  const bf16* WTp, int Ktot, const float* bias, int relu,
                  float* Cf, bf16* Cbf, int ldc) {
    dim3 g(nT, mT);
    if (TP == 128)
      mfma_gemm_kernel<128><<<g, 256, 0, stream>>>(A, lda, aofs, WTp, Ktot, bias, relu, Cf, Cbf, ldc);
    else
      mfma_gemm_kernel<1024><<<g, 256, 0, stream>>>(A, lda, aofs, WTp, Ktot, bias, relu, Cf, Cbf, ldc);
  };

  // run one transformer layer (enc: TP=128, dec: TP=1024)
  auto run_layer = [&](int TP, const float* const* w, int i, float* Xf, bf16* Xbf,
                       const float* mask) {
    const int mT = B_ * TP / 128;
    const int tshift = (TP == 128) ? 7 : 10;
    tw(w[6] + (size_t)i * 3 * D_ * INTER_, 0, C1T, 0, 3 * D_, INTER_, 0, 1);
    tw(w[8] + (size_t)i * 3 * INTER_ * D_, 0, C2T, 0, 3 * INTER_, D_, 0, 1);
    gemm(TP, QKV_N / 128, mT, Xbf, D_, 0, QKVT + (size_t)i * QKV_N * D_, D_,
         nullptr, 0, nullptr, QKVbf, QKV_N);
    attn3_kernel<<<dim3(TP / QB_, H_, B_), 256, 0, stream>>>(QKVbf, mask, OBbf, TP);
    gemm(TP, D_ / 128, mT, OBbf, D_, 0, WOT + (size_t)i * D_ * D_, D_,
         nullptr, 0, OF, nullptr, D_);
    add_ln_kernel<<<B_ * TP, 128, 0, stream>>>(Xf, OF, w[4] + (size_t)i * D_,
                                               w[5] + (size_t)i * D_, YT, YTbf, tshift);
    gemm(TP, INTER_ / 128, mT, YTbf, D_, D_, C1T, 3 * D_,
         w[7] + (size_t)i * INTER_, 1, nullptr, MIDbf, INTER_);
    gemm(TP, D_ / 128, mT, MIDbf, INTER_, INTER_, C2T, 3 * INTER_,
         w[9] + (size_t)i * D_, 0, OF, nullptr, D_);
    add_ln_kernel<<<B_ * TP, 128, 0, stream>>>(YT, OF, w[10] + (size_t)i * D_,
                                               w[11] + (size_t)i * D_, Xf, Xbf, tshift);
  };

  // 1) embed + masks + pad zeroing (enc layouts)
  embed_kernel<<<(B_ * T_ * D_ + 255) / 256, 256, 0, stream>>>(tokens, emb, XE, XEbf);
  enc_mask_kernel<<<(B_ * T_ + 255) / 256, 256, 0, stream>>>(token_lengths, MASKE);
  zero_pads_kernel<<<B_ * 2, 256, 0, stream>>>(XEbf, T_, D_);
  zero_pads_kernel<<<B_ * 2, 256, 0, stream>>>(YTbf, T_, D_);
  zero_pads_kernel<<<B_ * 2, 256, 0, stream>>>(MIDbf, T_, INTER_);

  // 2) encoder weights (QKV packed + WO) and stack
  tw(encw[0], (long)D_ * HD_, QKVT, (long)QKV_N * D_, D_, HD_, 0, L_);
  tw(encw[1], (long)D_ * HD_, QKVT, (long)QKV_N * D_, D_, HD_, 384, L_);
  tw(encw[2], (long)D_ * HD_, QKVT, (long)QKV_N * D_, D_, HD_, 768, L_);
  tw(encw[3], (long)HD_ * D_, WOT, (long)D_ * D_, HD_, D_, 0, L_);
  for (int i = 0; i < L_; ++i) run_layer(T_, encw, i, XE, XEbf, MASKE);

  // 3) duration predictor
  tw(dp_c1w, 0, DP1T, 0, 3 * D_, D_, 0, 1);
  tw(dp_c2w, 0, DP2T, 0, 3 * D_, D_, 0, 1);
  gemm(T_, D_ / 128, B_, XEbf, D_, D_, DP1T, 3 * D_, dp_c1b, 1, OF, nullptr, D_);
  add_ln_kernel<<<B_ * T_, 128, 0, stream>>>(OF, nullptr, dp_ln1g, dp_ln1b, YT, YTbf, 7);
  gemm(T_, D_ / 128, B_, YTbf, D_, D_, DP2T, 3 * D_, dp_c2b, 1, OF, nullptr, D_);
  add_ln_kernel<<<B_ * T_, 128, 0, stream>>>(OF, nullptr, dp_ln2g, dp_ln2b, YT, nullptr, 7);
  dp_linear_kernel<<<B_ * T_, 64, 0, stream>>>(YT, dp_w, dp_b, out_lp);

  // 4) length regulator
  lr_scan_kernel<<<B_, 32, 0, stream>>>(durations, CS, MEL);
  lr_build_kernel<<<B_, 256, 0, stream>>>(CS, MEL, IDX, MASKD);
  zero_pads_kernel<<<B_ * 2, 256, 0, stream>>>(XDbf, TMEL_, D_);
  zero_pads_kernel<<<B_ * 2, 256, 0, stream>>>(YTbf, TMEL_, D_);
  zero_pads_kernel<<<B_ * 2, 256, 0, stream>>>(MIDbf, TMEL_, INTER_);
  lr_gather_kernel<<<B_ * TMEL_, 128, 0, stream>>>(XE, IDX, XD, XDbf);

  // 5) decoder weights + stack
  tw(decw[0], (long)D_ * HD_, QKVT, (long)QKV_N * D_, D_, HD_, 0, L_);
  tw(decw[1], (long)D_ * HD_, QKVT, (long)QKV_N * D_, D_, HD_, 384, L_);
  tw(decw[2], (long)D_ * HD_, QKVT, (long)QKV_N * D_, D_, HD_, 768, L_);
  tw(decw[3], (long)HD_ * D_, WOT, (long)D_ * D_, HD_, D_, 0, L_);
  for (int i = 0; i < L_; ++i) run_layer(TMEL_, decw, i, XD, XDbf, MASKD);

  // 6) final projection
  final_out_kernel<<<dim3(TMEL_, B_), 128, 0, stream>>>(XD, out_w, out_b, out0);
}

// Round 4
// 1833.694 us; speedup vs baseline: 13.2340x; 1.5889x over previous
//
#include <hip/hip_runtime.h>
#include <math.h>

typedef __bf16 bf16;
typedef __attribute__((ext_vector_type(8))) __bf16 bf16x8;
typedef __attribute__((ext_vector_type(4))) float f32x4;

// ---- problem constants ----
constexpr int B_ = 8;
constexpr int T_ = 128;
constexpr int D_ = 384;
constexpr int H_ = 6;
constexpr int DH_ = 64;
constexpr int L_ = 4;
constexpr int INTER_ = 1536;
constexpr int OUT_C = 80;
constexpr int TMEL_ = 1024;
constexpr int HD_ = 384;     // H*DH
constexpr int QKV_N = 1152;  // 3*HD

// ===========================================================================
// Embedding + PE (PE indexed by BATCH per reference quirk): x = 2*emb + pe[b]
// ===========================================================================
__global__ __launch_bounds__(256) void embed_kernel(
    const int* __restrict__ tokens, const float* __restrict__ emb,
    float* __restrict__ X, bf16* __restrict__ Xbf) {
  int i = blockIdx.x * 256 + threadIdx.x;
  if (i >= B_ * T_ * D_) return;
  int d = i % D_;
  int bt = i / D_;
  int b = bt / T_, t = bt % T_;
  int tok = tokens[bt];
  int i2 = d & ~1;
  const float c = 9.210340371976184f / (float)D_;  // ln(10000)/D
  float freq = expf(-(float)i2 * c);
  float ang = (float)b * freq;
  float pe = (d & 1) ? cosf(ang) : sinf(ang);
  float v = 2.0f * emb[(size_t)tok * D_ + d] + pe;
  X[i] = v;
  Xbf[((size_t)b * (T_ + 2) + 1 + t) * D_ + d] = (bf16)v;
}

__global__ void enc_mask_kernel(const int* __restrict__ tl, float* __restrict__ maske) {
  int i = blockIdx.x * 256 + threadIdx.x;
  if (i >= B_ * T_) return;
  int b = i / T_, t = i % T_;
  maske[i] = (t > tl[b]) ? -INFINITY : 0.0f;
}

// ===========================================================================
// Weight transpose: src fp32 [K][N] -> dst bf16 [Ndst + rowOfs][K] row-major.
// K multiple of 32. Ndst >= N rows are zero-filled (for padded N like 80->128).
// ===========================================================================
__global__ __launch_bounds__(256) void transpose_w_kernel(
    const float* __restrict__ src, long srcLS, bf16* __restrict__ dst,
    long dstLS, int K, int N, int rowOfs) {
  src += (size_t)blockIdx.z * srcLS;
  dst += (size_t)blockIdx.z * dstLS;
  __shared__ float tile[32][33];
  const int tx = threadIdx.x & 31, ty = threadIdx.x >> 5;
  const int n0 = blockIdx.x * 32, k0 = blockIdx.y * 32;
#pragma unroll
  for (int j = 0; j < 4; ++j)
    tile[ty + j * 8][tx] =
        (n0 + tx < N) ? src[(size_t)(k0 + ty + j * 8) * N + n0 + tx] : 0.0f;
  __syncthreads();
#pragma unroll
  for (int j = 0; j < 4; ++j)
    dst[(size_t)(n0 + rowOfs + ty + j * 8) * K + k0 + tx] = (bf16)tile[tx][ty + j * 8];
}

// Zero the 2 padding rows per batch of a padded bf16 activation buffer.
__global__ void zero_pads_kernel(bf16* buf, int Tp, int C) {
  int b = blockIdx.x >> 1, side = blockIdx.x & 1;
  size_t row = (size_t)b * (Tp + 2) + (side ? (Tp + 1) : 0);
  for (int c = threadIdx.x; c < C; c += 256) buf[row * C + c] = (bf16)0.0f;
}

// ===========================================================================
// V transpose per layer: QKVbf [b][(T+2)][1152] cols 768.. -> VT [b*6+h][64][T]
// ===========================================================================
__global__ __launch_bounds__(256) void transpose_v_kernel(
    const bf16* __restrict__ QKV, bf16* __restrict__ VT, int T) {
  const int tb = blockIdx.x, db = blockIdx.y, bh = blockIdx.z;
  const int b = bh / H_, h = bh % H_;
  __shared__ float tile[32][33];
  const int tx = threadIdx.x & 31, ty = threadIdx.x >> 5;
  const size_t src = ((size_t)b * (T + 2) + 1 + tb * 32) * QKV_N + 768 + h * DH_ + db * 32;
#pragma unroll
  for (int j = 0; j < 4; ++j)
    tile[ty + 8 * j][tx] = (float)QKV[src + (size_t)(ty + 8 * j) * QKV_N + tx];
  __syncthreads();
  const size_t dst = ((size_t)(b * H_ + h) * DH_ + db * 32) * T + tb * 32;
#pragma unroll
  for (int j = 0; j < 4; ++j)
    VT[dst + (size_t)(ty + 8 * j) * T + tx] = (bf16)tile[tx][ty + 8 * j];
}

// ===========================================================================
// MFMA bf16 GEMM, 128x128 tile, BK=64, 4 waves (2x2 of 64x64).
// transC: write fp32 transposed mel output out[(b*OUT_C+col)*TMEL + t], col<80.
// ===========================================================================
template <int TP>
__global__ __launch_bounds__(256) void mfma_gemm_kernel(
    const bf16* __restrict__ A, int lda, int aofs,
    const bf16* __restrict__ WT, int Ktot,
    const float* __restrict__ bias, int relu,
    float* __restrict__ Cf, bf16* __restrict__ Cbf, int ldc, int transC) {
  __shared__ bf16 As[128 * 64];
  __shared__ bf16 Bs[128 * 64];
  const int tid = threadIdx.x;
  const int lane = tid & 63;
  const int wave = tid >> 6;
  const int wr = wave >> 1, wc = wave & 1;
  const int rowBase = blockIdx.y * 128;
  const int colBase = blockIdx.x * 128;
  const int bb = rowBase / TP;
  const long pr0 = (long)bb * (TP + 2) + 1 + (rowBase - bb * TP);
  const long abase = pr0 * (long)lda - aofs;

  f32x4 acc[4][4] = {};

  for (int k0 = 0; k0 < Ktot; k0 += 64) {
#pragma unroll
    for (int e = 0; e < 4; ++e) {
      int idx = e * 256 + tid;
      int lrow = idx >> 3, cb = idx & 7;
      const bf16* gp = A + abase + (long)lrow * lda + k0 + ((cb ^ (lrow & 7)) << 3);
      __builtin_amdgcn_global_load_lds(
          (const __attribute__((address_space(1))) unsigned int*)gp,
          (__attribute__((address_space(3))) unsigned int*)(As + idx * 8), 16, 0, 0);
    }
#pragma unroll
    for (int e = 0; e < 4; ++e) {
      int idx = e * 256 + tid;
      int lrow = idx >> 3, cb = idx & 7;
      const bf16* gp = WT + (long)(colBase + lrow) * Ktot + k0 + ((cb ^ (lrow & 7)) << 3);
      __builtin_amdgcn_global_load_lds(
          (const __attribute__((address_space(1))) unsigned int*)gp,
          (__attribute__((address_space(3))) unsigned int*)(Bs + idx * 8), 16, 0, 0);
    }
    __syncthreads();
#pragma unroll
    for (int ks = 0; ks < 2; ++ks) {
      bf16x8 af[4], bw[4];
#pragma unroll
      for (int m = 0; m < 4; ++m) {
        int row = wr * 64 + m * 16 + (lane & 15);
        int cb = ((ks << 2) + (lane >> 4)) ^ (row & 7);
        af[m] = *(const bf16x8*)(As + row * 64 + cb * 8);
      }
#pragma unroll
      for (int n = 0; n < 4; ++n) {
        int row = wc * 64 + n * 16 + (lane & 15);
        int cb = ((ks << 2) + (lane >> 4)) ^ (row & 7);
        bw[n] = *(const bf16x8*)(Bs + row * 64 + cb * 8);
      }
#pragma unroll
      for (int m = 0; m < 4; ++m)
#pragma unroll
        for (int n = 0; n < 4; ++n)
          acc[m][n] = __builtin_amdgcn_mfma_f32_16x16x32_bf16(af[m], bw[n], acc[m][n], 0, 0, 0);
    }
    __syncthreads();
  }

  const int qr = (lane >> 4) * 4;
  const int qc = lane & 15;
#pragma unroll
  for (int m = 0; m < 4; ++m) {
    int lrow = wr * 64 + m * 16 + qr;
#pragma unroll
    for (int n = 0; n < 4; ++n) {
      int gcol = colBase + wc * 64 + n * 16 + qc;
      float bv = (bias && (!transC || gcol < OUT_C)) ? bias[gcol] : 0.0f;
#pragma unroll
      for (int q = 0; q < 4; ++q) {
        float v = acc[m][n][q] + bv;
        if (relu) v = fmaxf(v, 0.0f);
        if (transC) {
          if (gcol < OUT_C)
            Cf[((long)bb * OUT_C + gcol) * TMEL_ + (rowBase - bb * TP + lrow + q)] = v;
        } else {
          if (Cf) Cf[(long)(rowBase + lrow + q) * ldc + gcol] = v;
          if (Cbf) Cbf[(pr0 + lrow + q) * ldc + gcol] = (bf16)v;
        }
      }
    }
  }
}

// ===========================================================================
// MFMA flash attention. Block = (64-query tile, h, b), 4 waves x 16 queries.
// QK^T and PV via mfma_f32_16x16x32_bf16. K/V^T tiles (64 keys) staged in LDS
// with XOR-swizzled 16B blocks; P converted C-layout -> A-frag via per-wave
// swizzled LDS tile. Online softmax in C-layout registers (shfl over 16-lane
// key groups).
// ===========================================================================
__global__ __launch_bounds__(256) void attn4_kernel(
    const bf16* __restrict__ QKV, const bf16* __restrict__ VT,
    const float* __restrict__ maskadd, bf16* __restrict__ Obf, int T) {
  const int qt = blockIdx.x, h = blockIdx.y, b = blockIdx.z;
  const int tid = threadIdx.x;
  const int lane = tid & 63;
  const int wave = tid >> 6;
  const int l15 = lane & 15, g = lane >> 4;

  __shared__ bf16 Ks[64 * 64];    // swizzled [key][dh]
  __shared__ bf16 Vts[64 * 64];   // swizzled [dh][key]
  __shared__ bf16 Ps[4][16 * 64]; // per-wave swizzled [q][key]
  __shared__ float mask_s[TMEL_];

  const int q0 = qt * 64;
  const size_t brow0 = (size_t)b * (T + 2) + 1;

  for (int i = tid; i < T; i += 256) mask_s[i] = maskadd[(size_t)b * T + i];

  // Q fragments (A-frag: row=l15, k=g*8+j+ks*32), held in registers
  const size_t qrow = brow0 + q0 + wave * 16 + l15;
  bf16x8 qf0 = *(const bf16x8*)(QKV + qrow * QKV_N + h * DH_ + g * 8);
  bf16x8 qf1 = *(const bf16x8*)(QKV + qrow * QKV_N + h * DH_ + g * 8 + 32);

  float mreg[4], lreg[4];
#pragma unroll
  for (int r = 0; r < 4; ++r) { mreg[r] = -INFINITY; lreg[r] = 0.0f; }
  f32x4 oacc[4] = {};
  bf16* Psb = Ps[wave];

  const int nt = T / 64;
  for (int t = 0; t < nt; ++t) {
    const int k0 = t * 64;
    // ---- stage K and V^T (swizzled: 16B block index ^= row&7) ----
#pragma unroll
    for (int it = 0; it < 2; ++it) {
      int c = it * 256 + tid;  // 0..511
      int r = c >> 3, d0 = c & 7;
      bf16x8 kv = *(const bf16x8*)(QKV + (brow0 + k0 + r) * QKV_N + 384 + h * DH_ + d0 * 8);
      *(bf16x8*)(Ks + r * 64 + ((d0 ^ (r & 7)) << 3)) = kv;
      bf16x8 vv = *(const bf16x8*)(VT + ((size_t)(b * H_ + h) * DH_ + r) * T + k0 + d0 * 8);
      *(bf16x8*)(Vts + r * 64 + ((d0 ^ (r & 7)) << 3)) = vv;
    }
    __syncthreads();

    // ---- S = Q K^T (4 key-subtiles x 2 k-steps) ----
    f32x4 sacc[4] = {};
#pragma unroll
    for (int ks = 0; ks < 2; ++ks) {
#pragma unroll
      for (int n = 0; n < 4; ++n) {
        int key = n * 16 + l15;
        bf16x8 bf = *(const bf16x8*)(Ks + key * 64 + (((g + ks * 4) ^ (key & 7)) << 3));
        sacc[n] = __builtin_amdgcn_mfma_f32_16x16x32_bf16(ks ? qf1 : qf0, bf, sacc[n], 0, 0, 0);
      }
    }

    // ---- scale + mask; row-max over keys (in-lane over n, shfl over 16) ----
    float s[4][4];
    float tm[4] = {-INFINITY, -INFINITY, -INFINITY, -INFINITY};
#pragma unroll
    for (int n = 0; n < 4; ++n) {
      float mv = mask_s[k0 + n * 16 + l15];
#pragma unroll
      for (int r = 0; r < 4; ++r) {
        float v = sacc[n][r] * 0.125f + mv;
        s[n][r] = v;
        tm[r] = fmaxf(tm[r], v);
      }
    }
#pragma unroll
    for (int msk = 1; msk < 16; msk <<= 1)
#pragma unroll
      for (int r = 0; r < 4; ++r) tm[r] = fmaxf(tm[r], __shfl_xor(tm[r], msk));

    // ---- online update ----
    float sc[4];
#pragma unroll
    for (int r = 0; r < 4; ++r) {
      float mn = fmaxf(mreg[r], tm[r]);
      sc[r] = __expf(mreg[r] - mn);
      mreg[r] = mn;
    }
    float psum[4] = {0.0f, 0.0f, 0.0f, 0.0f};
#pragma unroll
    for (int n = 0; n < 4; ++n) {
      int key = n * 16 + l15;
      int kblk = key >> 3, kin = key & 7;
#pragma unroll
      for (int r = 0; r < 4; ++r) {
        float p = __expf(s[n][r] - mreg[r]);
        psum[r] += p;
        int q = g * 4 + r;
        Psb[q * 64 + ((kblk ^ (q & 7)) << 3) + kin] = (bf16)p;
      }
    }
#pragma unroll
    for (int msk = 1; msk < 16; msk <<= 1)
#pragma unroll
      for (int r = 0; r < 4; ++r) psum[r] += __shfl_xor(psum[r], msk);
#pragma unroll
    for (int r = 0; r < 4; ++r) lreg[r] = lreg[r] * sc[r] + psum[r];
#pragma unroll
    for (int n = 0; n < 4; ++n)
#pragma unroll
      for (int r = 0; r < 4; ++r) oacc[n][r] *= sc[r];

    // ---- O += P V (A-frag from own Ps; B-frag from swizzled Vts) ----
#pragma unroll
    for (int ks = 0; ks < 2; ++ks) {
      bf16x8 af = *(const bf16x8*)(Psb + l15 * 64 + (((g + ks * 4) ^ (l15 & 7)) << 3));
#pragma unroll
      for (int n = 0; n < 4; ++n) {
        int dh = n * 16 + l15;
        bf16x8 bv = *(const bf16x8*)(Vts + dh * 64 + (((g + ks * 4) ^ (dh & 7)) << 3));
        oacc[n] = __builtin_amdgcn_mfma_f32_16x16x32_bf16(af, bv, oacc[n], 0, 0, 0);
      }
    }
    __syncthreads();
  }

  // ---- epilogue: O / l -> bf16 padded [B][T+2][384] ----
  float inv[4];
#pragma unroll
  for (int r = 0; r < 4; ++r) inv[r] = 1.0f / lreg[r];
  const size_t orow = brow0 + q0 + wave * 16 + g * 4;
#pragma unroll
  for (int n = 0; n < 4; ++n)
#pragma unroll
    for (int r = 0; r < 4; ++r)
      Obf[(orow + r) * D_ + h * DH_ + n * 16 + l15] = (bf16)(oacc[n][r] * inv[r]);
}

// ===========================================================================
// Y = LN(X + Hh) * g + b. Writes fp32 Yf and optional padded bf16 Ybf.
// ===========================================================================
__global__ __launch_bounds__(128) void add_ln_kernel(
    const float* __restrict__ X, const float* __restrict__ Hh,
    const float* __restrict__ g, const float* __restrict__ bb,
    float* __restrict__ Yf, bf16* __restrict__ Ybf, int tshift) {
  const int row = blockIdx.x;
  const int tid = threadIdx.x;
  __shared__ float red[128];
  float v[3];
  float s = 0.0f;
#pragma unroll
  for (int e = 0; e < 3; ++e) {
    int d = tid + e * 128;
    float x = X[(size_t)row * D_ + d];
    if (Hh) x += Hh[(size_t)row * D_ + d];
    v[e] = x;
    s += x;
  }
  red[tid] = s;
  __syncthreads();
  for (int off = 64; off > 0; off >>= 1) {
    if (tid < off) red[tid] += red[tid + off];
    __syncthreads();
  }
  float mean = red[0] / (float)D_;
  __syncthreads();
  float s2 = 0.0f;
#pragma unroll
  for (int e = 0; e < 3; ++e) {
    float dd = v[e] - mean;
    s2 += dd * dd;
  }
  red[tid] = s2;
  __syncthreads();
  for (int off = 64; off > 0; off >>= 1) {
    if (tid < off) red[tid] += red[tid + off];
    __syncthreads();
  }
  float invstd = rsqrtf(red[0] / (float)D_ + 1e-5f);
  __syncthreads();
  const int b = row >> tshift, t = row & ((1 << tshift) - 1);
  const size_t prow = (size_t)b * ((1 << tshift) + 2) + 1 + t;
#pragma unroll
  for (int e = 0; e < 3; ++e) {
    int d = tid + e * 128;
    float y = (v[e] - mean) * invstd * g[d] + bb[d];
    Yf[(size_t)row * D_ + d] = y;
    if (Ybf) Ybf[prow * D_ + d] = (bf16)y;
  }
}

__global__ __launch_bounds__(64) void dp_linear_kernel(
    const float* __restrict__ Hh, const float* __restrict__ w,
    const float* __restrict__ b0, float* __restrict__ lp) {
  const int row = blockIdx.x;
  const int tid = threadIdx.x;
  float s = 0.0f;
  for (int d = tid; d < D_; d += 64) s += Hh[(size_t)row * D_ + d] * w[d];
#pragma unroll
  for (int off = 32; off > 0; off >>= 1) s += __shfl_down(s, off);
  if (tid == 0) lp[row] = s + b0[0];
}

// ---------------------------------------------------------------------------
// Length regulator
// ---------------------------------------------------------------------------
__global__ void lr_scan_kernel(const int* __restrict__ dur, int* __restrict__ cs,
                               int* __restrict__ mel) {
  int b = blockIdx.x;
  if (threadIdx.x == 0) {
    int s = 0;
    for (int t = 0; t < T_; ++t) {
      s += dur[b * T_ + t];
      cs[b * T_ + t] = s;
    }
    mel[b] = s;
  }
}

__global__ __launch_bounds__(256) void lr_build_kernel(
    const int* __restrict__ cs, const int* __restrict__ mel,
    int* __restrict__ idx, float* __restrict__ maskd) {
  int b = blockIdx.x;
  int mlen = mel[b];
  for (int m = threadIdx.x; m < TMEL_; m += 256) {
    int t = -1;
    if (m < mlen) {
      int lo = 0, hi = T_ - 1;
      while (lo < hi) {
        int mid = (lo + hi) >> 1;
        if (cs[b * T_ + mid] > m) hi = mid; else lo = mid + 1;
      }
      t = lo;
    }
    idx[b * TMEL_ + m] = t;
    maskd[b * TMEL_ + m] = (m > mlen) ? -INFINITY : 0.0f;
  }
}

__global__ __launch_bounds__(128) void lr_gather_kernel(
    const float* __restrict__ XE, const int* __restrict__ idx,
    float* __restrict__ XD, bf16* __restrict__ XDbf) {
  int row = blockIdx.x;  // b*TMEL + m
  int b = row / TMEL_, m = row % TMEL_;
  int t = idx[row];
  size_t prow = ((size_t)b * (TMEL_ + 2) + 1 + m) * D_;
  for (int d = threadIdx.x; d < D_; d += 128) {
    float v = (t >= 0) ? XE[((size_t)(b * T_ + t)) * D_ + d] : 0.0f;
    XD[(size_t)row * D_ + d] = v;
    XDbf[prow + d] = (bf16)v;
  }
}

// ===========================================================================
// Host
// ===========================================================================
extern "C" void kernel_launch(void* const* d_in, const int* in_sizes, int n_in,
                              void* d_out, int out_size, void* d_ws, size_t ws_size,
                              hipStream_t stream) {
  const int* tokens = (const int*)d_in[0];
  const int* token_lengths = (const int*)d_in[1];
  const int* durations = (const int*)d_in[2];
  const float* emb = (const float*)d_in[3];
  const float* encw[12];
  const float* decw[12];
  for (int i = 0; i < 12; ++i) encw[i] = (const float*)d_in[4 + i];
  for (int i = 0; i < 12; ++i) decw[i] = (const float*)d_in[16 + i];
  const float* dp_c1w = (const float*)d_in[28];
  const float* dp_c1b = (const float*)d_in[29];
  const float* dp_ln1g = (const float*)d_in[30];
  const float* dp_ln1b = (const float*)d_in[31];
  const float* dp_c2w = (const float*)d_in[32];
  const float* dp_c2b = (const float*)d_in[33];
  const float* dp_ln2g = (const float*)d_in[34];
  const float* dp_ln2b = (const float*)d_in[35];
  const float* dp_w = (const float*)d_in[36];
  const float* dp_b = (const float*)d_in[37];
  const float* out_w = (const float*)d_in[38];
  const float* out_b = (const float*)d_in[39];

  float* out0 = (float*)d_out;                        // [B, OUT, TMEL]
  float* out_lp = out0 + (size_t)B_ * OUT_C * TMEL_;  // [B, T]

  // ---- workspace ----
  char* wsB = (char*)d_ws;
  size_t off = 0;
  auto alloc = [&](size_t bytes) {
    void* p = wsB + off;
    off = (off + bytes + 255) & ~(size_t)255;
    return p;
  };
  float* XE = (float*)alloc((size_t)B_ * T_ * D_ * 4);
  float* XD = (float*)alloc((size_t)B_ * TMEL_ * D_ * 4);
  float* YT = (float*)alloc((size_t)B_ * TMEL_ * D_ * 4);
  bf16* XEbf = (bf16*)alloc((size_t)B_ * (T_ + 2) * D_ * 2);
  bf16* XDbf = (bf16*)alloc((size_t)B_ * (TMEL_ + 2) * D_ * 2);
  bf16* YTbf = (bf16*)alloc((size_t)B_ * (TMEL_ + 2) * D_ * 2);
  bf16* MIDbf = (bf16*)alloc((size_t)B_ * (TMEL_ + 2) * INTER_ * 2);
  bf16* QKVbf = (bf16*)alloc((size_t)B_ * (TMEL_ + 2) * QKV_N * 2);
  bf16* OBbf = (bf16*)alloc((size_t)B_ * (TMEL_ + 2) * D_ * 2);
  bf16* VTb = (bf16*)alloc((size_t)B_ * H_ * DH_ * TMEL_ * 2);
  float* OF = (float*)QKVbf;  // fp32 GEMM outputs alias QKVbf (disjoint lifetime)
  bf16* QKVT = (bf16*)alloc((size_t)L_ * QKV_N * D_ * 2);
  bf16* WOT = (bf16*)alloc((size_t)L_ * D_ * D_ * 2);
  bf16* C1T = (bf16*)alloc((size_t)INTER_ * (3 * D_) * 2);
  bf16* C2T = (bf16*)alloc((size_t)D_ * (3 * INTER_) * 2);
  bf16* DP1T = (bf16*)alloc((size_t)D_ * (3 * D_) * 2);
  bf16* DP2T = (bf16*)alloc((size_t)D_ * (3 * D_) * 2);
  bf16* OUTT = (bf16*)alloc((size_t)128 * D_ * 2);
  float* MASKE = (float*)alloc(B_ * T_ * 4);
  float* MASKD = (float*)alloc(B_ * TMEL_ * 4);
  int* CS = (int*)alloc(B_ * T_ * 4);
  int* MEL = (int*)alloc(B_ * 4);
  int* IDX = (int*)alloc(B_ * TMEL_ * 4);

  auto tw = [&](const float* s, long sls, bf16* d, long dls, int K, int N,
                int Ndst, int ro, int Lz) {
    transpose_w_kernel<<<dim3(Ndst / 32, K / 32, Lz), 256, 0, stream>>>(s, sls, d, dls, K, N, ro);
  };
  auto gemm = [&](int TP, int nT, int mT, const bf16* A, int lda, int aofs,
                  const bf16* WTp, int Ktot, const float* bias, int relu,
                  float* Cf, bf16* Cbf, int ldc, int transC) {
    dim3 g(nT, mT);
    if (TP == 128)
      mfma_gemm_kernel<128><<<g, 256, 0, stream>>>(A, lda, aofs, WTp, Ktot, bias, relu, Cf, Cbf, ldc, transC);
    else
      mfma_gemm_kernel<1024><<<g, 256, 0, stream>>>(A, lda, aofs, WTp, Ktot, bias, relu, Cf, Cbf, ldc, transC);
  };

  auto run_layer = [&](int TP, const float* const* w, int i, float* Xf, bf16* Xbf,
                       const float* mask) {
    const int mT = B_ * TP / 128;
    const int tshift = (TP == 128) ? 7 : 10;
    tw(w[6] + (size_t)i * 3 * D_ * INTER_, 0, C1T, 0, 3 * D_, INTER_, INTER_, 0, 1);
    tw(w[8] + (size_t)i * 3 * INTER_ * D_, 0, C2T, 0, 3 * INTER_, D_, D_, 0, 1);
    gemm(TP, QKV_N / 128, mT, Xbf, D_, 0, QKVT + (size_t)i * QKV_N * D_, D_,
         nullptr, 0, nullptr, QKVbf, QKV_N, 0);
    transpose_v_kernel<<<dim3(TP / 32, 2, B_ * H_), 256, 0, stream>>>(QKVbf, VTb, TP);
    attn4_kernel<<<dim3(TP / 64, H_, B_), 256, 0, stream>>>(QKVbf, VTb, mask, OBbf, TP);
    gemm(TP, D_ / 128, mT, OBbf, D_, 0, WOT + (size_t)i * D_ * D_, D_,
         nullptr, 0, OF, nullptr, D_, 0);
    add_ln_kernel<<<B_ * TP, 128, 0, stream>>>(Xf, OF, w[4] + (size_t)i * D_,
                                               w[5] + (size_t)i * D_, YT, YTbf, tshift);
    gemm(TP, INTER_ / 128, mT, YTbf, D_, D_, C1T, 3 * D_,
         w[7] + (size_t)i * INTER_, 1, nullptr, MIDbf, INTER_, 0);
    gemm(TP, D_ / 128, mT, MIDbf, INTER_, INTER_, C2T, 3 * INTER_,
         w[9] + (size_t)i * D_, 0, OF, nullptr, D_, 0);
    add_ln_kernel<<<B_ * TP, 128, 0, stream>>>(YT, OF, w[10] + (size_t)i * D_,
                                               w[11] + (size_t)i * D_, Xf, Xbf, tshift);
  };

  // 1) embed + masks + pad zeroing
  embed_kernel<<<(B_ * T_ * D_ + 255) / 256, 256, 0, stream>>>(tokens, emb, XE, XEbf);
  enc_mask_kernel<<<(B_ * T_ + 255) / 256, 256, 0, stream>>>(token_lengths, MASKE);
  zero_pads_kernel<<<B_ * 2, 256, 0, stream>>>(XEbf, T_, D_);
  zero_pads_kernel<<<B_ * 2, 256, 0, stream>>>(YTbf, T_, D_);
  zero_pads_kernel<<<B_ * 2, 256, 0, stream>>>(MIDbf, T_, INTER_);

  // 2) encoder
  tw(encw[0], (long)D_ * HD_, QKVT, (long)QKV_N * D_, D_, HD_, HD_, 0, L_);
  tw(encw[1], (long)D_ * HD_, QKVT, (long)QKV_N * D_, D_, HD_, HD_, 384, L_);
  tw(encw[2], (long)D_ * HD_, QKVT, (long)QKV_N * D_, D_, HD_, HD_, 768, L_);
  tw(encw[3], (long)HD_ * D_, WOT, (long)D_ * D_, HD_, D_, D_, 0, L_);
  for (int i = 0; i < L_; ++i) run_layer(T_, encw, i, XE, XEbf, MASKE);

  // 3) duration predictor
  tw(dp_c1w, 0, DP1T, 0, 3 * D_, D_, D_, 0, 1);
  tw(dp_c2w, 0, DP2T, 0, 3 * D_, D_, D_, 0, 1);
  gemm(T_, D_ / 128, B_, XEbf, D_, D_, DP1T, 3 * D_, dp_c1b, 1, OF, nullptr, D_, 0);
  add_ln_kernel<<<B_ * T_, 128, 0, stream>>>(OF, nullptr, dp_ln1g, dp_ln1b, YT, YTbf, 7);
  gemm(T_, D_ / 128, B_, YTbf, D_, D_, DP2T, 3 * D_, dp_c2b, 1, OF, nullptr, D_, 0);
  add_ln_kernel<<<B_ * T_, 128, 0, stream>>>(OF, nullptr, dp_ln2g, dp_ln2b, YT, nullptr, 7);
  dp_linear_kernel<<<B_ * T_, 64, 0, stream>>>(YT, dp_w, dp_b, out_lp);

  // 4) length regulator
  lr_scan_kernel<<<B_, 32, 0, stream>>>(durations, CS, MEL);
  lr_build_kernel<<<B_, 256, 0, stream>>>(CS, MEL, IDX, MASKD);
  zero_pads_kernel<<<B_ * 2, 256, 0, stream>>>(XDbf, TMEL_, D_);
  zero_pads_kernel<<<B_ * 2, 256, 0, stream>>>(YTbf, TMEL_, D_);
  zero_pads_kernel<<<B_ * 2, 256, 0, stream>>>(MIDbf, TMEL_, INTER_);
  lr_gather_kernel<<<B_ * TMEL_, 128, 0, stream>>>(XE, IDX, XD, XDbf);

  // 5) decoder
  tw(decw[0], (long)D_ * HD_, QKVT, (long)QKV_N * D_, D_, HD_, HD_, 0, L_);
  tw(decw[1], (long)D_ * HD_, QKVT, (long)QKV_N * D_, D_, HD_, HD_, 384, L_);
  tw(decw[2], (long)D_ * HD_, QKVT, (long)QKV_N * D_, D_, HD_, HD_, 768, L_);
  tw(decw[3], (long)HD_ * D_, WOT, (long)D_ * D_, HD_, D_, D_, 0, L_);
  for (int i = 0; i < L_; ++i) run_layer(TMEL_, decw, i, XD, XDbf, MASKD);

  // 6) final projection via MFMA GEMM with transposed mel write
  tw(out_w, 0, OUTT, 0, D_, OUT_C, 128, 0, 1);
  gemm(TMEL_, 1, B_ * TMEL_ / 128, XDbf, D_, 0, OUTT, D_, out_b, 0,
       out0, nullptr, 0, 1);
}

// Round 6
// 1567.133 us; speedup vs baseline: 15.4851x; 1.1701x over previous
//
#include <hip/hip_runtime.h>
#include <math.h>

typedef __bf16 bf16;
typedef __attribute__((ext_vector_type(8))) __bf16 bf16x8;
typedef __attribute__((ext_vector_type(4))) float f32x4;

// ---- problem constants ----
constexpr int B_ = 8;
constexpr int T_ = 128;
constexpr int D_ = 384;
constexpr int H_ = 6;
constexpr int DH_ = 64;
constexpr int L_ = 4;
constexpr int INTER_ = 1536;
constexpr int OUT_C = 80;
constexpr int TMEL_ = 1024;
constexpr int HD_ = 384;     // H*DH
constexpr int QKV_N = 1152;  // 3*HD

// ===========================================================================
// Embedding + PE (PE indexed by BATCH per reference quirk): x = 2*emb + pe[b]
// ===========================================================================
__global__ __launch_bounds__(256) void embed_kernel(
    const int* __restrict__ tokens, const float* __restrict__ emb,
    float* __restrict__ X, bf16* __restrict__ Xbf) {
  int i = blockIdx.x * 256 + threadIdx.x;
  if (i >= B_ * T_ * D_) return;
  int d = i % D_;
  int bt = i / D_;
  int b = bt / T_, t = bt % T_;
  int tok = tokens[bt];
  int i2 = d & ~1;
  const float c = 9.210340371976184f / (float)D_;  // ln(10000)/D
  float freq = expf(-(float)i2 * c);
  float ang = (float)b * freq;
  float pe = (d & 1) ? cosf(ang) : sinf(ang);
  float v = 2.0f * emb[(size_t)tok * D_ + d] + pe;
  X[i] = v;
  Xbf[((size_t)b * (T_ + 2) + 1 + t) * D_ + d] = (bf16)v;
}

__global__ void enc_mask_kernel(const int* __restrict__ tl, float* __restrict__ maske) {
  int i = blockIdx.x * 256 + threadIdx.x;
  if (i >= B_ * T_) return;
  int b = i / T_, t = i % T_;
  maske[i] = (t > tl[b]) ? -INFINITY : 0.0f;
}

// ===========================================================================
// Weight transpose: src fp32 [K][N] -> dst bf16 [Ndst + rowOfs][K] row-major.
// ===========================================================================
__global__ __launch_bounds__(256) void transpose_w_kernel(
    const float* __restrict__ src, long srcLS, bf16* __restrict__ dst,
    long dstLS, int K, int N, int rowOfs) {
  src += (size_t)blockIdx.z * srcLS;
  dst += (size_t)blockIdx.z * dstLS;
  __shared__ float tile[32][33];
  const int tx = threadIdx.x & 31, ty = threadIdx.x >> 5;
  const int n0 = blockIdx.x * 32, k0 = blockIdx.y * 32;
#pragma unroll
  for (int j = 0; j < 4; ++j)
    tile[ty + j * 8][tx] =
        (n0 + tx < N) ? src[(size_t)(k0 + ty + j * 8) * N + n0 + tx] : 0.0f;
  __syncthreads();
#pragma unroll
  for (int j = 0; j < 4; ++j)
    dst[(size_t)(n0 + rowOfs + ty + j * 8) * K + k0 + tx] = (bf16)tile[tx][ty + j * 8];
}

// Zero the 2 padding rows per batch of a padded bf16 activation buffer.
__global__ void zero_pads_kernel(bf16* buf, int Tp, int C) {
  int b = blockIdx.x >> 1, side = blockIdx.x & 1;
  size_t row = (size_t)b * (Tp + 2) + (side ? (Tp + 1) : 0);
  for (int c = threadIdx.x; c < C; c += 256) buf[row * C + c] = (bf16)0.0f;
}

// ===========================================================================
// V transpose per layer: QKVbf [b][(T+2)][1152] cols 768.. -> VT [b*6+h][64][T]
// ===========================================================================
__global__ __launch_bounds__(256) void transpose_v_kernel(
    const bf16* __restrict__ QKV, bf16* __restrict__ VT, int T) {
  const int tb = blockIdx.x, db = blockIdx.y, bh = blockIdx.z;
  const int b = bh / H_, h = bh % H_;
  __shared__ float tile[32][33];
  const int tx = threadIdx.x & 31, ty = threadIdx.x >> 5;
  const size_t src = ((size_t)b * (T + 2) + 1 + tb * 32) * QKV_N + 768 + h * DH_ + db * 32;
#pragma unroll
  for (int j = 0; j < 4; ++j)
    tile[ty + 8 * j][tx] = (float)QKV[src + (size_t)(ty + 8 * j) * QKV_N + tx];
  __syncthreads();
  const size_t dst = ((size_t)(b * H_ + h) * DH_ + db * 32) * T + tb * 32;
#pragma unroll
  for (int j = 0; j < 4; ++j)
    VT[dst + (size_t)(ty + 8 * j) * T + tx] = (bf16)tile[tx][ty + 8 * j];
}

// ===========================================================================
// MFMA bf16 GEMM, 128x128 tile, BK=64, 4 waves (2x2 of 64x64).
// Double-buffered LDS: stage tile t+1 while computing t, one barrier per
// K-step. Split-K via gridDim.z (z==0 -> Cf (+bias), z==1 -> Cf2).
// transC: write fp32 transposed mel output out[(b*OUT_C+col)*TMEL + t].
// ===========================================================================
template <int TP>
__global__ __launch_bounds__(256) void mfma_gemm_kernel(
    const bf16* __restrict__ A, int lda, int aofs,
    const bf16* __restrict__ WT, int ldw, int kslice,
    const float* __restrict__ bias, int relu,
    float* __restrict__ Cf, float* __restrict__ Cf2,
    bf16* __restrict__ Cbf, int ldc, int transC) {
  __shared__ bf16 As[2][128 * 64];
  __shared__ bf16 Bs[2][128 * 64];
  const int tid = threadIdx.x;
  const int lane = tid & 63;
  const int wave = tid >> 6;
  const int wr = wave >> 1, wc = wave & 1;
  const int rowBase = blockIdx.y * 128;
  const int colBase = blockIdx.x * 128;
  const int z = blockIdx.z;
  const int k0beg = z * kslice;
  const int nt = kslice / 64;
  const int bb = rowBase / TP;
  const long pr0 = (long)bb * (TP + 2) + 1 + (rowBase - bb * TP);
  const long abase = pr0 * (long)lda - aofs;

  const int srow = tid >> 3, scb = tid & 7;

  auto stage = [&](int t, int buf) {
    const int k0 = k0beg + t * 64;
#pragma unroll
    for (int e = 0; e < 4; ++e) {
      int idx = e * 256 + tid;
      int lrow = srow + e * 32;
      const bf16* gp = A + abase + (long)lrow * lda + k0 + ((scb ^ (lrow & 7)) << 3);
      __builtin_amdgcn_global_load_lds(
          (const __attribute__((address_space(1))) unsigned int*)gp,
          (__attribute__((address_space(3))) unsigned int*)(As[buf] + idx * 8), 16, 0, 0);
    }
#pragma unroll
    for (int e = 0; e < 4; ++e) {
      int idx = e * 256 + tid;
      int lrow = srow + e * 32;
      const bf16* gp = WT + (long)(colBase + lrow) * ldw + k0 + ((scb ^ (lrow & 7)) << 3);
      __builtin_amdgcn_global_load_lds(
          (const __attribute__((address_space(1))) unsigned int*)gp,
          (__attribute__((address_space(3))) unsigned int*)(Bs[buf] + idx * 8), 16, 0, 0);
    }
  };

  f32x4 acc[4][4] = {};

  stage(0, 0);
  __syncthreads();
  for (int t = 0; t < nt; ++t) {
    const int cur = t & 1;
    if (t + 1 < nt) stage(t + 1, cur ^ 1);
    const bf16* Asb = As[cur];
    const bf16* Bsb = Bs[cur];
#pragma unroll
    for (int ks = 0; ks < 2; ++ks) {
      bf16x8 af[4], bw[4];
#pragma unroll
      for (int m = 0; m < 4; ++m) {
        int row = wr * 64 + m * 16 + (lane & 15);
        int cb = ((ks << 2) + (lane >> 4)) ^ (row & 7);
        af[m] = *(const bf16x8*)(Asb + row * 64 + cb * 8);
      }
#pragma unroll
      for (int n = 0; n < 4; ++n) {
        int row = wc * 64 + n * 16 + (lane & 15);
        int cb = ((ks << 2) + (lane >> 4)) ^ (row & 7);
        bw[n] = *(const bf16x8*)(Bsb + row * 64 + cb * 8);
      }
#pragma unroll
      for (int m = 0; m < 4; ++m)
#pragma unroll
        for (int n = 0; n < 4; ++n)
          acc[m][n] = __builtin_amdgcn_mfma_f32_16x16x32_bf16(af[m], bw[n], acc[m][n], 0, 0, 0);
    }
    __syncthreads();  // drains this iter's prefetch; guards buffer reuse
  }

  float* Cfz = z ? Cf2 : Cf;
  const float* biasz = z ? nullptr : bias;
  const int qr = (lane >> 4) * 4;
  const int qc = lane & 15;
#pragma unroll
  for (int m = 0; m < 4; ++m) {
    int lrow = wr * 64 + m * 16 + qr;
#pragma unroll
    for (int n = 0; n < 4; ++n) {
      int gcol = colBase + wc * 64 + n * 16 + qc;
      float bv = (biasz && (!transC || gcol < OUT_C)) ? biasz[gcol] : 0.0f;
#pragma unroll
      for (int q = 0; q < 4; ++q) {
        float v = acc[m][n][q] + bv;
        if (relu) v = fmaxf(v, 0.0f);
        if (transC) {
          if (gcol < OUT_C)
            Cfz[((long)bb * OUT_C + gcol) * TMEL_ + (rowBase - bb * TP + lrow + q)] = v;
        } else {
          if (Cfz) Cfz[(long)(rowBase + lrow + q) * ldc + gcol] = v;
          if (Cbf) Cbf[(pr0 + lrow + q) * ldc + gcol] = (bf16)v;
        }
      }
    }
  }
}

// ===========================================================================
// MFMA flash attention (unchanged).
// ===========================================================================
__global__ __launch_bounds__(256) void attn4_kernel(
    const bf16* __restrict__ QKV, const bf16* __restrict__ VT,
    const float* __restrict__ maskadd, bf16* __restrict__ Obf, int T) {
  const int qt = blockIdx.x, h = blockIdx.y, b = blockIdx.z;
  const int tid = threadIdx.x;
  const int lane = tid & 63;
  const int wave = tid >> 6;
  const int l15 = lane & 15, g = lane >> 4;

  __shared__ bf16 Ks[64 * 64];
  __shared__ bf16 Vts[64 * 64];
  __shared__ bf16 Ps[4][16 * 64];
  __shared__ float mask_s[TMEL_];

  const int q0 = qt * 64;
  const size_t brow0 = (size_t)b * (T + 2) + 1;

  for (int i = tid; i < T; i += 256) mask_s[i] = maskadd[(size_t)b * T + i];

  const size_t qrow = brow0 + q0 + wave * 16 + l15;
  bf16x8 qf0 = *(const bf16x8*)(QKV + qrow * QKV_N + h * DH_ + g * 8);
  bf16x8 qf1 = *(const bf16x8*)(QKV + qrow * QKV_N + h * DH_ + g * 8 + 32);

  float mreg[4], lreg[4];
#pragma unroll
  for (int r = 0; r < 4; ++r) { mreg[r] = -INFINITY; lreg[r] = 0.0f; }
  f32x4 oacc[4] = {};
  bf16* Psb = Ps[wave];

  const int nt = T / 64;
  for (int t = 0; t < nt; ++t) {
    const int k0 = t * 64;
#pragma unroll
    for (int it = 0; it < 2; ++it) {
      int c = it * 256 + tid;
      int r = c >> 3, d0 = c & 7;
      bf16x8 kv = *(const bf16x8*)(QKV + (brow0 + k0 + r) * QKV_N + 384 + h * DH_ + d0 * 8);
      *(bf16x8*)(Ks + r * 64 + ((d0 ^ (r & 7)) << 3)) = kv;
      bf16x8 vv = *(const bf16x8*)(VT + ((size_t)(b * H_ + h) * DH_ + r) * T + k0 + d0 * 8);
      *(bf16x8*)(Vts + r * 64 + ((d0 ^ (r & 7)) << 3)) = vv;
    }
    __syncthreads();

    f32x4 sacc[4] = {};
#pragma unroll
    for (int ks = 0; ks < 2; ++ks) {
#pragma unroll
      for (int n = 0; n < 4; ++n) {
        int key = n * 16 + l15;
        bf16x8 bf = *(const bf16x8*)(Ks + key * 64 + (((g + ks * 4) ^ (key & 7)) << 3));
        sacc[n] = __builtin_amdgcn_mfma_f32_16x16x32_bf16(ks ? qf1 : qf0, bf, sacc[n], 0, 0, 0);
      }
    }

    float s[4][4];
    float tm[4] = {-INFINITY, -INFINITY, -INFINITY, -INFINITY};
#pragma unroll
    for (int n = 0; n < 4; ++n) {
      float mv = mask_s[k0 + n * 16 + l15];
#pragma unroll
      for (int r = 0; r < 4; ++r) {
        float v = sacc[n][r] * 0.125f + mv;
        s[n][r] = v;
        tm[r] = fmaxf(tm[r], v);
      }
    }
#pragma unroll
    for (int msk = 1; msk < 16; msk <<= 1)
#pragma unroll
      for (int r = 0; r < 4; ++r) tm[r] = fmaxf(tm[r], __shfl_xor(tm[r], msk));

    float sc[4];
#pragma unroll
    for (int r = 0; r < 4; ++r) {
      float mn = fmaxf(mreg[r], tm[r]);
      sc[r] = __expf(mreg[r] - mn);
      mreg[r] = mn;
    }
    float psum[4] = {0.0f, 0.0f, 0.0f, 0.0f};
#pragma unroll
    for (int n = 0; n < 4; ++n) {
      int key = n * 16 + l15;
      int kblk = key >> 3, kin = key & 7;
#pragma unroll
      for (int r = 0; r < 4; ++r) {
        float p = __expf(s[n][r] - mreg[r]);
        psum[r] += p;
        int q = g * 4 + r;
        Psb[q * 64 + ((kblk ^ (q & 7)) << 3) + kin] = (bf16)p;
      }
    }
#pragma unroll
    for (int msk = 1; msk < 16; msk <<= 1)
#pragma unroll
      for (int r = 0; r < 4; ++r) psum[r] += __shfl_xor(psum[r], msk);
#pragma unroll
    for (int r = 0; r < 4; ++r) lreg[r] = lreg[r] * sc[r] + psum[r];
#pragma unroll
    for (int n = 0; n < 4; ++n)
#pragma unroll
      for (int r = 0; r < 4; ++r) oacc[n][r] *= sc[r];

#pragma unroll
    for (int ks = 0; ks < 2; ++ks) {
      bf16x8 af = *(const bf16x8*)(Psb + l15 * 64 + (((g + ks * 4) ^ (l15 & 7)) << 3));
#pragma unroll
      for (int n = 0; n < 4; ++n) {
        int dh = n * 16 + l15;
        bf16x8 bv = *(const bf16x8*)(Vts + dh * 64 + (((g + ks * 4) ^ (dh & 7)) << 3));
        oacc[n] = __builtin_amdgcn_mfma_f32_16x16x32_bf16(af, bv, oacc[n], 0, 0, 0);
      }
    }
    __syncthreads();
  }

  float inv[4];
#pragma unroll
  for (int r = 0; r < 4; ++r) inv[r] = 1.0f / lreg[r];
  const size_t orow = brow0 + q0 + wave * 16 + g * 4;
#pragma unroll
  for (int n = 0; n < 4; ++n)
#pragma unroll
    for (int r = 0; r < 4; ++r)
      Obf[(orow + r) * D_ + h * DH_ + n * 16 + l15] = (bf16)(oacc[n][r] * inv[r]);
}

// ===========================================================================
// Y = LN(X + H1 + H2) * g + b. H1/H2 nullable (H2 = second split-K slice).
// ===========================================================================
__global__ __launch_bounds__(128) void add_ln_kernel(
    const float* __restrict__ X, const float* __restrict__ H1,
    const float* __restrict__ H2,
    const float* __restrict__ g, const float* __restrict__ bb,
    float* __restrict__ Yf, bf16* __restrict__ Ybf, int tshift) {
  const int row = blockIdx.x;
  const int tid = threadIdx.x;
  __shared__ float red[128];
  float v[3];
  float s = 0.0f;
#pragma unroll
  for (int e = 0; e < 3; ++e) {
    int d = tid + e * 128;
    float x = X[(size_t)row * D_ + d];
    if (H1) x += H1[(size_t)row * D_ + d];
    if (H2) x += H2[(size_t)row * D_ + d];
    v[e] = x;
    s += x;
  }
  red[tid] = s;
  __syncthreads();
  for (int off = 64; off > 0; off >>= 1) {
    if (tid < off) red[tid] += red[tid + off];
    __syncthreads();
  }
  float mean = red[0] / (float)D_;
  __syncthreads();
  float s2 = 0.0f;
#pragma unroll
  for (int e = 0; e < 3; ++e) {
    float dd = v[e] - mean;
    s2 += dd * dd;
  }
  red[tid] = s2;
  __syncthreads();
  for (int off = 64; off > 0; off >>= 1) {
    if (tid < off) red[tid] += red[tid + off];
    __syncthreads();
  }
  float invstd = rsqrtf(red[0] / (float)D_ + 1e-5f);
  __syncthreads();
  const int b = row >> tshift, t = row & ((1 << tshift) - 1);
  const size_t prow = (size_t)b * ((1 << tshift) + 2) + 1 + t;
#pragma unroll
  for (int e = 0; e < 3; ++e) {
    int d = tid + e * 128;
    float y = (v[e] - mean) * invstd * g[d] + bb[d];
    Yf[(size_t)row * D_ + d] = y;
    if (Ybf) Ybf[prow * D_ + d] = (bf16)y;
  }
}

__global__ __launch_bounds__(64) void dp_linear_kernel(
    const float* __restrict__ Hh, const float* __restrict__ w,
    const float* __restrict__ b0, float* __restrict__ lp) {
  const int row = blockIdx.x;
  const int tid = threadIdx.x;
  float s = 0.0f;
  for (int d = tid; d < D_; d += 64) s += Hh[(size_t)row * D_ + d] * w[d];
#pragma unroll
  for (int off = 32; off > 0; off >>= 1) s += __shfl_down(s, off);
  if (tid == 0) lp[row] = s + b0[0];
}

// ---------------------------------------------------------------------------
// Length regulator
// ---------------------------------------------------------------------------
__global__ void lr_scan_kernel(const int* __restrict__ dur, int* __restrict__ cs,
                               int* __restrict__ mel) {
  int b = blockIdx.x;
  if (threadIdx.x == 0) {
    int s = 0;
    for (int t = 0; t < T_; ++t) {
      s += dur[b * T_ + t];
      cs[b * T_ + t] = s;
    }
    mel[b] = s;
  }
}

__global__ __launch_bounds__(256) void lr_build_kernel(
    const int* __restrict__ cs, const int* __restrict__ mel,
    int* __restrict__ idx, float* __restrict__ maskd) {
  int b = blockIdx.x;
  int mlen = mel[b];
  for (int m = threadIdx.x; m < TMEL_; m += 256) {
    int t = -1;
    if (m < mlen) {
      int lo = 0, hi = T_ - 1;
      while (lo < hi) {
        int mid = (lo + hi) >> 1;
        if (cs[b * T_ + mid] > m) hi = mid; else lo = mid + 1;
      }
      t = lo;
    }
    idx[b * TMEL_ + m] = t;
    maskd[b * TMEL_ + m] = (m > mlen) ? -INFINITY : 0.0f;
  }
}

__global__ __launch_bounds__(128) void lr_gather_kernel(
    const float* __restrict__ XE, const int* __restrict__ idx,
    float* __restrict__ XD, bf16* __restrict__ XDbf) {
  int row = blockIdx.x;
  int b = row / TMEL_, m = row % TMEL_;
  int t = idx[row];
  size_t prow = ((size_t)b * (TMEL_ + 2) + 1 + m) * D_;
  for (int d = threadIdx.x; d < D_; d += 128) {
    float v = (t >= 0) ? XE[((size_t)(b * T_ + t)) * D_ + d] : 0.0f;
    XD[(size_t)row * D_ + d] = v;
    XDbf[prow + d] = (bf16)v;
  }
}

// ===========================================================================
// Host
// ===========================================================================
extern "C" void kernel_launch(void* const* d_in, const int* in_sizes, int n_in,
                              void* d_out, int out_size, void* d_ws, size_t ws_size,
                              hipStream_t stream) {
  const int* tokens = (const int*)d_in[0];
  const int* token_lengths = (const int*)d_in[1];
  const int* durations = (const int*)d_in[2];
  const float* emb = (const float*)d_in[3];
  const float* encw[12];
  const float* decw[12];
  for (int i = 0; i < 12; ++i) encw[i] = (const float*)d_in[4 + i];
  for (int i = 0; i < 12; ++i) decw[i] = (const float*)d_in[16 + i];
  const float* dp_c1w = (const float*)d_in[28];
  const float* dp_c1b = (const float*)d_in[29];
  const float* dp_ln1g = (const float*)d_in[30];
  const float* dp_ln1b = (const float*)d_in[31];
  const float* dp_c2w = (const float*)d_in[32];
  const float* dp_c2b = (const float*)d_in[33];
  const float* dp_ln2g = (const float*)d_in[34];
  const float* dp_ln2b = (const float*)d_in[35];
  const float* dp_w = (const float*)d_in[36];
  const float* dp_b = (const float*)d_in[37];
  const float* out_w = (const float*)d_in[38];
  const float* out_b = (const float*)d_in[39];

  float* out0 = (float*)d_out;                        // [B, OUT, TMEL]
  float* out_lp = out0 + (size_t)B_ * OUT_C * TMEL_;  // [B, T]

  // ---- workspace ----
  char* wsB = (char*)d_ws;
  size_t off = 0;
  auto alloc = [&](size_t bytes) {
    void* p = wsB + off;
    off = (off + bytes + 255) & ~(size_t)255;
    return p;
  };
  float* XE = (float*)alloc((size_t)B_ * T_ * D_ * 4);
  float* XD = (float*)alloc((size_t)B_ * TMEL_ * D_ * 4);
  float* YT = (float*)alloc((size_t)B_ * TMEL_ * D_ * 4);
  bf16* XEbf = (bf16*)alloc((size_t)B_ * (T_ + 2) * D_ * 2);
  bf16* XDbf = (bf16*)alloc((size_t)B_ * (TMEL_ + 2) * D_ * 2);
  bf16* YTbf = (bf16*)alloc((size_t)B_ * (TMEL_ + 2) * D_ * 2);
  bf16* MIDbf = (bf16*)alloc((size_t)B_ * (TMEL_ + 2) * INTER_ * 2);
  bf16* QKVbf = (bf16*)alloc((size_t)B_ * (TMEL_ + 2) * QKV_N * 2);
  bf16* OBbf = (bf16*)alloc((size_t)B_ * (TMEL_ + 2) * D_ * 2);   // 6.30 MB
  bf16* VTb = (bf16*)alloc((size_t)B_ * H_ * DH_ * TMEL_ * 2);    // 6.29 MB, adjacent
  float* OF = (float*)QKVbf;  // fp32 GEMM out slice 0 (aliases QKVbf; disjoint lifetime)
  // Split-K slice 1: needs B*TMEL*D*4 = 12.58 MB. OBbf (6.30 MB) + VTb (6.29 MB)
  // are adjacent and BOTH dead during conv2 (OBbf consumed by WO-proj, VTb by
  // attn) -> alias the contiguous span starting at OBbf. (Round-5 bug: aliasing
  // VTb alone overflowed into the transposed-weight buffers -> NaN.)
  float* PT2 = (float*)OBbf;
  bf16* QKVT = (bf16*)alloc((size_t)L_ * QKV_N * D_ * 2);
  bf16* WOT = (bf16*)alloc((size_t)L_ * D_ * D_ * 2);
  bf16* C1T = (bf16*)alloc((size_t)INTER_ * (3 * D_) * 2);
  bf16* C2T = (bf16*)alloc((size_t)D_ * (3 * INTER_) * 2);
  bf16* DP1T = (bf16*)alloc((size_t)D_ * (3 * D_) * 2);
  bf16* DP2T = (bf16*)alloc((size_t)D_ * (3 * D_) * 2);
  bf16* OUTT = (bf16*)alloc((size_t)128 * D_ * 2);
  float* MASKE = (float*)alloc(B_ * T_ * 4);
  float* MASKD = (float*)alloc(B_ * TMEL_ * 4);
  int* CS = (int*)alloc(B_ * T_ * 4);
  int* MEL = (int*)alloc(B_ * 4);
  int* IDX = (int*)alloc(B_ * TMEL_ * 4);

  auto tw = [&](const float* s, long sls, bf16* d, long dls, int K, int N,
                int Ndst, int ro, int Lz) {
    transpose_w_kernel<<<dim3(Ndst / 32, K / 32, Lz), 256, 0, stream>>>(s, sls, d, dls, K, N, ro);
  };
  auto gemm = [&](int TP, int nT, int mT, int nz, const bf16* A, int lda, int aofs,
                  const bf16* WTp, int ldw, int kslice, const float* bias, int relu,
                  float* Cf, float* Cf2, bf16* Cbf, int ldc, int transC) {
    dim3 g(nT, mT, nz);
    if (TP == 128)
      mfma_gemm_kernel<128><<<g, 256, 0, stream>>>(A, lda, aofs, WTp, ldw, kslice,
                                                   bias, relu, Cf, Cf2, Cbf, ldc, transC);
    else
      mfma_gemm_kernel<1024><<<g, 256, 0, stream>>>(A, lda, aofs, WTp, ldw, kslice,
                                                    bias, relu, Cf, Cf2, Cbf, ldc, transC);
  };

  auto run_layer = [&](int TP, const float* const* w, int i, float* Xf, bf16* Xbf,
                       const float* mask) {
    const int mT = B_ * TP / 128;
    const int tshift = (TP == 128) ? 7 : 10;
    tw(w[6] + (size_t)i * 3 * D_ * INTER_, 0, C1T, 0, 3 * D_, INTER_, INTER_, 0, 1);
    tw(w[8] + (size_t)i * 3 * INTER_ * D_, 0, C2T, 0, 3 * INTER_, D_, D_, 0, 1);
    gemm(TP, QKV_N / 128, mT, 1, Xbf, D_, 0, QKVT + (size_t)i * QKV_N * D_, D_, D_,
         nullptr, 0, nullptr, nullptr, QKVbf, QKV_N, 0);
    transpose_v_kernel<<<dim3(TP / 32, 2, B_ * H_), 256, 0, stream>>>(QKVbf, VTb, TP);
    attn4_kernel<<<dim3(TP / 64, H_, B_), 256, 0, stream>>>(QKVbf, VTb, mask, OBbf, TP);
    gemm(TP, D_ / 128, mT, 1, OBbf, D_, 0, WOT + (size_t)i * D_ * D_, D_, D_,
         nullptr, 0, OF, nullptr, nullptr, D_, 0);
    add_ln_kernel<<<B_ * TP, 128, 0, stream>>>(Xf, OF, nullptr, w[4] + (size_t)i * D_,
                                               w[5] + (size_t)i * D_, YT, YTbf, tshift);
    gemm(TP, INTER_ / 128, mT, 1, YTbf, D_, D_, C1T, 3 * D_, 3 * D_,
         w[7] + (size_t)i * INTER_, 1, nullptr, nullptr, MIDbf, INTER_, 0);
    // conv2 split-K=2: slice0 -> OF (QKVbf alias), slice1 -> PT2 (OBbf+VTb span)
    gemm(TP, D_ / 128, mT, 2, MIDbf, INTER_, INTER_, C2T, 3 * INTER_, 3 * INTER_ / 2,
         w[9] + (size_t)i * D_, 0, OF, PT2, nullptr, D_, 0);
    add_ln_kernel<<<B_ * TP, 128, 0, stream>>>(YT, OF, PT2, w[10] + (size_t)i * D_,
                                               w[11] + (size_t)i * D_, Xf, Xbf, tshift);
  };

  // 1) embed + masks + pad zeroing
  embed_kernel<<<(B_ * T_ * D_ + 255) / 256, 256, 0, stream>>>(tokens, emb, XE, XEbf);
  enc_mask_kernel<<<(B_ * T_ + 255) / 256, 256, 0, stream>>>(token_lengths, MASKE);
  zero_pads_kernel<<<B_ * 2, 256, 0, stream>>>(XEbf, T_, D_);
  zero_pads_kernel<<<B_ * 2, 256, 0, stream>>>(YTbf, T_, D_);
  zero_pads_kernel<<<B_ * 2, 256, 0, stream>>>(MIDbf, T_, INTER_);

  // 2) encoder
  tw(encw[0], (long)D_ * HD_, QKVT, (long)QKV_N * D_, D_, HD_, HD_, 0, L_);
  tw(encw[1], (long)D_ * HD_, QKVT, (long)QKV_N * D_, D_, HD_, HD_, 384, L_);
  tw(encw[2], (long)D_ * HD_, QKVT, (long)QKV_N * D_, D_, HD_, HD_, 768, L_);
  tw(encw[3], (long)HD_ * D_, WOT, (long)D_ * D_, HD_, D_, D_, 0, L_);
  for (int i = 0; i < L_; ++i) run_layer(T_, encw, i, XE, XEbf, MASKE);

  // 3) duration predictor
  tw(dp_c1w, 0, DP1T, 0, 3 * D_, D_, D_, 0, 1);
  tw(dp_c2w, 0, DP2T, 0, 3 * D_, D_, D_, 0, 1);
  gemm(128, D_ / 128, B_, 1, XEbf, D_, D_, DP1T, 3 * D_, 3 * D_, dp_c1b, 1,
       OF, nullptr, nullptr, D_, 0);
  add_ln_kernel<<<B_ * T_, 128, 0, stream>>>(OF, nullptr, nullptr, dp_ln1g, dp_ln1b, YT, YTbf, 7);
  gemm(128, D_ / 128, B_, 1, YTbf, D_, D_, DP2T, 3 * D_, 3 * D_, dp_c2b, 1,
       OF, nullptr, nullptr, D_, 0);
  add_ln_kernel<<<B_ * T_, 128, 0, stream>>>(OF, nullptr, nullptr, dp_ln2g, dp_ln2b, YT, nullptr, 7);
  dp_linear_kernel<<<B_ * T_, 64, 0, stream>>>(YT, dp_w, dp_b, out_lp);

  // 4) length regulator
  lr_scan_kernel<<<B_, 32, 0, stream>>>(durations, CS, MEL);
  lr_build_kernel<<<B_, 256, 0, stream>>>(CS, MEL, IDX, MASKD);
  zero_pads_kernel<<<B_ * 2, 256, 0, stream>>>(XDbf, TMEL_, D_);
  zero_pads_kernel<<<B_ * 2, 256, 0, stream>>>(YTbf, TMEL_, D_);
  zero_pads_kernel<<<B_ * 2, 256, 0, stream>>>(MIDbf, TMEL_, INTER_);
  lr_gather_kernel<<<B_ * TMEL_, 128, 0, stream>>>(XE, IDX, XD, XDbf);

  // 5) decoder
  tw(decw[0], (long)D_ * HD_, QKVT, (long)QKV_N * D_, D_, HD_, HD_, 0, L_);
  tw(decw[1], (long)D_ * HD_, QKVT, (long)QKV_N * D_, D_, HD_, HD_, 384, L_);
  tw(decw[2], (long)D_ * HD_, QKVT, (long)QKV_N * D_, D_, HD_, HD_, 768, L_);
  tw(decw[3], (long)HD_ * D_, WOT, (long)D_ * D_, HD_, D_, D_, 0, L_);
  for (int i = 0; i < L_; ++i) run_layer(TMEL_, decw, i, XD, XDbf, MASKD);

  // 6) final projection via MFMA GEMM with transposed mel write
  tw(out_w, 0, OUTT, 0, D_, OUT_C, 128, 0, 1);
  gemm(TMEL_, 1, B_ * TMEL_ / 128, 1, XDbf, D_, 0, OUTT, D_, D_, out_b, 0,
       out0, nullptr, nullptr, 0, 1);
}

// Round 7
// 1497.751 us; speedup vs baseline: 16.2024x; 1.0463x over previous
//
#include <hip/hip_runtime.h>
#include <math.h>

typedef __bf16 bf16;
typedef __attribute__((ext_vector_type(8))) __bf16 bf16x8;
typedef __attribute__((ext_vector_type(4))) float f32x4;

// ---- problem constants ----
constexpr int B_ = 8;
constexpr int T_ = 128;
constexpr int D_ = 384;
constexpr int H_ = 6;
constexpr int DH_ = 64;
constexpr int L_ = 4;
constexpr int INTER_ = 1536;
constexpr int OUT_C = 80;
constexpr int TMEL_ = 1024;
constexpr int HD_ = 384;     // H*DH
constexpr int QKV_N = 1152;  // 3*HD

// ===========================================================================
// Embedding + PE (PE indexed by BATCH per reference quirk): x = 2*emb + pe[b]
// ===========================================================================
__global__ __launch_bounds__(256) void embed_kernel(
    const int* __restrict__ tokens, const float* __restrict__ emb,
    float* __restrict__ X, bf16* __restrict__ Xbf) {
  int i = blockIdx.x * 256 + threadIdx.x;
  if (i >= B_ * T_ * D_) return;
  int d = i % D_;
  int bt = i / D_;
  int b = bt / T_, t = bt % T_;
  int tok = tokens[bt];
  int i2 = d & ~1;
  const float c = 9.210340371976184f / (float)D_;  // ln(10000)/D
  float freq = expf(-(float)i2 * c);
  float ang = (float)b * freq;
  float pe = (d & 1) ? cosf(ang) : sinf(ang);
  float v = 2.0f * emb[(size_t)tok * D_ + d] + pe;
  X[i] = v;
  Xbf[((size_t)b * (T_ + 2) + 1 + t) * D_ + d] = (bf16)v;
}

__global__ void enc_mask_kernel(const int* __restrict__ tl, float* __restrict__ maske) {
  int i = blockIdx.x * 256 + threadIdx.x;
  if (i >= B_ * T_) return;
  int b = i / T_, t = i % T_;
  maske[i] = (t > tl[b]) ? -INFINITY : 0.0f;
}

// ===========================================================================
// Weight transpose: src fp32 [K][N] -> dst bf16 [Ndst + rowOfs][K] row-major.
// ===========================================================================
__global__ __launch_bounds__(256) void transpose_w_kernel(
    const float* __restrict__ src, long srcLS, bf16* __restrict__ dst,
    long dstLS, int K, int N, int rowOfs) {
  src += (size_t)blockIdx.z * srcLS;
  dst += (size_t)blockIdx.z * dstLS;
  __shared__ float tile[32][33];
  const int tx = threadIdx.x & 31, ty = threadIdx.x >> 5;
  const int n0 = blockIdx.x * 32, k0 = blockIdx.y * 32;
#pragma unroll
  for (int j = 0; j < 4; ++j)
    tile[ty + j * 8][tx] =
        (n0 + tx < N) ? src[(size_t)(k0 + ty + j * 8) * N + n0 + tx] : 0.0f;
  __syncthreads();
#pragma unroll
  for (int j = 0; j < 4; ++j)
    dst[(size_t)(n0 + rowOfs + ty + j * 8) * K + k0 + tx] = (bf16)tile[tx][ty + j * 8];
}

// Zero the 2 padding rows per batch of a padded bf16 activation buffer.
__global__ void zero_pads_kernel(bf16* buf, int Tp, int C) {
  int b = blockIdx.x >> 1, side = blockIdx.x & 1;
  size_t row = (size_t)b * (Tp + 2) + (side ? (Tp + 1) : 0);
  for (int c = threadIdx.x; c < C; c += 256) buf[row * C + c] = (bf16)0.0f;
}

// ===========================================================================
// V transpose: QKVbf [b][(T+2)][1152] cols 768.. -> VT [b*6+h][64][T].
// Gated: only key tiles the attention will actually stage (tb < ntiles*2).
// ===========================================================================
__global__ __launch_bounds__(256) void transpose_v_kernel(
    const bf16* __restrict__ QKV, bf16* __restrict__ VT,
    const int* __restrict__ lens, int T) {
  const int tb = blockIdx.x, db = blockIdx.y, bh = blockIdx.z;
  const int b = bh / H_, h = bh % H_;
  const int ntiles = min(T >> 6, (lens[b] + 64) >> 6);
  if (tb >= ntiles * 2) return;
  __shared__ float tile[32][33];
  const int tx = threadIdx.x & 31, ty = threadIdx.x >> 5;
  const size_t src = ((size_t)b * (T + 2) + 1 + tb * 32) * QKV_N + 768 + h * DH_ + db * 32;
#pragma unroll
  for (int j = 0; j < 4; ++j)
    tile[ty + 8 * j][tx] = (float)QKV[src + (size_t)(ty + 8 * j) * QKV_N + tx];
  __syncthreads();
  const size_t dst = ((size_t)(b * H_ + h) * DH_ + db * 32) * T + tb * 32;
#pragma unroll
  for (int j = 0; j < 4; ++j)
    VT[dst + (size_t)(ty + 8 * j) * T + tx] = (bf16)tile[tx][ty + 8 * j];
}

// ===========================================================================
// MFMA bf16 GEMM, 128x128 tile, BK=32, 4 waves (2x2 of 64x64).
// Double-buffered LDS (32 KB total -> 4-5 blocks/CU): stage tile t+1 while
// computing t, one barrier per K-step. Swizzle for 64B rows: cb ^= (row>>1)&3
// (<=2-way bank aliasing = free); source pre-inverse-swizzled (rule 21).
// Split-K via gridDim.z (z==0 -> Cf (+bias), z==1 -> Cf2).
// transC: write fp32 transposed mel output out[(b*OUT_C+col)*TMEL + t].
// ===========================================================================
template <int TP>
__global__ __launch_bounds__(256) void mfma_gemm_kernel(
    const bf16* __restrict__ A, int lda, int aofs,
    const bf16* __restrict__ WT, int ldw, int kslice,
    const float* __restrict__ bias, int relu,
    float* __restrict__ Cf, float* __restrict__ Cf2,
    bf16* __restrict__ Cbf, int ldc, int transC) {
  __shared__ bf16 As[2][128 * 32];
  __shared__ bf16 Bs[2][128 * 32];
  const int tid = threadIdx.x;
  const int lane = tid & 63;
  const int wave = tid >> 6;
  const int wr = wave >> 1, wc = wave & 1;
  const int rowBase = blockIdx.y * 128;
  const int colBase = blockIdx.x * 128;
  const int z = blockIdx.z;
  const int k0beg = z * kslice;
  const int nt = kslice / 32;
  const int bb = rowBase / TP;
  const long pr0 = (long)bb * (TP + 2) + 1 + (rowBase - bb * TP);
  const long abase = pr0 * (long)lda - aofs;

  // staging: slot = e*256+tid; row = slot>>2, cb = slot&3 (16B blocks)
  const int srow = tid >> 2, scb = tid & 3;

  auto stage = [&](int t, int buf) {
    const int k0 = k0beg + t * 32;
#pragma unroll
    for (int e = 0; e < 2; ++e) {
      int idx = e * 256 + tid;
      int lrow = srow + e * 64;
      const bf16* gp = A + abase + (long)lrow * lda + k0 + ((scb ^ ((lrow >> 1) & 3)) << 3);
      __builtin_amdgcn_global_load_lds(
          (const __attribute__((address_space(1))) unsigned int*)gp,
          (__attribute__((address_space(3))) unsigned int*)(As[buf] + idx * 8), 16, 0, 0);
    }
#pragma unroll
    for (int e = 0; e < 2; ++e) {
      int idx = e * 256 + tid;
      int lrow = srow + e * 64;
      const bf16* gp = WT + (long)(colBase + lrow) * ldw + k0 + ((scb ^ ((lrow >> 1) & 3)) << 3);
      __builtin_amdgcn_global_load_lds(
          (const __attribute__((address_space(1))) unsigned int*)gp,
          (__attribute__((address_space(3))) unsigned int*)(Bs[buf] + idx * 8), 16, 0, 0);
    }
  };

  f32x4 acc[4][4] = {};
  const int g = lane >> 4, l15 = lane & 15;

  stage(0, 0);
  __syncthreads();
  for (int t = 0; t < nt; ++t) {
    const int cur = t & 1;
    if (t + 1 < nt) stage(t + 1, cur ^ 1);
    const bf16* Asb = As[cur];
    const bf16* Bsb = Bs[cur];
    bf16x8 af[4], bw[4];
#pragma unroll
    for (int m = 0; m < 4; ++m) {
      int row = wr * 64 + m * 16 + l15;
      int cb = g ^ ((row >> 1) & 3);
      af[m] = *(const bf16x8*)(Asb + row * 32 + cb * 8);
    }
#pragma unroll
    for (int n = 0; n < 4; ++n) {
      int row = wc * 64 + n * 16 + l15;
      int cb = g ^ ((row >> 1) & 3);
      bw[n] = *(const bf16x8*)(Bsb + row * 32 + cb * 8);
    }
#pragma unroll
    for (int m = 0; m < 4; ++m)
#pragma unroll
      for (int n = 0; n < 4; ++n)
        acc[m][n] = __builtin_amdgcn_mfma_f32_16x16x32_bf16(af[m], bw[n], acc[m][n], 0, 0, 0);
    __syncthreads();  // drains this iter's prefetch; guards buffer reuse
  }

  float* Cfz = z ? Cf2 : Cf;
  const float* biasz = z ? nullptr : bias;
  const int qr = (lane >> 4) * 4;
  const int qc = lane & 15;
#pragma unroll
  for (int m = 0; m < 4; ++m) {
    int lrow = wr * 64 + m * 16 + qr;
#pragma unroll
    for (int n = 0; n < 4; ++n) {
      int gcol = colBase + wc * 64 + n * 16 + qc;
      float bv = (biasz && (!transC || gcol < OUT_C)) ? biasz[gcol] : 0.0f;
#pragma unroll
      for (int q = 0; q < 4; ++q) {
        float v = acc[m][n][q] + bv;
        if (relu) v = fmaxf(v, 0.0f);
        if (transC) {
          if (gcol < OUT_C)
            Cfz[((long)bb * OUT_C + gcol) * TMEL_ + (rowBase - bb * TP + lrow + q)] = v;
        } else {
          if (Cfz) Cfz[(long)(rowBase + lrow + q) * ldc + gcol] = v;
          if (Cbf) Cbf[(pr0 + lrow + q) * ldc + gcol] = (bf16)v;
        }
      }
    }
  }
}

// ===========================================================================
// MFMA flash attention with exact key-tile skip: keys > lens[b] are -inf
// masked (softmax weight exactly 0), so only ntiles = (lens[b]+64)/64 tiles.
// ===========================================================================
__global__ __launch_bounds__(256) void attn4_kernel(
    const bf16* __restrict__ QKV, const bf16* __restrict__ VT,
    const float* __restrict__ maskadd, const int* __restrict__ lens,
    bf16* __restrict__ Obf, int T) {
  const int qt = blockIdx.x, h = blockIdx.y, b = blockIdx.z;
  const int tid = threadIdx.x;
  const int lane = tid & 63;
  const int wave = tid >> 6;
  const int l15 = lane & 15, g = lane >> 4;

  __shared__ bf16 Ks[64 * 64];
  __shared__ bf16 Vts[64 * 64];
  __shared__ bf16 Ps[4][16 * 64];
  __shared__ float mask_s[TMEL_];

  const int q0 = qt * 64;
  const size_t brow0 = (size_t)b * (T + 2) + 1;

  for (int i = tid; i < T; i += 256) mask_s[i] = maskadd[(size_t)b * T + i];

  const size_t qrow = brow0 + q0 + wave * 16 + l15;
  bf16x8 qf0 = *(const bf16x8*)(QKV + qrow * QKV_N + h * DH_ + g * 8);
  bf16x8 qf1 = *(const bf16x8*)(QKV + qrow * QKV_N + h * DH_ + g * 8 + 32);

  float mreg[4], lreg[4];
#pragma unroll
  for (int r = 0; r < 4; ++r) { mreg[r] = -INFINITY; lreg[r] = 0.0f; }
  f32x4 oacc[4] = {};
  bf16* Psb = Ps[wave];

  const int nt = min(T >> 6, (lens[b] + 64) >> 6);
  for (int t = 0; t < nt; ++t) {
    const int k0 = t * 64;
#pragma unroll
    for (int it = 0; it < 2; ++it) {
      int c = it * 256 + tid;
      int r = c >> 3, d0 = c & 7;
      bf16x8 kv = *(const bf16x8*)(QKV + (brow0 + k0 + r) * QKV_N + 384 + h * DH_ + d0 * 8);
      *(bf16x8*)(Ks + r * 64 + ((d0 ^ (r & 7)) << 3)) = kv;
      bf16x8 vv = *(const bf16x8*)(VT + ((size_t)(b * H_ + h) * DH_ + r) * T + k0 + d0 * 8);
      *(bf16x8*)(Vts + r * 64 + ((d0 ^ (r & 7)) << 3)) = vv;
    }
    __syncthreads();

    f32x4 sacc[4] = {};
#pragma unroll
    for (int ks = 0; ks < 2; ++ks) {
#pragma unroll
      for (int n = 0; n < 4; ++n) {
        int key = n * 16 + l15;
        bf16x8 bf = *(const bf16x8*)(Ks + key * 64 + (((g + ks * 4) ^ (key & 7)) << 3));
        sacc[n] = __builtin_amdgcn_mfma_f32_16x16x32_bf16(ks ? qf1 : qf0, bf, sacc[n], 0, 0, 0);
      }
    }

    float s[4][4];
    float tm[4] = {-INFINITY, -INFINITY, -INFINITY, -INFINITY};
#pragma unroll
    for (int n = 0; n < 4; ++n) {
      float mv = mask_s[k0 + n * 16 + l15];
#pragma unroll
      for (int r = 0; r < 4; ++r) {
        float v = sacc[n][r] * 0.125f + mv;
        s[n][r] = v;
        tm[r] = fmaxf(tm[r], v);
      }
    }
#pragma unroll
    for (int msk = 1; msk < 16; msk <<= 1)
#pragma unroll
      for (int r = 0; r < 4; ++r) tm[r] = fmaxf(tm[r], __shfl_xor(tm[r], msk));

    float sc[4];
#pragma unroll
    for (int r = 0; r < 4; ++r) {
      float mn = fmaxf(mreg[r], tm[r]);
      sc[r] = __expf(mreg[r] - mn);
      mreg[r] = mn;
    }
    float psum[4] = {0.0f, 0.0f, 0.0f, 0.0f};
#pragma unroll
    for (int n = 0; n < 4; ++n) {
      int key = n * 16 + l15;
      int kblk = key >> 3, kin = key & 7;
#pragma unroll
      for (int r = 0; r < 4; ++r) {
        float p = __expf(s[n][r] - mreg[r]);
        psum[r] += p;
        int q = g * 4 + r;
        Psb[q * 64 + ((kblk ^ (q & 7)) << 3) + kin] = (bf16)p;
      }
    }
#pragma unroll
    for (int msk = 1; msk < 16; msk <<= 1)
#pragma unroll
      for (int r = 0; r < 4; ++r) psum[r] += __shfl_xor(psum[r], msk);
#pragma unroll
    for (int r = 0; r < 4; ++r) lreg[r] = lreg[r] * sc[r] + psum[r];
#pragma unroll
    for (int n = 0; n < 4; ++n)
#pragma unroll
      for (int r = 0; r < 4; ++r) oacc[n][r] *= sc[r];

#pragma unroll
    for (int ks = 0; ks < 2; ++ks) {
      bf16x8 af = *(const bf16x8*)(Psb + l15 * 64 + (((g + ks * 4) ^ (l15 & 7)) << 3));
#pragma unroll
      for (int n = 0; n < 4; ++n) {
        int dh = n * 16 + l15;
        bf16x8 bv = *(const bf16x8*)(Vts + dh * 64 + (((g + ks * 4) ^ (dh & 7)) << 3));
        oacc[n] = __builtin_amdgcn_mfma_f32_16x16x32_bf16(af, bv, oacc[n], 0, 0, 0);
      }
    }
    __syncthreads();
  }

  float inv[4];
#pragma unroll
  for (int r = 0; r < 4; ++r) inv[r] = 1.0f / lreg[r];
  const size_t orow = brow0 + q0 + wave * 16 + g * 4;
#pragma unroll
  for (int n = 0; n < 4; ++n)
#pragma unroll
    for (int r = 0; r < 4; ++r)
      Obf[(orow + r) * D_ + h * DH_ + n * 16 + l15] = (bf16)(oacc[n][r] * inv[r]);
}

// ===========================================================================
// Y = LN(opt-relu(X + H1 + H2)) * g + b. H1/H2 nullable (split-K slices).
// Safe when H1/H2 alias Yf (row-local: all reads before writes).
// ===========================================================================
__global__ __launch_bounds__(128) void add_ln_kernel(
    const float* __restrict__ X, const float* __restrict__ H1,
    const float* __restrict__ H2,
    const float* __restrict__ g, const float* __restrict__ bb,
    float* __restrict__ Yf, bf16* __restrict__ Ybf, int tshift, int relu) {
  const int row = blockIdx.x;
  const int tid = threadIdx.x;
  __shared__ float red[128];
  float v[3];
  float s = 0.0f;
#pragma unroll
  for (int e = 0; e < 3; ++e) {
    int d = tid + e * 128;
    float x = X[(size_t)row * D_ + d];
    if (H1) x += H1[(size_t)row * D_ + d];
    if (H2) x += H2[(size_t)row * D_ + d];
    if (relu) x = fmaxf(x, 0.0f);
    v[e] = x;
    s += x;
  }
  red[tid] = s;
  __syncthreads();
  for (int off = 64; off > 0; off >>= 1) {
    if (tid < off) red[tid] += red[tid + off];
    __syncthreads();
  }
  float mean = red[0] / (float)D_;
  __syncthreads();
  float s2 = 0.0f;
#pragma unroll
  for (int e = 0; e < 3; ++e) {
    float dd = v[e] - mean;
    s2 += dd * dd;
  }
  red[tid] = s2;
  __syncthreads();
  for (int off = 64; off > 0; off >>= 1) {
    if (tid < off) red[tid] += red[tid + off];
    __syncthreads();
  }
  float invstd = rsqrtf(red[0] / (float)D_ + 1e-5f);
  __syncthreads();
  const int b = row >> tshift, t = row & ((1 << tshift) - 1);
  const size_t prow = (size_t)b * ((1 << tshift) + 2) + 1 + t;
#pragma unroll
  for (int e = 0; e < 3; ++e) {
    int d = tid + e * 128;
    float y = (v[e] - mean) * invstd * g[d] + bb[d];
    Yf[(size_t)row * D_ + d] = y;
    if (Ybf) Ybf[prow * D_ + d] = (bf16)y;
  }
}

__global__ __launch_bounds__(64) void dp_linear_kernel(
    const float* __restrict__ Hh, const float* __restrict__ w,
    const float* __restrict__ b0, float* __restrict__ lp) {
  const int row = blockIdx.x;
  const int tid = threadIdx.x;
  float s = 0.0f;
  for (int d = tid; d < D_; d += 64) s += Hh[(size_t)row * D_ + d] * w[d];
#pragma unroll
  for (int off = 32; off > 0; off >>= 1) s += __shfl_down(s, off);
  if (tid == 0) lp[row] = s + b0[0];
}

// ---------------------------------------------------------------------------
// Length regulator
// ---------------------------------------------------------------------------
__global__ void lr_scan_kernel(const int* __restrict__ dur, int* __restrict__ cs,
                               int* __restrict__ mel) {
  int b = blockIdx.x;
  if (threadIdx.x == 0) {
    int s = 0;
    for (int t = 0; t < T_; ++t) {
      s += dur[b * T_ + t];
      cs[b * T_ + t] = s;
    }
    mel[b] = s;
  }
}

__global__ __launch_bounds__(256) void lr_build_kernel(
    const int* __restrict__ cs, const int* __restrict__ mel,
    int* __restrict__ idx, float* __restrict__ maskd) {
  int b = blockIdx.x;
  int mlen = mel[b];
  for (int m = threadIdx.x; m < TMEL_; m += 256) {
    int t = -1;
    if (m < mlen) {
      int lo = 0, hi = T_ - 1;
      while (lo < hi) {
        int mid = (lo + hi) >> 1;
        if (cs[b * T_ + mid] > m) hi = mid; else lo = mid + 1;
      }
      t = lo;
    }
    idx[b * TMEL_ + m] = t;
    maskd[b * TMEL_ + m] = (m > mlen) ? -INFINITY : 0.0f;
  }
}

__global__ __launch_bounds__(128) void lr_gather_kernel(
    const float* __restrict__ XE, const int* __restrict__ idx,
    float* __restrict__ XD, bf16* __restrict__ XDbf) {
  int row = blockIdx.x;
  int b = row / TMEL_, m = row % TMEL_;
  int t = idx[row];
  size_t prow = ((size_t)b * (TMEL_ + 2) + 1 + m) * D_;
  for (int d = threadIdx.x; d < D_; d += 128) {
    float v = (t >= 0) ? XE[((size_t)(b * T_ + t)) * D_ + d] : 0.0f;
    XD[(size_t)row * D_ + d] = v;
    XDbf[prow + d] = (bf16)v;
  }
}

// ===========================================================================
// Host
// ===========================================================================
extern "C" void kernel_launch(void* const* d_in, const int* in_sizes, int n_in,
                              void* d_out, int out_size, void* d_ws, size_t ws_size,
                              hipStream_t stream) {
  const int* tokens = (const int*)d_in[0];
  const int* token_lengths = (const int*)d_in[1];
  const int* durations = (const int*)d_in[2];
  const float* emb = (const float*)d_in[3];
  const float* encw[12];
  const float* decw[12];
  for (int i = 0; i < 12; ++i) encw[i] = (const float*)d_in[4 + i];
  for (int i = 0; i < 12; ++i) decw[i] = (const float*)d_in[16 + i];
  const float* dp_c1w = (const float*)d_in[28];
  const float* dp_c1b = (const float*)d_in[29];
  const float* dp_ln1g = (const float*)d_in[30];
  const float* dp_ln1b = (const float*)d_in[31];
  const float* dp_c2w = (const float*)d_in[32];
  const float* dp_c2b = (const float*)d_in[33];
  const float* dp_ln2g = (const float*)d_in[34];
  const float* dp_ln2b = (const float*)d_in[35];
  const float* dp_w = (const float*)d_in[36];
  const float* dp_b = (const float*)d_in[37];
  const float* out_w = (const float*)d_in[38];
  const float* out_b = (const float*)d_in[39];

  float* out0 = (float*)d_out;                        // [B, OUT, TMEL]
  float* out_lp = out0 + (size_t)B_ * OUT_C * TMEL_;  // [B, T]

  // ---- workspace ----
  char* wsB = (char*)d_ws;
  size_t off = 0;
  auto alloc = [&](size_t bytes) {
    void* p = wsB + off;
    off = (off + bytes + 255) & ~(size_t)255;
    return p;
  };
  float* XE = (float*)alloc((size_t)B_ * T_ * D_ * 4);
  float* XD = (float*)alloc((size_t)B_ * TMEL_ * D_ * 4);
  float* YT = (float*)alloc((size_t)B_ * TMEL_ * D_ * 4);
  bf16* XEbf = (bf16*)alloc((size_t)B_ * (T_ + 2) * D_ * 2);
  bf16* XDbf = (bf16*)alloc((size_t)B_ * (TMEL_ + 2) * D_ * 2);
  bf16* YTbf = (bf16*)alloc((size_t)B_ * (TMEL_ + 2) * D_ * 2);
  bf16* MIDbf = (bf16*)alloc((size_t)B_ * (TMEL_ + 2) * INTER_ * 2);
  bf16* QKVbf = (bf16*)alloc((size_t)B_ * (TMEL_ + 2) * QKV_N * 2);
  bf16* OBbf = (bf16*)alloc((size_t)B_ * (TMEL_ + 2) * D_ * 2);   // 6.30 MB
  bf16* VTb = (bf16*)alloc((size_t)B_ * H_ * DH_ * TMEL_ * 2);    // 6.29 MB, adjacent
  float* OF = (float*)QKVbf;  // fp32 slice-0 out (aliases QKVbf; disjoint lifetime)
  float* PT2 = (float*)OBbf;  // conv2 slice-1: OBbf+VTb contiguous span (both dead)
  float* YTal = (float*)YT;   // WO/dp slice-1: YT dead at those points; add_ln
                              // reads it before rewriting (row-local safe)
  bf16* QKVT = (bf16*)alloc((size_t)L_ * QKV_N * D_ * 2);
  bf16* WOT = (bf16*)alloc((size_t)L_ * D_ * D_ * 2);
  bf16* C1T = (bf16*)alloc((size_t)L_ * INTER_ * (3 * D_) * 2);
  bf16* C2T = (bf16*)alloc((size_t)L_ * D_ * (3 * INTER_) * 2);
  bf16* DP1T = (bf16*)alloc((size_t)D_ * (3 * D_) * 2);
  bf16* DP2T = (bf16*)alloc((size_t)D_ * (3 * D_) * 2);
  bf16* OUTT = (bf16*)alloc((size_t)128 * D_ * 2);
  float* MASKE = (float*)alloc(B_ * T_ * 4);
  float* MASKD = (float*)alloc(B_ * TMEL_ * 4);
  int* CS = (int*)alloc(B_ * T_ * 4);
  int* MEL = (int*)alloc(B_ * 4);
  int* IDX = (int*)alloc(B_ * TMEL_ * 4);

  auto tw = [&](const float* s, long sls, bf16* d, long dls, int K, int N,
                int Ndst, int ro, int Lz) {
    transpose_w_kernel<<<dim3(Ndst / 32, K / 32, Lz), 256, 0, stream>>>(s, sls, d, dls, K, N, ro);
  };
  auto gemm = [&](int TP, int nT, int mT, int nz, const bf16* A, int lda, int aofs,
                  const bf16* WTp, int ldw, int kslice, const float* bias, int relu,
                  float* Cf, float* Cf2, bf16* Cbf, int ldc, int transC) {
    dim3 g(nT, mT, nz);
    if (TP == 128)
      mfma_gemm_kernel<128><<<g, 256, 0, stream>>>(A, lda, aofs, WTp, ldw, kslice,
                                                   bias, relu, Cf, Cf2, Cbf, ldc, transC);
    else
      mfma_gemm_kernel<1024><<<g, 256, 0, stream>>>(A, lda, aofs, WTp, ldw, kslice,
                                                    bias, relu, Cf, Cf2, Cbf, ldc, transC);
  };

  auto run_layer = [&](int TP, const float* const* w, int i, float* Xf, bf16* Xbf,
                       const float* mask, const int* lens) {
    const int mT = B_ * TP / 128;
    const int tshift = (TP == 128) ? 7 : 10;
    gemm(TP, QKV_N / 128, mT, 1, Xbf, D_, 0, QKVT + (size_t)i * QKV_N * D_, D_, D_,
         nullptr, 0, nullptr, nullptr, QKVbf, QKV_N, 0);
    transpose_v_kernel<<<dim3(TP / 32, 2, B_ * H_), 256, 0, stream>>>(QKVbf, VTb, lens, TP);
    attn4_kernel<<<dim3(TP / 64, H_, B_), 256, 0, stream>>>(QKVbf, VTb, mask, lens, OBbf, TP);
    // WO split-K=2: slice0 -> OF, slice1 -> YTal (YT dead; ln reads then rewrites)
    gemm(TP, D_ / 128, mT, 2, OBbf, D_, 0, WOT + (size_t)i * D_ * D_, D_, D_ / 2,
         nullptr, 0, OF, YTal, nullptr, D_, 0);
    add_ln_kernel<<<B_ * TP, 128, 0, stream>>>(Xf, OF, YTal, w[4] + (size_t)i * D_,
                                               w[5] + (size_t)i * D_, YT, YTbf, tshift, 0);
    gemm(TP, INTER_ / 128, mT, 1, YTbf, D_, D_, C1T + (size_t)i * INTER_ * 3 * D_, 3 * D_,
         3 * D_, w[7] + (size_t)i * INTER_, 1, nullptr, nullptr, MIDbf, INTER_, 0);
    // conv2 split-K=2: slice0 -> OF, slice1 -> PT2 (OBbf+VTb span)
    gemm(TP, D_ / 128, mT, 2, MIDbf, INTER_, INTER_, C2T + (size_t)i * D_ * 3 * INTER_,
         3 * INTER_, 3 * INTER_ / 2, w[9] + (size_t)i * D_, 0, OF, PT2, nullptr, D_, 0);
    add_ln_kernel<<<B_ * TP, 128, 0, stream>>>(YT, OF, PT2, w[10] + (size_t)i * D_,
                                               w[11] + (size_t)i * D_, Xf, Xbf, tshift, 0);
  };

  // 1) embed + masks + pad zeroing
  embed_kernel<<<(B_ * T_ * D_ + 255) / 256, 256, 0, stream>>>(tokens, emb, XE, XEbf);
  enc_mask_kernel<<<(B_ * T_ + 255) / 256, 256, 0, stream>>>(token_lengths, MASKE);
  zero_pads_kernel<<<B_ * 2, 256, 0, stream>>>(XEbf, T_, D_);
  zero_pads_kernel<<<B_ * 2, 256, 0, stream>>>(YTbf, T_, D_);
  zero_pads_kernel<<<B_ * 2, 256, 0, stream>>>(MIDbf, T_, INTER_);

  // 2) encoder weights (batched) + stack
  tw(encw[0], (long)D_ * HD_, QKVT, (long)QKV_N * D_, D_, HD_, HD_, 0, L_);
  tw(encw[1], (long)D_ * HD_, QKVT, (long)QKV_N * D_, D_, HD_, HD_, 384, L_);
  tw(encw[2], (long)D_ * HD_, QKVT, (long)QKV_N * D_, D_, HD_, HD_, 768, L_);
  tw(encw[3], (long)HD_ * D_, WOT, (long)D_ * D_, HD_, D_, D_, 0, L_);
  tw(encw[6], (long)3 * D_ * INTER_, C1T, (long)INTER_ * 3 * D_, 3 * D_, INTER_, INTER_, 0, L_);
  tw(encw[8], (long)3 * INTER_ * D_, C2T, (long)D_ * 3 * INTER_, 3 * INTER_, D_, D_, 0, L_);
  for (int i = 0; i < L_; ++i) run_layer(T_, encw, i, XE, XEbf, MASKE, token_lengths);

  // 3) duration predictor (split-K=2, relu moved into add_ln)
  tw(dp_c1w, 0, DP1T, 0, 3 * D_, D_, D_, 0, 1);
  tw(dp_c2w, 0, DP2T, 0, 3 * D_, D_, D_, 0, 1);
  gemm(128, D_ / 128, B_, 2, XEbf, D_, D_, DP1T, 3 * D_, 3 * D_ / 2, dp_c1b, 0,
       OF, YTal, nullptr, D_, 0);
  add_ln_kernel<<<B_ * T_, 128, 0, stream>>>(OF, YTal, nullptr, dp_ln1g, dp_ln1b,
                                             YT, YTbf, 7, 1);
  gemm(128, D_ / 128, B_, 2, YTbf, D_, D_, DP2T, 3 * D_, 3 * D_ / 2, dp_c2b, 0,
       OF, YTal, nullptr, D_, 0);
  add_ln_kernel<<<B_ * T_, 128, 0, stream>>>(OF, YTal, nullptr, dp_ln2g, dp_ln2b,
                                             YT, nullptr, 7, 1);
  dp_linear_kernel<<<B_ * T_, 64, 0, stream>>>(YT, dp_w, dp_b, out_lp);

  // 4) length regulator
  lr_scan_kernel<<<B_, 32, 0, stream>>>(durations, CS, MEL);
  lr_build_kernel<<<B_, 256, 0, stream>>>(CS, MEL, IDX, MASKD);
  zero_pads_kernel<<<B_ * 2, 256, 0, stream>>>(XDbf, TMEL_, D_);
  zero_pads_kernel<<<B_ * 2, 256, 0, stream>>>(YTbf, TMEL_, D_);
  zero_pads_kernel<<<B_ * 2, 256, 0, stream>>>(MIDbf, TMEL_, INTER_);
  lr_gather_kernel<<<B_ * TMEL_, 128, 0, stream>>>(XE, IDX, XD, XDbf);

  // 5) decoder weights (batched) + stack
  tw(decw[0], (long)D_ * HD_, QKVT, (long)QKV_N * D_, D_, HD_, HD_, 0, L_);
  tw(decw[1], (long)D_ * HD_, QKVT, (long)QKV_N * D_, D_, HD_, HD_, 384, L_);
  tw(decw[2], (long)D_ * HD_, QKVT, (long)QKV_N * D_, D_, HD_, HD_, 768, L_);
  tw(decw[3], (long)HD_ * D_, WOT, (long)D_ * D_, HD_, D_, D_, 0, L_);
  tw(decw[6], (long)3 * D_ * INTER_, C1T, (long)INTER_ * 3 * D_, 3 * D_, INTER_, INTER_, 0, L_);
  tw(decw[8], (long)3 * INTER_ * D_, C2T, (long)D_ * 3 * INTER_, 3 * INTER_, D_, D_, 0, L_);
  for (int i = 0; i < L_; ++i) run_layer(TMEL_, decw, i, XD, XDbf, MASKD, MEL);

  // 6) final projection via MFMA GEMM with transposed mel write
  tw(out_w, 0, OUTT, 0, D_, OUT_C, 128, 0, 1);
  gemm(TMEL_, 1, B_ * TMEL_ / 128, 1, XDbf, D_, 0, OUTT, D_, D_, out_b, 0,
       out0, nullptr, nullptr, 0, 1);
}

// Round 8
// 1452.561 us; speedup vs baseline: 16.7065x; 1.0311x over previous
//
#include <hip/hip_runtime.h>
#include <math.h>

typedef __bf16 bf16;
typedef __attribute__((ext_vector_type(8))) __bf16 bf16x8;
typedef __attribute__((ext_vector_type(4))) float f32x4;

// ---- problem constants ----
constexpr int B_ = 8;
constexpr int T_ = 128;
constexpr int D_ = 384;
constexpr int H_ = 6;
constexpr int DH_ = 64;
constexpr int L_ = 4;
constexpr int INTER_ = 1536;
constexpr int OUT_C = 80;
constexpr int TMEL_ = 1024;
constexpr int HD_ = 384;     // H*DH
constexpr int QKV_N = 1152;  // 3*HD

// XCD-aware chunked swizzle (T1): bijective when nwg%8==0; identity otherwise.
__device__ __forceinline__ int xcd_swizzle(int bid, int nwg) {
  if (nwg & 7) return bid;
  return (bid & 7) * (nwg >> 3) + (bid >> 3);
}

// ===========================================================================
// Embedding + PE (PE indexed by BATCH per reference quirk): x = 2*emb + pe[b]
// ===========================================================================
__global__ __launch_bounds__(256) void embed_kernel(
    const int* __restrict__ tokens, const float* __restrict__ emb,
    float* __restrict__ X, bf16* __restrict__ Xbf) {
  int i = blockIdx.x * 256 + threadIdx.x;
  if (i >= B_ * T_ * D_) return;
  int d = i % D_;
  int bt = i / D_;
  int b = bt / T_, t = bt % T_;
  int tok = tokens[bt];
  int i2 = d & ~1;
  const float c = 9.210340371976184f / (float)D_;  // ln(10000)/D
  float freq = expf(-(float)i2 * c);
  float ang = (float)b * freq;
  float pe = (d & 1) ? cosf(ang) : sinf(ang);
  float v = 2.0f * emb[(size_t)tok * D_ + d] + pe;
  X[i] = v;
  Xbf[((size_t)b * (T_ + 2) + 1 + t) * D_ + d] = (bf16)v;
}

__global__ void enc_mask_kernel(const int* __restrict__ tl, float* __restrict__ maske) {
  int i = blockIdx.x * 256 + threadIdx.x;
  if (i >= B_ * T_) return;
  int b = i / T_, t = i % T_;
  maske[i] = (t > tl[b]) ? -INFINITY : 0.0f;
}

// ===========================================================================
// Weight transpose: src fp32 [K][N] -> dst bf16 [Ndst + rowOfs][K] row-major.
// ===========================================================================
__global__ __launch_bounds__(256) void transpose_w_kernel(
    const float* __restrict__ src, long srcLS, bf16* __restrict__ dst,
    long dstLS, int K, int N, int rowOfs) {
  src += (size_t)blockIdx.z * srcLS;
  dst += (size_t)blockIdx.z * dstLS;
  __shared__ float tile[32][33];
  const int tx = threadIdx.x & 31, ty = threadIdx.x >> 5;
  const int n0 = blockIdx.x * 32, k0 = blockIdx.y * 32;
#pragma unroll
  for (int j = 0; j < 4; ++j)
    tile[ty + j * 8][tx] =
        (n0 + tx < N) ? src[(size_t)(k0 + ty + j * 8) * N + n0 + tx] : 0.0f;
  __syncthreads();
#pragma unroll
  for (int j = 0; j < 4; ++j)
    dst[(size_t)(n0 + rowOfs + ty + j * 8) * K + k0 + tx] = (bf16)tile[tx][ty + j * 8];
}

// Zero the 2 padding rows per batch of a padded bf16 activation buffer.
__global__ void zero_pads_kernel(bf16* buf, int Tp, int C) {
  int b = blockIdx.x >> 1, side = blockIdx.x & 1;
  size_t row = (size_t)b * (Tp + 2) + (side ? (Tp + 1) : 0);
  for (int c = threadIdx.x; c < C; c += 256) buf[row * C + c] = (bf16)0.0f;
}

// ===========================================================================
// V transpose: QKVbf [b][(T+2)][1152] cols 768.. -> VT [b*6+h][64][T].
// Gated: only key tiles the attention will actually stage (tb < ntiles*2).
// ===========================================================================
__global__ __launch_bounds__(256) void transpose_v_kernel(
    const bf16* __restrict__ QKV, bf16* __restrict__ VT,
    const int* __restrict__ lens, int T) {
  const int tb = blockIdx.x, db = blockIdx.y, bh = blockIdx.z;
  const int b = bh / H_, h = bh % H_;
  const int ntiles = min(T >> 6, (lens[b] + 64) >> 6);
  if (tb >= ntiles * 2) return;
  __shared__ float tile[32][33];
  const int tx = threadIdx.x & 31, ty = threadIdx.x >> 5;
  const size_t src = ((size_t)b * (T + 2) + 1 + tb * 32) * QKV_N + 768 + h * DH_ + db * 32;
#pragma unroll
  for (int j = 0; j < 4; ++j)
    tile[ty + 8 * j][tx] = (float)QKV[src + (size_t)(ty + 8 * j) * QKV_N + tx];
  __syncthreads();
  const size_t dst = ((size_t)(b * H_ + h) * DH_ + db * 32) * T + tb * 32;
#pragma unroll
  for (int j = 0; j < 4; ++j)
    VT[dst + (size_t)(ty + 8 * j) * T + tx] = (bf16)tile[tx][ty + 8 * j];
}

// ===========================================================================
// MFMA bf16 GEMM, 128x128 tile, BK=32, 4 waves (2x2 of 64x64).
// Double-buffered LDS; XCD-chunked block swizzle (x fastest within chunk ->
// A-panel reused within one XCD's L2, W panel L2-resident per XCD).
// Split-K via z (z==0 -> Cf (+bias), z==1 -> Cf2).
// transC: write fp32 transposed mel output out[(b*OUT_C+col)*TMEL + t].
// ===========================================================================
template <int TP>
__global__ __launch_bounds__(256) void mfma_gemm_kernel(
    const bf16* __restrict__ A, int lda, int aofs,
    const bf16* __restrict__ WT, int ldw, int kslice,
    const float* __restrict__ bias, int relu,
    float* __restrict__ Cf, float* __restrict__ Cf2,
    bf16* __restrict__ Cbf, int ldc, int transC) {
  __shared__ bf16 As[2][128 * 32];
  __shared__ bf16 Bs[2][128 * 32];
  const int tid = threadIdx.x;
  const int lane = tid & 63;
  const int wave = tid >> 6;
  const int wr = wave >> 1, wc = wave & 1;

  // ---- XCD swizzle: decode (bx, by, z) from chunked work id ----
  const int nT = gridDim.x, mT = gridDim.y;
  const int nwg = nT * mT * gridDim.z;
  int bid = blockIdx.x + nT * (blockIdx.y + mT * blockIdx.z);
  int wid = xcd_swizzle(bid, nwg);
  const int bx = wid % nT;
  int tmp = wid / nT;
  const int by = tmp % mT;
  const int z = tmp / mT;

  const int rowBase = by * 128;
  const int colBase = bx * 128;
  const int k0beg = z * kslice;
  const int nt = kslice / 32;
  const int bb = rowBase / TP;
  const long pr0 = (long)bb * (TP + 2) + 1 + (rowBase - bb * TP);
  const long abase = pr0 * (long)lda - aofs;

  const int srow = tid >> 2, scb = tid & 3;

  auto stage = [&](int t, int buf) {
    const int k0 = k0beg + t * 32;
#pragma unroll
    for (int e = 0; e < 2; ++e) {
      int idx = e * 256 + tid;
      int lrow = srow + e * 64;
      const bf16* gp = A + abase + (long)lrow * lda + k0 + ((scb ^ ((lrow >> 1) & 3)) << 3);
      __builtin_amdgcn_global_load_lds(
          (const __attribute__((address_space(1))) unsigned int*)gp,
          (__attribute__((address_space(3))) unsigned int*)(As[buf] + idx * 8), 16, 0, 0);
    }
#pragma unroll
    for (int e = 0; e < 2; ++e) {
      int idx = e * 256 + tid;
      int lrow = srow + e * 64;
      const bf16* gp = WT + (long)(colBase + lrow) * ldw + k0 + ((scb ^ ((lrow >> 1) & 3)) << 3);
      __builtin_amdgcn_global_load_lds(
          (const __attribute__((address_space(1))) unsigned int*)gp,
          (__attribute__((address_space(3))) unsigned int*)(Bs[buf] + idx * 8), 16, 0, 0);
    }
  };

  f32x4 acc[4][4] = {};
  const int g = lane >> 4, l15 = lane & 15;

  stage(0, 0);
  __syncthreads();
  for (int t = 0; t < nt; ++t) {
    const int cur = t & 1;
    if (t + 1 < nt) stage(t + 1, cur ^ 1);
    const bf16* Asb = As[cur];
    const bf16* Bsb = Bs[cur];
    bf16x8 af[4], bw[4];
#pragma unroll
    for (int m = 0; m < 4; ++m) {
      int row = wr * 64 + m * 16 + l15;
      int cb = g ^ ((row >> 1) & 3);
      af[m] = *(const bf16x8*)(Asb + row * 32 + cb * 8);
    }
#pragma unroll
    for (int n = 0; n < 4; ++n) {
      int row = wc * 64 + n * 16 + l15;
      int cb = g ^ ((row >> 1) & 3);
      bw[n] = *(const bf16x8*)(Bsb + row * 32 + cb * 8);
    }
#pragma unroll
    for (int m = 0; m < 4; ++m)
#pragma unroll
      for (int n = 0; n < 4; ++n)
        acc[m][n] = __builtin_amdgcn_mfma_f32_16x16x32_bf16(af[m], bw[n], acc[m][n], 0, 0, 0);
    __syncthreads();  // drains this iter's prefetch; guards buffer reuse
  }

  float* Cfz = z ? Cf2 : Cf;
  const float* biasz = z ? nullptr : bias;
  const int qr = (lane >> 4) * 4;
  const int qc = lane & 15;
#pragma unroll
  for (int m = 0; m < 4; ++m) {
    int lrow = wr * 64 + m * 16 + qr;
#pragma unroll
    for (int n = 0; n < 4; ++n) {
      int gcol = colBase + wc * 64 + n * 16 + qc;
      float bv = (biasz && (!transC || gcol < OUT_C)) ? biasz[gcol] : 0.0f;
#pragma unroll
      for (int q = 0; q < 4; ++q) {
        float v = acc[m][n][q] + bv;
        if (relu) v = fmaxf(v, 0.0f);
        if (transC) {
          if (gcol < OUT_C)
            Cfz[((long)bb * OUT_C + gcol) * TMEL_ + (rowBase - bb * TP + lrow + q)] = v;
        } else {
          if (Cfz) Cfz[(long)(rowBase + lrow + q) * ldc + gcol] = v;
          if (Cbf) Cbf[(pr0 + lrow + q) * ldc + gcol] = (bf16)v;
        }
      }
    }
  }
}

// ===========================================================================
// MFMA flash attention with exact key-tile skip + XCD-chunked swizzle
// (qt fastest within chunk -> each XCD keeps one batch's K/V in its L2).
// ===========================================================================
__global__ __launch_bounds__(256) void attn4_kernel(
    const bf16* __restrict__ QKV, const bf16* __restrict__ VT,
    const float* __restrict__ maskadd, const int* __restrict__ lens,
    bf16* __restrict__ Obf, int T) {
  const int nQT = gridDim.x;
  const int nwg = nQT * H_ * B_;
  int bid = blockIdx.x + nQT * (blockIdx.y + H_ * blockIdx.z);
  int wid = xcd_swizzle(bid, nwg);
  const int qt = wid % nQT;
  int tmp = wid / nQT;
  const int h = tmp % H_;
  const int b = tmp / H_;

  const int tid = threadIdx.x;
  const int lane = tid & 63;
  const int wave = tid >> 6;
  const int l15 = lane & 15, g = lane >> 4;

  __shared__ bf16 Ks[64 * 64];
  __shared__ bf16 Vts[64 * 64];
  __shared__ bf16 Ps[4][16 * 64];
  __shared__ float mask_s[TMEL_];

  const int q0 = qt * 64;
  const size_t brow0 = (size_t)b * (T + 2) + 1;

  for (int i = tid; i < T; i += 256) mask_s[i] = maskadd[(size_t)b * T + i];

  const size_t qrow = brow0 + q0 + wave * 16 + l15;
  bf16x8 qf0 = *(const bf16x8*)(QKV + qrow * QKV_N + h * DH_ + g * 8);
  bf16x8 qf1 = *(const bf16x8*)(QKV + qrow * QKV_N + h * DH_ + g * 8 + 32);

  float mreg[4], lreg[4];
#pragma unroll
  for (int r = 0; r < 4; ++r) { mreg[r] = -INFINITY; lreg[r] = 0.0f; }
  f32x4 oacc[4] = {};
  bf16* Psb = Ps[wave];

  const int nt = min(T >> 6, (lens[b] + 64) >> 6);
  for (int t = 0; t < nt; ++t) {
    const int k0 = t * 64;
#pragma unroll
    for (int it = 0; it < 2; ++it) {
      int c = it * 256 + tid;
      int r = c >> 3, d0 = c & 7;
      bf16x8 kv = *(const bf16x8*)(QKV + (brow0 + k0 + r) * QKV_N + 384 + h * DH_ + d0 * 8);
      *(bf16x8*)(Ks + r * 64 + ((d0 ^ (r & 7)) << 3)) = kv;
      bf16x8 vv = *(const bf16x8*)(VT + ((size_t)(b * H_ + h) * DH_ + r) * T + k0 + d0 * 8);
      *(bf16x8*)(Vts + r * 64 + ((d0 ^ (r & 7)) << 3)) = vv;
    }
    __syncthreads();

    f32x4 sacc[4] = {};
#pragma unroll
    for (int ks = 0; ks < 2; ++ks) {
#pragma unroll
      for (int n = 0; n < 4; ++n) {
        int key = n * 16 + l15;
        bf16x8 bf = *(const bf16x8*)(Ks + key * 64 + (((g + ks * 4) ^ (key & 7)) << 3));
        sacc[n] = __builtin_amdgcn_mfma_f32_16x16x32_bf16(ks ? qf1 : qf0, bf, sacc[n], 0, 0, 0);
      }
    }

    float s[4][4];
    float tm[4] = {-INFINITY, -INFINITY, -INFINITY, -INFINITY};
#pragma unroll
    for (int n = 0; n < 4; ++n) {
      float mv = mask_s[k0 + n * 16 + l15];
#pragma unroll
      for (int r = 0; r < 4; ++r) {
        float v = sacc[n][r] * 0.125f + mv;
        s[n][r] = v;
        tm[r] = fmaxf(tm[r], v);
      }
    }
#pragma unroll
    for (int msk = 1; msk < 16; msk <<= 1)
#pragma unroll
      for (int r = 0; r < 4; ++r) tm[r] = fmaxf(tm[r], __shfl_xor(tm[r], msk));

    float sc[4];
#pragma unroll
    for (int r = 0; r < 4; ++r) {
      float mn = fmaxf(mreg[r], tm[r]);
      sc[r] = __expf(mreg[r] - mn);
      mreg[r] = mn;
    }
    float psum[4] = {0.0f, 0.0f, 0.0f, 0.0f};
#pragma unroll
    for (int n = 0; n < 4; ++n) {
      int key = n * 16 + l15;
      int kblk = key >> 3, kin = key & 7;
#pragma unroll
      for (int r = 0; r < 4; ++r) {
        float p = __expf(s[n][r] - mreg[r]);
        psum[r] += p;
        int q = g * 4 + r;
        Psb[q * 64 + ((kblk ^ (q & 7)) << 3) + kin] = (bf16)p;
      }
    }
#pragma unroll
    for (int msk = 1; msk < 16; msk <<= 1)
#pragma unroll
      for (int r = 0; r < 4; ++r) psum[r] += __shfl_xor(psum[r], msk);
#pragma unroll
    for (int r = 0; r < 4; ++r) lreg[r] = lreg[r] * sc[r] + psum[r];
#pragma unroll
    for (int n = 0; n < 4; ++n)
#pragma unroll
      for (int r = 0; r < 4; ++r) oacc[n][r] *= sc[r];

#pragma unroll
    for (int ks = 0; ks < 2; ++ks) {
      bf16x8 af = *(const bf16x8*)(Psb + l15 * 64 + (((g + ks * 4) ^ (l15 & 7)) << 3));
#pragma unroll
      for (int n = 0; n < 4; ++n) {
        int dh = n * 16 + l15;
        bf16x8 bv = *(const bf16x8*)(Vts + dh * 64 + (((g + ks * 4) ^ (dh & 7)) << 3));
        oacc[n] = __builtin_amdgcn_mfma_f32_16x16x32_bf16(af, bv, oacc[n], 0, 0, 0);
      }
    }
    __syncthreads();
  }

  float inv[4];
#pragma unroll
  for (int r = 0; r < 4; ++r) inv[r] = 1.0f / lreg[r];
  const size_t orow = brow0 + q0 + wave * 16 + g * 4;
#pragma unroll
  for (int n = 0; n < 4; ++n)
#pragma unroll
    for (int r = 0; r < 4; ++r)
      Obf[(orow + r) * D_ + h * DH_ + n * 16 + l15] = (bf16)(oacc[n][r] * inv[r]);
}

// ===========================================================================
// Y = LN(opt-relu(X + H1 + H2)) * g + b. H1/H2 nullable (split-K slices).
// Safe when H1/H2 alias Yf (row-local: all reads before writes).
// ===========================================================================
__global__ __launch_bounds__(128) void add_ln_kernel(
    const float* __restrict__ X, const float* __restrict__ H1,
    const float* __restrict__ H2,
    const float* __restrict__ g, const float* __restrict__ bb,
    float* __restrict__ Yf, bf16* __restrict__ Ybf, int tshift, int relu) {
  const int row = blockIdx.x;
  const int tid = threadIdx.x;
  __shared__ float red[128];
  float v[3];
  float s = 0.0f;
#pragma unroll
  for (int e = 0; e < 3; ++e) {
    int d = tid + e * 128;
    float x = X[(size_t)row * D_ + d];
    if (H1) x += H1[(size_t)row * D_ + d];
    if (H2) x += H2[(size_t)row * D_ + d];
    if (relu) x = fmaxf(x, 0.0f);
    v[e] = x;
    s += x;
  }
  red[tid] = s;
  __syncthreads();
  for (int off = 64; off > 0; off >>= 1) {
    if (tid < off) red[tid] += red[tid + off];
    __syncthreads();
  }
  float mean = red[0] / (float)D_;
  __syncthreads();
  float s2 = 0.0f;
#pragma unroll
  for (int e = 0; e < 3; ++e) {
    float dd = v[e] - mean;
    s2 += dd * dd;
  }
  red[tid] = s2;
  __syncthreads();
  for (int off = 64; off > 0; off >>= 1) {
    if (tid < off) red[tid] += red[tid + off];
    __syncthreads();
  }
  float invstd = rsqrtf(red[0] / (float)D_ + 1e-5f);
  __syncthreads();
  const int b = row >> tshift, t = row & ((1 << tshift) - 1);
  const size_t prow = (size_t)b * ((1 << tshift) + 2) + 1 + t;
#pragma unroll
  for (int e = 0; e < 3; ++e) {
    int d = tid + e * 128;
    float y = (v[e] - mean) * invstd * g[d] + bb[d];
    Yf[(size_t)row * D_ + d] = y;
    if (Ybf) Ybf[prow * D_ + d] = (bf16)y;
  }
}

__global__ __launch_bounds__(64) void dp_linear_kernel(
    const float* __restrict__ Hh, const float* __restrict__ w,
    const float* __restrict__ b0, float* __restrict__ lp) {
  const int row = blockIdx.x;
  const int tid = threadIdx.x;
  float s = 0.0f;
  for (int d = tid; d < D_; d += 64) s += Hh[(size_t)row * D_ + d] * w[d];
#pragma unroll
  for (int off = 32; off > 0; off >>= 1) s += __shfl_down(s, off);
  if (tid == 0) lp[row] = s + b0[0];
}

// ---------------------------------------------------------------------------
// Length regulator
// ---------------------------------------------------------------------------
__global__ void lr_scan_kernel(const int* __restrict__ dur, int* __restrict__ cs,
                               int* __restrict__ mel) {
  int b = blockIdx.x;
  if (threadIdx.x == 0) {
    int s = 0;
    for (int t = 0; t < T_; ++t) {
      s += dur[b * T_ + t];
      cs[b * T_ + t] = s;
    }
    mel[b] = s;
  }
}

__global__ __launch_bounds__(256) void lr_build_kernel(
    const int* __restrict__ cs, const int* __restrict__ mel,
    int* __restrict__ idx, float* __restrict__ maskd) {
  int b = blockIdx.x;
  int mlen = mel[b];
  for (int m = threadIdx.x; m < TMEL_; m += 256) {
    int t = -1;
    if (m < mlen) {
      int lo = 0, hi = T_ - 1;
      while (lo < hi) {
        int mid = (lo + hi) >> 1;
        if (cs[b * T_ + mid] > m) hi = mid; else lo = mid + 1;
      }
      t = lo;
    }
    idx[b * TMEL_ + m] = t;
    maskd[b * TMEL_ + m] = (m > mlen) ? -INFINITY : 0.0f;
  }
}

__global__ __launch_bounds__(128) void lr_gather_kernel(
    const float* __restrict__ XE, const int* __restrict__ idx,
    float* __restrict__ XD, bf16* __restrict__ XDbf) {
  int row = blockIdx.x;
  int b = row / TMEL_, m = row % TMEL_;
  int t = idx[row];
  size_t prow = ((size_t)b * (TMEL_ + 2) + 1 + m) * D_;
  for (int d = threadIdx.x; d < D_; d += 128) {
    float v = (t >= 0) ? XE[((size_t)(b * T_ + t)) * D_ + d] : 0.0f;
    XD[(size_t)row * D_ + d] = v;
    XDbf[prow + d] = (bf16)v;
  }
}

// ===========================================================================
// Host
// ===========================================================================
extern "C" void kernel_launch(void* const* d_in, const int* in_sizes, int n_in,
                              void* d_out, int out_size, void* d_ws, size_t ws_size,
                              hipStream_t stream) {
  const int* tokens = (const int*)d_in[0];
  const int* token_lengths = (const int*)d_in[1];
  const int* durations = (const int*)d_in[2];
  const float* emb = (const float*)d_in[3];
  const float* encw[12];
  const float* decw[12];
  for (int i = 0; i < 12; ++i) encw[i] = (const float*)d_in[4 + i];
  for (int i = 0; i < 12; ++i) decw[i] = (const float*)d_in[16 + i];
  const float* dp_c1w = (const float*)d_in[28];
  const float* dp_c1b = (const float*)d_in[29];
  const float* dp_ln1g = (const float*)d_in[30];
  const float* dp_ln1b = (const float*)d_in[31];
  const float* dp_c2w = (const float*)d_in[32];
  const float* dp_c2b = (const float*)d_in[33];
  const float* dp_ln2g = (const float*)d_in[34];
  const float* dp_ln2b = (const float*)d_in[35];
  const float* dp_w = (const float*)d_in[36];
  const float* dp_b = (const float*)d_in[37];
  const float* out_w = (const float*)d_in[38];
  const float* out_b = (const float*)d_in[39];

  float* out0 = (float*)d_out;                        // [B, OUT, TMEL]
  float* out_lp = out0 + (size_t)B_ * OUT_C * TMEL_;  // [B, T]

  // ---- workspace ----
  char* wsB = (char*)d_ws;
  size_t off = 0;
  auto alloc = [&](size_t bytes) {
    void* p = wsB + off;
    off = (off + bytes + 255) & ~(size_t)255;
    return p;
  };
  float* XE = (float*)alloc((size_t)B_ * T_ * D_ * 4);
  float* XD = (float*)alloc((size_t)B_ * TMEL_ * D_ * 4);
  float* YT = (float*)alloc((size_t)B_ * TMEL_ * D_ * 4);
  bf16* XEbf = (bf16*)alloc((size_t)B_ * (T_ + 2) * D_ * 2);
  bf16* XDbf = (bf16*)alloc((size_t)B_ * (TMEL_ + 2) * D_ * 2);
  bf16* YTbf = (bf16*)alloc((size_t)B_ * (TMEL_ + 2) * D_ * 2);
  bf16* MIDbf = (bf16*)alloc((size_t)B_ * (TMEL_ + 2) * INTER_ * 2);
  bf16* QKVbf = (bf16*)alloc((size_t)B_ * (TMEL_ + 2) * QKV_N * 2);
  bf16* OBbf = (bf16*)alloc((size_t)B_ * (TMEL_ + 2) * D_ * 2);   // 6.30 MB
  bf16* VTb = (bf16*)alloc((size_t)B_ * H_ * DH_ * TMEL_ * 2);    // 6.29 MB, adjacent
  float* OF = (float*)QKVbf;  // fp32 slice-0 out (aliases QKVbf; disjoint lifetime)
  float* PT2 = (float*)OBbf;  // conv2 slice-1: OBbf+VTb contiguous span (both dead)
  float* YTal = (float*)YT;   // WO/dp slice-1: YT dead at those points; add_ln
                              // reads it before rewriting (row-local safe)
  bf16* QKVT = (bf16*)alloc((size_t)L_ * QKV_N * D_ * 2);
  bf16* WOT = (bf16*)alloc((size_t)L_ * D_ * D_ * 2);
  bf16* C1T = (bf16*)alloc((size_t)L_ * INTER_ * (3 * D_) * 2);
  bf16* C2T = (bf16*)alloc((size_t)L_ * D_ * (3 * INTER_) * 2);
  bf16* DP1T = (bf16*)alloc((size_t)D_ * (3 * D_) * 2);
  bf16* DP2T = (bf16*)alloc((size_t)D_ * (3 * D_) * 2);
  bf16* OUTT = (bf16*)alloc((size_t)128 * D_ * 2);
  float* MASKE = (float*)alloc(B_ * T_ * 4);
  float* MASKD = (float*)alloc(B_ * TMEL_ * 4);
  int* CS = (int*)alloc(B_ * T_ * 4);
  int* MEL = (int*)alloc(B_ * 4);
  int* IDX = (int*)alloc(B_ * TMEL_ * 4);

  auto tw = [&](const float* s, long sls, bf16* d, long dls, int K, int N,
                int Ndst, int ro, int Lz) {
    transpose_w_kernel<<<dim3(Ndst / 32, K / 32, Lz), 256, 0, stream>>>(s, sls, d, dls, K, N, ro);
  };
  auto gemm = [&](int TP, int nT, int mT, int nz, const bf16* A, int lda, int aofs,
                  const bf16* WTp, int ldw, int kslice, const float* bias, int relu,
                  float* Cf, float* Cf2, bf16* Cbf, int ldc, int transC) {
    dim3 g(nT, mT, nz);
    if (TP == 128)
      mfma_gemm_kernel<128><<<g, 256, 0, stream>>>(A, lda, aofs, WTp, ldw, kslice,
                                                   bias, relu, Cf, Cf2, Cbf, ldc, transC);
    else
      mfma_gemm_kernel<1024><<<g, 256, 0, stream>>>(A, lda, aofs, WTp, ldw, kslice,
                                                    bias, relu, Cf, Cf2, Cbf, ldc, transC);
  };

  auto run_layer = [&](int TP, const float* const* w, int i, float* Xf, bf16* Xbf,
                       const float* mask, const int* lens) {
    const int mT = B_ * TP / 128;
    const int tshift = (TP == 128) ? 7 : 10;
    gemm(TP, QKV_N / 128, mT, 1, Xbf, D_, 0, QKVT + (size_t)i * QKV_N * D_, D_, D_,
         nullptr, 0, nullptr, nullptr, QKVbf, QKV_N, 0);
    transpose_v_kernel<<<dim3(TP / 32, 2, B_ * H_), 256, 0, stream>>>(QKVbf, VTb, lens, TP);
    attn4_kernel<<<dim3(TP / 64, H_, B_), 256, 0, stream>>>(QKVbf, VTb, mask, lens, OBbf, TP);
    // WO split-K=2: slice0 -> OF, slice1 -> YTal (YT dead; ln reads then rewrites)
    gemm(TP, D_ / 128, mT, 2, OBbf, D_, 0, WOT + (size_t)i * D_ * D_, D_, D_ / 2,
         nullptr, 0, OF, YTal, nullptr, D_, 0);
    add_ln_kernel<<<B_ * TP, 128, 0, stream>>>(Xf, OF, YTal, w[4] + (size_t)i * D_,
                                               w[5] + (size_t)i * D_, YT, YTbf, tshift, 0);
    gemm(TP, INTER_ / 128, mT, 1, YTbf, D_, D_, C1T + (size_t)i * INTER_ * 3 * D_, 3 * D_,
         3 * D_, w[7] + (size_t)i * INTER_, 1, nullptr, nullptr, MIDbf, INTER_, 0);
    // conv2 split-K=2: slice0 -> OF, slice1 -> PT2 (OBbf+VTb span)
    gemm(TP, D_ / 128, mT, 2, MIDbf, INTER_, INTER_, C2T + (size_t)i * D_ * 3 * INTER_,
         3 * INTER_, 3 * INTER_ / 2, w[9] + (size_t)i * D_, 0, OF, PT2, nullptr, D_, 0);
    add_ln_kernel<<<B_ * TP, 128, 0, stream>>>(YT, OF, PT2, w[10] + (size_t)i * D_,
                                               w[11] + (size_t)i * D_, Xf, Xbf, tshift, 0);
  };

  // 1) embed + masks + pad zeroing
  embed_kernel<<<(B_ * T_ * D_ + 255) / 256, 256, 0, stream>>>(tokens, emb, XE, XEbf);
  enc_mask_kernel<<<(B_ * T_ + 255) / 256, 256, 0, stream>>>(token_lengths, MASKE);
  zero_pads_kernel<<<B_ * 2, 256, 0, stream>>>(XEbf, T_, D_);
  zero_pads_kernel<<<B_ * 2, 256, 0, stream>>>(YTbf, T_, D_);
  zero_pads_kernel<<<B_ * 2, 256, 0, stream>>>(MIDbf, T_, INTER_);

  // 2) encoder weights (batched) + stack
  tw(encw[0], (long)D_ * HD_, QKVT, (long)QKV_N * D_, D_, HD_, HD_, 0, L_);
  tw(encw[1], (long)D_ * HD_, QKVT, (long)QKV_N * D_, D_, HD_, HD_, 384, L_);
  tw(encw[2], (long)D_ * HD_, QKVT, (long)QKV_N * D_, D_, HD_, HD_, 768, L_);
  tw(encw[3], (long)HD_ * D_, WOT, (long)D_ * D_, HD_, D_, D_, 0, L_);
  tw(encw[6], (long)3 * D_ * INTER_, C1T, (long)INTER_ * 3 * D_, 3 * D_, INTER_, INTER_, 0, L_);
  tw(encw[8], (long)3 * INTER_ * D_, C2T, (long)D_ * 3 * INTER_, 3 * INTER_, D_, D_, 0, L_);
  for (int i = 0; i < L_; ++i) run_layer(T_, encw, i, XE, XEbf, MASKE, token_lengths);

  // 3) duration predictor (split-K=2, relu moved into add_ln)
  tw(dp_c1w, 0, DP1T, 0, 3 * D_, D_, D_, 0, 1);
  tw(dp_c2w, 0, DP2T, 0, 3 * D_, D_, D_, 0, 1);
  gemm(128, D_ / 128, B_, 2, XEbf, D_, D_, DP1T, 3 * D_, 3 * D_ / 2, dp_c1b, 0,
       OF, YTal, nullptr, D_, 0);
  add_ln_kernel<<<B_ * T_, 128, 0, stream>>>(OF, YTal, nullptr, dp_ln1g, dp_ln1b,
                                             YT, YTbf, 7, 1);
  gemm(128, D_ / 128, B_, 2, YTbf, D_, D_, DP2T, 3 * D_, 3 * D_ / 2, dp_c2b, 0,
       OF, YTal, nullptr, D_, 0);
  add_ln_kernel<<<B_ * T_, 128, 0, stream>>>(OF, YTal, nullptr, dp_ln2g, dp_ln2b,
                                             YT, nullptr, 7, 1);
  dp_linear_kernel<<<B_ * T_, 64, 0, stream>>>(YT, dp_w, dp_b, out_lp);

  // 4) length regulator
  lr_scan_kernel<<<B_, 32, 0, stream>>>(durations, CS, MEL);
  lr_build_kernel<<<B_, 256, 0, stream>>>(CS, MEL, IDX, MASKD);
  zero_pads_kernel<<<B_ * 2, 256, 0, stream>>>(XDbf, TMEL_, D_);
  zero_pads_kernel<<<B_ * 2, 256, 0, stream>>>(YTbf, TMEL_, D_);
  zero_pads_kernel<<<B_ * 2, 256, 0, stream>>>(MIDbf, TMEL_, INTER_);
  lr_gather_kernel<<<B_ * TMEL_, 128, 0, stream>>>(XE, IDX, XD, XDbf);

  // 5) decoder weights (batched) + stack
  tw(decw[0], (long)D_ * HD_, QKVT, (long)QKV_N * D_, D_, HD_, HD_, 0, L_);
  tw(decw[1], (long)D_ * HD_, QKVT, (long)QKV_N * D_, D_, HD_, HD_, 384, L_);
  tw(decw[2], (long)D_ * HD_, QKVT, (long)QKV_N * D_, D_, HD_, HD_, 768, L_);
  tw(decw[3], (long)HD_ * D_, WOT, (long)D_ * D_, HD_, D_, D_, 0, L_);
  tw(decw[6], (long)3 * D_ * INTER_, C1T, (long)INTER_ * 3 * D_, 3 * D_, INTER_, INTER_, 0, L_);
  tw(decw[8], (long)3 * INTER_ * D_, C2T, (long)D_ * 3 * INTER_, 3 * INTER_, D_, D_, 0, L_);
  for (int i = 0; i < L_; ++i) run_layer(TMEL_, decw, i, XD, XDbf, MASKD, MEL);

  // 6) final projection via MFMA GEMM with transposed mel write
  tw(out_w, 0, OUTT, 0, D_, OUT_C, 128, 0, 1);
  gemm(TMEL_, 1, B_ * TMEL_ / 128, 1, XDbf, D_, 0, OUTT, D_, D_, out_b, 0,
       out0, nullptr, nullptr, 0, 1);
}

// Round 9
// 1426.085 us; speedup vs baseline: 17.0166x; 1.0186x over previous
//
#include <hip/hip_runtime.h>
#include <math.h>

typedef __bf16 bf16;
typedef __attribute__((ext_vector_type(8))) __bf16 bf16x8;
typedef __attribute__((ext_vector_type(4))) float f32x4;

// ---- problem constants ----
constexpr int B_ = 8;
constexpr int T_ = 128;
constexpr int D_ = 384;
constexpr int H_ = 6;
constexpr int DH_ = 64;
constexpr int L_ = 4;
constexpr int INTER_ = 1536;
constexpr int OUT_C = 80;
constexpr int TMEL_ = 1024;
constexpr int HD_ = 384;     // H*DH
constexpr int QKV_N = 1152;  // 3*HD

// XCD-aware chunked swizzle (T1): bijective when nwg%8==0; identity otherwise.
__device__ __forceinline__ int xcd_swizzle(int bid, int nwg) {
  if (nwg & 7) return bid;
  return (bid & 7) * (nwg >> 3) + (bid >> 3);
}

// ===========================================================================
// Embedding + PE (PE indexed by BATCH per reference quirk): x = 2*emb + pe[b]
// ===========================================================================
__global__ __launch_bounds__(256) void embed_kernel(
    const int* __restrict__ tokens, const float* __restrict__ emb,
    float* __restrict__ X, bf16* __restrict__ Xbf) {
  int i = blockIdx.x * 256 + threadIdx.x;
  if (i >= B_ * T_ * D_) return;
  int d = i % D_;
  int bt = i / D_;
  int b = bt / T_, t = bt % T_;
  int tok = tokens[bt];
  int i2 = d & ~1;
  const float c = 9.210340371976184f / (float)D_;  // ln(10000)/D
  float freq = expf(-(float)i2 * c);
  float ang = (float)b * freq;
  float pe = (d & 1) ? cosf(ang) : sinf(ang);
  float v = 2.0f * emb[(size_t)tok * D_ + d] + pe;
  X[i] = v;
  Xbf[((size_t)b * (T_ + 2) + 1 + t) * D_ + d] = (bf16)v;
}

__global__ void enc_mask_kernel(const int* __restrict__ tl, float* __restrict__ maske) {
  int i = blockIdx.x * 256 + threadIdx.x;
  if (i >= B_ * T_) return;
  int b = i / T_, t = i % T_;
  maske[i] = (t > tl[b]) ? -INFINITY : 0.0f;
}

// ===========================================================================
// Weight transpose: src fp32 [K][N] -> dst bf16 [Ndst + rowOfs][K] row-major.
// ===========================================================================
__global__ __launch_bounds__(256) void transpose_w_kernel(
    const float* __restrict__ src, long srcLS, bf16* __restrict__ dst,
    long dstLS, int K, int N, int rowOfs) {
  src += (size_t)blockIdx.z * srcLS;
  dst += (size_t)blockIdx.z * dstLS;
  __shared__ float tile[32][33];
  const int tx = threadIdx.x & 31, ty = threadIdx.x >> 5;
  const int n0 = blockIdx.x * 32, k0 = blockIdx.y * 32;
#pragma unroll
  for (int j = 0; j < 4; ++j)
    tile[ty + j * 8][tx] =
        (n0 + tx < N) ? src[(size_t)(k0 + ty + j * 8) * N + n0 + tx] : 0.0f;
  __syncthreads();
#pragma unroll
  for (int j = 0; j < 4; ++j)
    dst[(size_t)(n0 + rowOfs + ty + j * 8) * K + k0 + tx] = (bf16)tile[tx][ty + j * 8];
}

// Zero padding rows of the three padded bf16 activation buffers in one launch.
__global__ void zero_pads3_kernel(bf16* a, bf16* c, bf16* m, int Tp) {
  int b = blockIdx.x >> 1, side = blockIdx.x & 1;
  size_t row = (size_t)b * (Tp + 2) + (side ? (Tp + 1) : 0);
  bf16* buf = (blockIdx.y == 0) ? a : (blockIdx.y == 1) ? c : m;
  int C = (blockIdx.y == 2) ? INTER_ : D_;
  for (int cc = threadIdx.x; cc < C; cc += 256) buf[row * C + cc] = (bf16)0.0f;
}

// ===========================================================================
// V transpose: QKVbf [b][(T+2)][1152] cols 768.. -> VT [b*6+h][64][T].
// Gated: only key tiles the attention will actually stage (tb < ntiles*2).
// ===========================================================================
__global__ __launch_bounds__(256) void transpose_v_kernel(
    const bf16* __restrict__ QKV, bf16* __restrict__ VT,
    const int* __restrict__ lens, int T) {
  const int tb = blockIdx.x, db = blockIdx.y, bh = blockIdx.z;
  const int b = bh / H_, h = bh % H_;
  const int ntiles = min(T >> 6, (lens[b] + 64) >> 6);
  if (tb >= ntiles * 2) return;
  __shared__ float tile[32][33];
  const int tx = threadIdx.x & 31, ty = threadIdx.x >> 5;
  const size_t src = ((size_t)b * (T + 2) + 1 + tb * 32) * QKV_N + 768 + h * DH_ + db * 32;
#pragma unroll
  for (int j = 0; j < 4; ++j)
    tile[ty + 8 * j][tx] = (float)QKV[src + (size_t)(ty + 8 * j) * QKV_N + tx];
  __syncthreads();
  const size_t dst = ((size_t)(b * H_ + h) * DH_ + db * 32) * T + tb * 32;
#pragma unroll
  for (int j = 0; j < 4; ++j)
    VT[dst + (size_t)(ty + 8 * j) * T + tx] = (bf16)tile[tx][ty + 8 * j];
}

// ===========================================================================
// MFMA bf16 GEMM, 128x128 tile, BK=32, 4 waves (2x2 of 64x64).
// 3-buffer LDS pipeline with COUNTED vmcnt (T4): issue stage(t+2), wait
// vmcnt(8) (only tile t's 8 load-insts), raw s_barrier (no drain), compute,
// raw s_barrier. Loads get 2 full iterations of latency coverage; the
// prefetch never drains to 0 in the main loop. vmcnt retires oldest-first.
// XCD-chunked block swizzle; split-K via z (z==0 -> Cf (+bias), z==1 -> Cf2).
// transC: write fp32 transposed mel output out[(b*OUT_C+col)*TMEL + t].
// ===========================================================================
template <int TP>
__global__ __launch_bounds__(256) void mfma_gemm_kernel(
    const bf16* __restrict__ A, int lda, int aofs,
    const bf16* __restrict__ WT, int ldw, int kslice,
    const float* __restrict__ bias, int relu,
    float* __restrict__ Cf, float* __restrict__ Cf2,
    bf16* __restrict__ Cbf, int ldc, int transC) {
  __shared__ bf16 As[3][128 * 32];
  __shared__ bf16 Bs[3][128 * 32];
  const int tid = threadIdx.x;
  const int lane = tid & 63;
  const int wave = tid >> 6;
  const int wr = wave >> 1, wc = wave & 1;

  // ---- XCD swizzle: decode (bx, by, z) from chunked work id ----
  const int nT = gridDim.x, mT = gridDim.y;
  const int nwg = nT * mT * gridDim.z;
  int bid = blockIdx.x + nT * (blockIdx.y + mT * blockIdx.z);
  int wid = xcd_swizzle(bid, nwg);
  const int bx = wid % nT;
  int tmp = wid / nT;
  const int by = tmp % mT;
  const int z = tmp / mT;

  const int rowBase = by * 128;
  const int colBase = bx * 128;
  const int k0beg = z * kslice;
  const int nt = kslice / 32;
  const int bb = rowBase / TP;
  const long pr0 = (long)bb * (TP + 2) + 1 + (rowBase - bb * TP);
  const long abase = pr0 * (long)lda - aofs;

  const int srow = tid >> 2, scb = tid & 3;

  auto stage = [&](int t, int buf) {  // 4 VMEM instructions per thread
    const int k0 = k0beg + t * 32;
#pragma unroll
    for (int e = 0; e < 2; ++e) {
      int idx = e * 256 + tid;
      int lrow = srow + e * 64;
      const bf16* gp = A + abase + (long)lrow * lda + k0 + ((scb ^ ((lrow >> 1) & 3)) << 3);
      __builtin_amdgcn_global_load_lds(
          (const __attribute__((address_space(1))) unsigned int*)gp,
          (__attribute__((address_space(3))) unsigned int*)(As[buf] + idx * 8), 16, 0, 0);
    }
#pragma unroll
    for (int e = 0; e < 2; ++e) {
      int idx = e * 256 + tid;
      int lrow = srow + e * 64;
      const bf16* gp = WT + (long)(colBase + lrow) * ldw + k0 + ((scb ^ ((lrow >> 1) & 3)) << 3);
      __builtin_amdgcn_global_load_lds(
          (const __attribute__((address_space(1))) unsigned int*)gp,
          (__attribute__((address_space(3))) unsigned int*)(Bs[buf] + idx * 8), 16, 0, 0);
    }
  };

  f32x4 acc[4][4] = {};
  const int g = lane >> 4, l15 = lane & 15;

  stage(0, 0);
  if (nt > 1) stage(1, 1);
  int cur = 0;
  for (int t = 0; t < nt; ++t) {
    if (t + 2 < nt) {
      int sb = cur + 2;
      if (sb >= 3) sb -= 3;
      stage(t + 2, sb);
    }
    // counted wait: leave the 'ahead' newest stages (4 insts each) in flight
    int ahead = nt - 1 - t;
    if (ahead >= 2)
      asm volatile("s_waitcnt vmcnt(8)" ::: "memory");
    else if (ahead == 1)
      asm volatile("s_waitcnt vmcnt(4)" ::: "memory");
    else
      asm volatile("s_waitcnt vmcnt(0)" ::: "memory");
    __builtin_amdgcn_s_barrier();   // all waves' tile-t loads landed
    asm volatile("" ::: "memory");

    const bf16* Asb = As[cur];
    const bf16* Bsb = Bs[cur];
    bf16x8 af[4], bw[4];
#pragma unroll
    for (int m = 0; m < 4; ++m) {
      int row = wr * 64 + m * 16 + l15;
      int cb = g ^ ((row >> 1) & 3);
      af[m] = *(const bf16x8*)(Asb + row * 32 + cb * 8);
    }
#pragma unroll
    for (int n = 0; n < 4; ++n) {
      int row = wc * 64 + n * 16 + l15;
      int cb = g ^ ((row >> 1) & 3);
      bw[n] = *(const bf16x8*)(Bsb + row * 32 + cb * 8);
    }
#pragma unroll
    for (int m = 0; m < 4; ++m)
#pragma unroll
      for (int n = 0; n < 4; ++n)
        acc[m][n] = __builtin_amdgcn_mfma_f32_16x16x32_bf16(af[m], bw[n], acc[m][n], 0, 0, 0);

    asm volatile("" ::: "memory");
    __builtin_amdgcn_s_barrier();   // all waves done reading buf cur
    cur = (cur + 1 == 3) ? 0 : cur + 1;
  }

  float* Cfz = z ? Cf2 : Cf;
  const float* biasz = z ? nullptr : bias;
  const int qr = (lane >> 4) * 4;
  const int qc = lane & 15;
#pragma unroll
  for (int m = 0; m < 4; ++m) {
    int lrow = wr * 64 + m * 16 + qr;
#pragma unroll
    for (int n = 0; n < 4; ++n) {
      int gcol = colBase + wc * 64 + n * 16 + qc;
      float bv = (biasz && (!transC || gcol < OUT_C)) ? biasz[gcol] : 0.0f;
#pragma unroll
      for (int q = 0; q < 4; ++q) {
        float v = acc[m][n][q] + bv;
        if (relu) v = fmaxf(v, 0.0f);
        if (transC) {
          if (gcol < OUT_C)
            Cfz[((long)bb * OUT_C + gcol) * TMEL_ + (rowBase - bb * TP + lrow + q)] = v;
        } else {
          if (Cfz) Cfz[(long)(rowBase + lrow + q) * ldc + gcol] = v;
          if (Cbf) Cbf[(pr0 + lrow + q) * ldc + gcol] = (bf16)v;
        }
      }
    }
  }
}

// ===========================================================================
// MFMA flash attention with exact key-tile skip + XCD-chunked swizzle
// (qt fastest within chunk -> each XCD keeps one batch's K/V in its L2).
// ===========================================================================
__global__ __launch_bounds__(256) void attn4_kernel(
    const bf16* __restrict__ QKV, const bf16* __restrict__ VT,
    const float* __restrict__ maskadd, const int* __restrict__ lens,
    bf16* __restrict__ Obf, int T) {
  const int nQT = gridDim.x;
  const int nwg = nQT * H_ * B_;
  int bid = blockIdx.x + nQT * (blockIdx.y + H_ * blockIdx.z);
  int wid = xcd_swizzle(bid, nwg);
  const int qt = wid % nQT;
  int tmp = wid / nQT;
  const int h = tmp % H_;
  const int b = tmp / H_;

  const int tid = threadIdx.x;
  const int lane = tid & 63;
  const int wave = tid >> 6;
  const int l15 = lane & 15, g = lane >> 4;

  __shared__ bf16 Ks[64 * 64];
  __shared__ bf16 Vts[64 * 64];
  __shared__ bf16 Ps[4][16 * 64];
  __shared__ float mask_s[TMEL_];

  const int q0 = qt * 64;
  const size_t brow0 = (size_t)b * (T + 2) + 1;

  for (int i = tid; i < T; i += 256) mask_s[i] = maskadd[(size_t)b * T + i];

  const size_t qrow = brow0 + q0 + wave * 16 + l15;
  bf16x8 qf0 = *(const bf16x8*)(QKV + qrow * QKV_N + h * DH_ + g * 8);
  bf16x8 qf1 = *(const bf16x8*)(QKV + qrow * QKV_N + h * DH_ + g * 8 + 32);

  float mreg[4], lreg[4];
#pragma unroll
  for (int r = 0; r < 4; ++r) { mreg[r] = -INFINITY; lreg[r] = 0.0f; }
  f32x4 oacc[4] = {};
  bf16* Psb = Ps[wave];

  const int nt = min(T >> 6, (lens[b] + 64) >> 6);
  for (int t = 0; t < nt; ++t) {
    const int k0 = t * 64;
#pragma unroll
    for (int it = 0; it < 2; ++it) {
      int c = it * 256 + tid;
      int r = c >> 3, d0 = c & 7;
      bf16x8 kv = *(const bf16x8*)(QKV + (brow0 + k0 + r) * QKV_N + 384 + h * DH_ + d0 * 8);
      *(bf16x8*)(Ks + r * 64 + ((d0 ^ (r & 7)) << 3)) = kv;
      bf16x8 vv = *(const bf16x8*)(VT + ((size_t)(b * H_ + h) * DH_ + r) * T + k0 + d0 * 8);
      *(bf16x8*)(Vts + r * 64 + ((d0 ^ (r & 7)) << 3)) = vv;
    }
    __syncthreads();

    f32x4 sacc[4] = {};
#pragma unroll
    for (int ks = 0; ks < 2; ++ks) {
#pragma unroll
      for (int n = 0; n < 4; ++n) {
        int key = n * 16 + l15;
        bf16x8 bf = *(const bf16x8*)(Ks + key * 64 + (((g + ks * 4) ^ (key & 7)) << 3));
        sacc[n] = __builtin_amdgcn_mfma_f32_16x16x32_bf16(ks ? qf1 : qf0, bf, sacc[n], 0, 0, 0);
      }
    }

    float s[4][4];
    float tm[4] = {-INFINITY, -INFINITY, -INFINITY, -INFINITY};
#pragma unroll
    for (int n = 0; n < 4; ++n) {
      float mv = mask_s[k0 + n * 16 + l15];
#pragma unroll
      for (int r = 0; r < 4; ++r) {
        float v = sacc[n][r] * 0.125f + mv;
        s[n][r] = v;
        tm[r] = fmaxf(tm[r], v);
      }
    }
#pragma unroll
    for (int msk = 1; msk < 16; msk <<= 1)
#pragma unroll
      for (int r = 0; r < 4; ++r) tm[r] = fmaxf(tm[r], __shfl_xor(tm[r], msk));

    float sc[4];
#pragma unroll
    for (int r = 0; r < 4; ++r) {
      float mn = fmaxf(mreg[r], tm[r]);
      sc[r] = __expf(mreg[r] - mn);
      mreg[r] = mn;
    }
    float psum[4] = {0.0f, 0.0f, 0.0f, 0.0f};
#pragma unroll
    for (int n = 0; n < 4; ++n) {
      int key = n * 16 + l15;
      int kblk = key >> 3, kin = key & 7;
#pragma unroll
      for (int r = 0; r < 4; ++r) {
        float p = __expf(s[n][r] - mreg[r]);
        psum[r] += p;
        int q = g * 4 + r;
        Psb[q * 64 + ((kblk ^ (q & 7)) << 3) + kin] = (bf16)p;
      }
    }
#pragma unroll
    for (int msk = 1; msk < 16; msk <<= 1)
#pragma unroll
      for (int r = 0; r < 4; ++r) psum[r] += __shfl_xor(psum[r], msk);
#pragma unroll
    for (int r = 0; r < 4; ++r) lreg[r] = lreg[r] * sc[r] + psum[r];
#pragma unroll
    for (int n = 0; n < 4; ++n)
#pragma unroll
      for (int r = 0; r < 4; ++r) oacc[n][r] *= sc[r];

#pragma unroll
    for (int ks = 0; ks < 2; ++ks) {
      bf16x8 af = *(const bf16x8*)(Psb + l15 * 64 + (((g + ks * 4) ^ (l15 & 7)) << 3));
#pragma unroll
      for (int n = 0; n < 4; ++n) {
        int dh = n * 16 + l15;
        bf16x8 bv = *(const bf16x8*)(Vts + dh * 64 + (((g + ks * 4) ^ (dh & 7)) << 3));
        oacc[n] = __builtin_amdgcn_mfma_f32_16x16x32_bf16(af, bv, oacc[n], 0, 0, 0);
      }
    }
    __syncthreads();
  }

  float inv[4];
#pragma unroll
  for (int r = 0; r < 4; ++r) inv[r] = 1.0f / lreg[r];
  const size_t orow = brow0 + q0 + wave * 16 + g * 4;
#pragma unroll
  for (int n = 0; n < 4; ++n)
#pragma unroll
    for (int r = 0; r < 4; ++r)
      Obf[(orow + r) * D_ + h * DH_ + n * 16 + l15] = (bf16)(oacc[n][r] * inv[r]);
}

// ===========================================================================
// Y = LN(opt-relu(X + H1 + H2)) * g + b. H1/H2 nullable (split-K slices).
// Safe when H1/H2 alias Yf (row-local: all reads before writes).
// ===========================================================================
__global__ __launch_bounds__(128) void add_ln_kernel(
    const float* __restrict__ X, const float* __restrict__ H1,
    const float* __restrict__ H2,
    const float* __restrict__ g, const float* __restrict__ bb,
    float* __restrict__ Yf, bf16* __restrict__ Ybf, int tshift, int relu) {
  const int row = blockIdx.x;
  const int tid = threadIdx.x;
  __shared__ float red[128];
  float v[3];
  float s = 0.0f;
#pragma unroll
  for (int e = 0; e < 3; ++e) {
    int d = tid + e * 128;
    float x = X[(size_t)row * D_ + d];
    if (H1) x += H1[(size_t)row * D_ + d];
    if (H2) x += H2[(size_t)row * D_ + d];
    if (relu) x = fmaxf(x, 0.0f);
    v[e] = x;
    s += x;
  }
  red[tid] = s;
  __syncthreads();
  for (int off = 64; off > 0; off >>= 1) {
    if (tid < off) red[tid] += red[tid + off];
    __syncthreads();
  }
  float mean = red[0] / (float)D_;
  __syncthreads();
  float s2 = 0.0f;
#pragma unroll
  for (int e = 0; e < 3; ++e) {
    float dd = v[e] - mean;
    s2 += dd * dd;
  }
  red[tid] = s2;
  __syncthreads();
  for (int off = 64; off > 0; off >>= 1) {
    if (tid < off) red[tid] += red[tid + off];
    __syncthreads();
  }
  float invstd = rsqrtf(red[0] / (float)D_ + 1e-5f);
  __syncthreads();
  const int b = row >> tshift, t = row & ((1 << tshift) - 1);
  const size_t prow = (size_t)b * ((1 << tshift) + 2) + 1 + t;
#pragma unroll
  for (int e = 0; e < 3; ++e) {
    int d = tid + e * 128;
    float y = (v[e] - mean) * invstd * g[d] + bb[d];
    Yf[(size_t)row * D_ + d] = y;
    if (Ybf) Ybf[prow * D_ + d] = (bf16)y;
  }
}

__global__ __launch_bounds__(64) void dp_linear_kernel(
    const float* __restrict__ Hh, const float* __restrict__ w,
    const float* __restrict__ b0, float* __restrict__ lp) {
  const int row = blockIdx.x;
  const int tid = threadIdx.x;
  float s = 0.0f;
  for (int d = tid; d < D_; d += 64) s += Hh[(size_t)row * D_ + d] * w[d];
#pragma unroll
  for (int off = 32; off > 0; off >>= 1) s += __shfl_down(s, off);
  if (tid == 0) lp[row] = s + b0[0];
}

// ---------------------------------------------------------------------------
// Length regulator
// ---------------------------------------------------------------------------
__global__ void lr_scan_kernel(const int* __restrict__ dur, int* __restrict__ cs,
                               int* __restrict__ mel) {
  int b = blockIdx.x;
  if (threadIdx.x == 0) {
    int s = 0;
    for (int t = 0; t < T_; ++t) {
      s += dur[b * T_ + t];
      cs[b * T_ + t] = s;
    }
    mel[b] = s;
  }
}

__global__ __launch_bounds__(256) void lr_build_kernel(
    const int* __restrict__ cs, const int* __restrict__ mel,
    int* __restrict__ idx, float* __restrict__ maskd) {
  int b = blockIdx.x;
  int mlen = mel[b];
  for (int m = threadIdx.x; m < TMEL_; m += 256) {
    int t = -1;
    if (m < mlen) {
      int lo = 0, hi = T_ - 1;
      while (lo < hi) {
        int mid = (lo + hi) >> 1;
        if (cs[b * T_ + mid] > m) hi = mid; else lo = mid + 1;
      }
      t = lo;
    }
    idx[b * TMEL_ + m] = t;
    maskd[b * TMEL_ + m] = (m > mlen) ? -INFINITY : 0.0f;
  }
}

__global__ __launch_bounds__(128) void lr_gather_kernel(
    const float* __restrict__ XE, const int* __restrict__ idx,
    float* __restrict__ XD, bf16* __restrict__ XDbf) {
  int row = blockIdx.x;
  int b = row / TMEL_, m = row % TMEL_;
  int t = idx[row];
  size_t prow = ((size_t)b * (TMEL_ + 2) + 1 + m) * D_;
  for (int d = threadIdx.x; d < D_; d += 128) {
    float v = (t >= 0) ? XE[((size_t)(b * T_ + t)) * D_ + d] : 0.0f;
    XD[(size_t)row * D_ + d] = v;
    XDbf[prow + d] = (bf16)v;
  }
}

// ===========================================================================
// Host
// ===========================================================================
extern "C" void kernel_launch(void* const* d_in, const int* in_sizes, int n_in,
                              void* d_out, int out_size, void* d_ws, size_t ws_size,
                              hipStream_t stream) {
  const int* tokens = (const int*)d_in[0];
  const int* token_lengths = (const int*)d_in[1];
  const int* durations = (const int*)d_in[2];
  const float* emb = (const float*)d_in[3];
  const float* encw[12];
  const float* decw[12];
  for (int i = 0; i < 12; ++i) encw[i] = (const float*)d_in[4 + i];
  for (int i = 0; i < 12; ++i) decw[i] = (const float*)d_in[16 + i];
  const float* dp_c1w = (const float*)d_in[28];
  const float* dp_c1b = (const float*)d_in[29];
  const float* dp_ln1g = (const float*)d_in[30];
  const float* dp_ln1b = (const float*)d_in[31];
  const float* dp_c2w = (const float*)d_in[32];
  const float* dp_c2b = (const float*)d_in[33];
  const float* dp_ln2g = (const float*)d_in[34];
  const float* dp_ln2b = (const float*)d_in[35];
  const float* dp_w = (const float*)d_in[36];
  const float* dp_b = (const float*)d_in[37];
  const float* out_w = (const float*)d_in[38];
  const float* out_b = (const float*)d_in[39];

  float* out0 = (float*)d_out;                        // [B, OUT, TMEL]
  float* out_lp = out0 + (size_t)B_ * OUT_C * TMEL_;  // [B, T]

  // ---- workspace ----
  char* wsB = (char*)d_ws;
  size_t off = 0;
  auto alloc = [&](size_t bytes) {
    void* p = wsB + off;
    off = (off + bytes + 255) & ~(size_t)255;
    return p;
  };
  float* XE = (float*)alloc((size_t)B_ * T_ * D_ * 4);
  float* XD = (float*)alloc((size_t)B_ * TMEL_ * D_ * 4);
  float* YT = (float*)alloc((size_t)B_ * TMEL_ * D_ * 4);
  bf16* XEbf = (bf16*)alloc((size_t)B_ * (T_ + 2) * D_ * 2);
  bf16* XDbf = (bf16*)alloc((size_t)B_ * (TMEL_ + 2) * D_ * 2);
  bf16* YTbf = (bf16*)alloc((size_t)B_ * (TMEL_ + 2) * D_ * 2);
  bf16* MIDbf = (bf16*)alloc((size_t)B_ * (TMEL_ + 2) * INTER_ * 2);
  bf16* QKVbf = (bf16*)alloc((size_t)B_ * (TMEL_ + 2) * QKV_N * 2);
  bf16* OBbf = (bf16*)alloc((size_t)B_ * (TMEL_ + 2) * D_ * 2);   // 6.30 MB
  bf16* VTb = (bf16*)alloc((size_t)B_ * H_ * DH_ * TMEL_ * 2);    // 6.29 MB, adjacent
  float* OF = (float*)QKVbf;  // fp32 slice-0 out (aliases QKVbf; disjoint lifetime)
  float* PT2 = (float*)OBbf;  // conv2 slice-1: OBbf+VTb contiguous span (both dead)
  float* YTal = (float*)YT;   // WO/dp slice-1: YT dead at those points; add_ln
                              // reads it before rewriting (row-local safe)
  bf16* QKVT = (bf16*)alloc((size_t)L_ * QKV_N * D_ * 2);
  bf16* WOT = (bf16*)alloc((size_t)L_ * D_ * D_ * 2);
  bf16* C1T = (bf16*)alloc((size_t)L_ * INTER_ * (3 * D_) * 2);
  bf16* C2T = (bf16*)alloc((size_t)L_ * D_ * (3 * INTER_) * 2);
  bf16* DP1T = (bf16*)alloc((size_t)D_ * (3 * D_) * 2);
  bf16* DP2T = (bf16*)alloc((size_t)D_ * (3 * D_) * 2);
  bf16* OUTT = (bf16*)alloc((size_t)128 * D_ * 2);
  float* MASKE = (float*)alloc(B_ * T_ * 4);
  float* MASKD = (float*)alloc(B_ * TMEL_ * 4);
  int* CS = (int*)alloc(B_ * T_ * 4);
  int* MEL = (int*)alloc(B_ * 4);
  int* IDX = (int*)alloc(B_ * TMEL_ * 4);

  auto tw = [&](const float* s, long sls, bf16* d, long dls, int K, int N,
                int Ndst, int ro, int Lz) {
    transpose_w_kernel<<<dim3(Ndst / 32, K / 32, Lz), 256, 0, stream>>>(s, sls, d, dls, K, N, ro);
  };
  auto gemm = [&](int TP, int nT, int mT, int nz, const bf16* A, int lda, int aofs,
                  const bf16* WTp, int ldw, int kslice, const float* bias, int relu,
                  float* Cf, float* Cf2, bf16* Cbf, int ldc, int transC) {
    dim3 g(nT, mT, nz);
    if (TP == 128)
      mfma_gemm_kernel<128><<<g, 256, 0, stream>>>(A, lda, aofs, WTp, ldw, kslice,
                                                   bias, relu, Cf, Cf2, Cbf, ldc, transC);
    else
      mfma_gemm_kernel<1024><<<g, 256, 0, stream>>>(A, lda, aofs, WTp, ldw, kslice,
                                                    bias, relu, Cf, Cf2, Cbf, ldc, transC);
  };

  auto run_layer = [&](int TP, const float* const* w, int i, float* Xf, bf16* Xbf,
                       const float* mask, const int* lens) {
    const int mT = B_ * TP / 128;
    const int tshift = (TP == 128) ? 7 : 10;
    gemm(TP, QKV_N / 128, mT, 1, Xbf, D_, 0, QKVT + (size_t)i * QKV_N * D_, D_, D_,
         nullptr, 0, nullptr, nullptr, QKVbf, QKV_N, 0);
    transpose_v_kernel<<<dim3(TP / 32, 2, B_ * H_), 256, 0, stream>>>(QKVbf, VTb, lens, TP);
    attn4_kernel<<<dim3(TP / 64, H_, B_), 256, 0, stream>>>(QKVbf, VTb, mask, lens, OBbf, TP);
    // WO split-K=2: slice0 -> OF, slice1 -> YTal (YT dead; ln reads then rewrites)
    gemm(TP, D_ / 128, mT, 2, OBbf, D_, 0, WOT + (size_t)i * D_ * D_, D_, D_ / 2,
         nullptr, 0, OF, YTal, nullptr, D_, 0);
    add_ln_kernel<<<B_ * TP, 128, 0, stream>>>(Xf, OF, YTal, w[4] + (size_t)i * D_,
                                               w[5] + (size_t)i * D_, YT, YTbf, tshift, 0);
    gemm(TP, INTER_ / 128, mT, 1, YTbf, D_, D_, C1T + (size_t)i * INTER_ * 3 * D_, 3 * D_,
         3 * D_, w[7] + (size_t)i * INTER_, 1, nullptr, nullptr, MIDbf, INTER_, 0);
    // conv2 split-K=2: slice0 -> OF, slice1 -> PT2 (OBbf+VTb span)
    gemm(TP, D_ / 128, mT, 2, MIDbf, INTER_, INTER_, C2T + (size_t)i * D_ * 3 * INTER_,
         3 * INTER_, 3 * INTER_ / 2, w[9] + (size_t)i * D_, 0, OF, PT2, nullptr, D_, 0);
    add_ln_kernel<<<B_ * TP, 128, 0, stream>>>(YT, OF, PT2, w[10] + (size_t)i * D_,
                                               w[11] + (size_t)i * D_, Xf, Xbf, tshift, 0);
  };

  // 1) embed + masks + pad zeroing
  embed_kernel<<<(B_ * T_ * D_ + 255) / 256, 256, 0, stream>>>(tokens, emb, XE, XEbf);
  enc_mask_kernel<<<(B_ * T_ + 255) / 256, 256, 0, stream>>>(token_lengths, MASKE);
  zero_pads3_kernel<<<dim3(B_ * 2, 3), 256, 0, stream>>>(XEbf, YTbf, MIDbf, T_);

  // 2) encoder weights (batched) + stack
  tw(encw[0], (long)D_ * HD_, QKVT, (long)QKV_N * D_, D_, HD_, HD_, 0, L_);
  tw(encw[1], (long)D_ * HD_, QKVT, (long)QKV_N * D_, D_, HD_, HD_, 384, L_);
  tw(encw[2], (long)D_ * HD_, QKVT, (long)QKV_N * D_, D_, HD_, HD_, 768, L_);
  tw(encw[3], (long)HD_ * D_, WOT, (long)D_ * D_, HD_, D_, D_, 0, L_);
  tw(encw[6], (long)3 * D_ * INTER_, C1T, (long)INTER_ * 3 * D_, 3 * D_, INTER_, INTER_, 0, L_);
  tw(encw[8], (long)3 * INTER_ * D_, C2T, (long)D_ * 3 * INTER_, 3 * INTER_, D_, D_, 0, L_);
  for (int i = 0; i < L_; ++i) run_layer(T_, encw, i, XE, XEbf, MASKE, token_lengths);

  // 3) duration predictor (split-K=2, relu moved into add_ln)
  tw(dp_c1w, 0, DP1T, 0, 3 * D_, D_, D_, 0, 1);
  tw(dp_c2w, 0, DP2T, 0, 3 * D_, D_, D_, 0, 1);
  gemm(128, D_ / 128, B_, 2, XEbf, D_, D_, DP1T, 3 * D_, 3 * D_ / 2, dp_c1b, 0,
       OF, YTal, nullptr, D_, 0);
  add_ln_kernel<<<B_ * T_, 128, 0, stream>>>(OF, YTal, nullptr, dp_ln1g, dp_ln1b,
                                             YT, YTbf, 7, 1);
  gemm(128, D_ / 128, B_, 2, YTbf, D_, D_, DP2T, 3 * D_, 3 * D_ / 2, dp_c2b, 0,
       OF, YTal, nullptr, D_, 0);
  add_ln_kernel<<<B_ * T_, 128, 0, stream>>>(OF, YTal, nullptr, dp_ln2g, dp_ln2b,
                                             YT, nullptr, 7, 1);
  dp_linear_kernel<<<B_ * T_, 64, 0, stream>>>(YT, dp_w, dp_b, out_lp);

  // 4) length regulator
  lr_scan_kernel<<<B_, 32, 0, stream>>>(durations, CS, MEL);
  lr_build_kernel<<<B_, 256, 0, stream>>>(CS, MEL, IDX, MASKD);
  zero_pads3_kernel<<<dim3(B_ * 2, 3), 256, 0, stream>>>(XDbf, YTbf, MIDbf, TMEL_);
  lr_gather_kernel<<<B_ * TMEL_, 128, 0, stream>>>(XE, IDX, XD, XDbf);

  // 5) decoder weights (batched) + stack
  tw(decw[0], (long)D_ * HD_, QKVT, (long)QKV_N * D_, D_, HD_, HD_, 0, L_);
  tw(decw[1], (long)D_ * HD_, QKVT, (long)QKV_N * D_, D_, HD_, HD_, 384, L_);
  tw(decw[2], (long)D_ * HD_, QKVT, (long)QKV_N * D_, D_, HD_, HD_, 768, L_);
  tw(decw[3], (long)HD_ * D_, WOT, (long)D_ * D_, HD_, D_, D_, 0, L_);
  tw(decw[6], (long)3 * D_ * INTER_, C1T, (long)INTER_ * 3 * D_, 3 * D_, INTER_, INTER_, 0, L_);
  tw(decw[8], (long)3 * INTER_ * D_, C2T, (long)D_ * 3 * INTER_, 3 * INTER_, D_, D_, 0, L_);
  for (int i = 0; i < L_; ++i) run_layer(TMEL_, decw, i, XD, XDbf, MASKD, MEL);

  // 6) final projection via MFMA GEMM with transposed mel write
  tw(out_w, 0, OUTT, 0, D_, OUT_C, 128, 0, 1);
  gemm(TMEL_, 1, B_ * TMEL_ / 128, 1, XDbf, D_, 0, OUTT, D_, D_, out_b, 0,
       out0, nullptr, nullptr, 0, 1);
}